// Round 6
// baseline (4800.856 us; speedup 1.0000x reference)
//
#include <hip/hip_runtime.h>
#include <hip/hip_bf16.h>
#include <math.h>

constexpr int Bn  = 4;
constexpr int Nn  = 1024;
constexpr int Mmm = 1024;
constexpr int PFDc = 1024;
constexpr int ADc  = 256;
constexpr int GFDc = 512;
constexpr int Hc   = 4;
constexpr int NRc  = 16;
constexpr float COEFFc = -28.125f;    // -0.5/(CUT/(NR-1))^2
constexpr float SCALEc = 0.125f;      // DH^-0.5
constexpr float STEPc  = 2.0f / 15.0f;

__device__ __forceinline__ float addf(float a, float b) { return a + b; }
__device__ __forceinline__ double addd(double a, double b) { return a + b; }

#define BLK_REDUCE_F(OP, VAR, RES) \
  red[tid] = (VAR); __syncthreads(); \
  for (int st_ = 128; st_ > 0; st_ >>= 1) { if (tid < st_) red[tid] = OP(red[tid], red[tid + st_]); __syncthreads(); } \
  (RES) = red[0]; __syncthreads();

#define BLK_REDUCE_D(OP, VAR, RES) \
  redd[tid] = (VAR); __syncthreads(); \
  for (int st_ = 128; st_ > 0; st_ >>= 1) { if (tid < st_) redd[tid] = OP(redd[tid], redd[tid + st_]); __syncthreads(); } \
  (RES) = redd[0]; __syncthreads();

// ---------------------------------------------------------------------------
// Naive GEMM: one thread per output element.
// ---------------------------------------------------------------------------
__global__ __launch_bounds__(256) void ngemm(
    const float* __restrict__ A, const float* __restrict__ W, const float* __restrict__ bias,
    const float* __restrict__ addsrc, float* __restrict__ C,
    int R, int K, int Cc, int act)
{
  long long idx = (long long)blockIdx.x * 256 + threadIdx.x;
  if (idx >= (long long)R * Cc) return;
  int r = (int)(idx / Cc), c = (int)(idx % Cc);
  float acc = 0.f;
  for (int k = 0; k < K; ++k)
    acc = fmaf(A[(size_t)r * K + k], W[(size_t)k * Cc + c], acc);
  float v = acc + bias[c];
  if (addsrc) v += addsrc[idx];
  if (act == 1) v = 0.5f * v * (1.f + erff(v * 0.70710678118654752f));
  C[idx] = v;
}

// logS[b][n][m] = (1/tau) * sum_k A[b,n,k] * Bm[b,m,k]
__global__ __launch_bounds__(256) void ngemm_nt(
    const float* __restrict__ A, const float* __restrict__ Bm, float* __restrict__ C,
    const float* __restrict__ temp)
{
  long long idx = (long long)blockIdx.x * 256 + threadIdx.x;   // B*N*M
  int b = (int)(idx >> 20);
  int n = (int)((idx >> 10) & 1023);
  int m = (int)(idx & 1023);
  float tau = fminf(fmaxf(temp[0], 0.01f), 1.0f);
  const float* Ar = A + ((size_t)b * Nn + n) * ADc;
  const float* Br = Bm + ((size_t)b * Mmm + m) * ADc;
  float acc = 0.f;
  for (int k = 0; k < ADc; ++k) acc = fmaf(Ar[k], Br[k], acc);
  C[idx] = acc / tau;
}

// ---------------------------------------------------------------------------
// LayerNorm (+ optional ReLU): one block per row
// ---------------------------------------------------------------------------
__global__ __launch_bounds__(256) void ln_k(
    const float* __restrict__ in, const float* __restrict__ g, const float* __restrict__ bb,
    float* __restrict__ out, int Cc, int relu)
{
  const int tid = threadIdx.x;
  const int row = blockIdx.x;
  const float* x = in + (size_t)row * Cc;
  float* o = out + (size_t)row * Cc;
  __shared__ float red[256];
  float s = 0.f;
  for (int j = tid; j < Cc; j += 256) s += x[j];
  float tot; BLK_REDUCE_F(addf, s, tot);
  float mu = tot / Cc;
  float s2 = 0.f;
  for (int j = tid; j < Cc; j += 256) { float d = x[j] - mu; s2 += d * d; }
  float tot2; BLK_REDUCE_F(addf, s2, tot2);
  float inv = 1.f / sqrtf(tot2 / Cc + 1e-5f);
  for (int j = tid; j < Cc; j += 256) {
    float v = (x[j] - mu) * inv * g[j] + bb[j];
    if (relu) v = fmaxf(v, 0.f);
    o[j] = v;
  }
}

// ---------------------------------------------------------------------------
// Naive attention: one block per (b,n,h); logits materialized in LDS.
// ---------------------------------------------------------------------------
__global__ __launch_bounds__(256) void nattn(
    const float* __restrict__ q, const float* __restrict__ k, const float* __restrict__ v,
    const float* __restrict__ src_pts, const float* __restrict__ tgt_pts,
    const float* __restrict__ rbfw, float* __restrict__ ctx)
{
  const int tid = threadIdx.x;
  const int id = blockIdx.x;          // B*N*H, h fastest
  const int h = id & 3;
  const int bn = id >> 2;
  const int b = bn >> 10;
  __shared__ float qs[64];
  __shared__ float rwh[NRc];
  __shared__ float lg[Mmm];
  __shared__ float red[256];
  __shared__ float part[4][64];
  if (tid < 64) qs[tid] = q[(size_t)bn * ADc + h * 64 + tid];
  if (tid < NRc) rwh[tid] = rbfw[tid * Hc + h];
  __syncthreads();
  float sp0 = src_pts[(size_t)bn * 3 + 0];
  float sp1 = src_pts[(size_t)bn * 3 + 1];
  float sp2 = src_pts[(size_t)bn * 3 + 2];
  float sp_sq = sp0 * sp0 + sp1 * sp1 + sp2 * sp2;

  float mx = -1e30f;
  for (int mi = 0; mi < 4; ++mi) {
    int m = mi * 256 + tid;
    const float* kr = k + ((size_t)b * Mmm + m) * ADc + h * 64;
    float dot = 0.f;
    for (int d = 0; d < 64; ++d) dot = fmaf(qs[d], kr[d], dot);
    float tp0 = tgt_pts[((size_t)b * Mmm + m) * 3 + 0];
    float tp1 = tgt_pts[((size_t)b * Mmm + m) * 3 + 1];
    float tp2 = tgt_pts[((size_t)b * Mmm + m) * 3 + 2];
    float d2 = sp_sq + tp0 * tp0 + tp1 * tp1 + tp2 * tp2
             - 2.f * (sp0 * tp0 + sp1 * tp1 + sp2 * tp2);
    float dist = sqrtf(fmaxf(d2, 0.f));
    float bias = 0.f;
    for (int r = 0; r < NRc; ++r) {
      float dd = dist - STEPc * r;
      bias = fmaf(expf(COEFFc * dd * dd), rwh[r], bias);
    }
    float lv = dot * SCALEc + bias;
    lg[m] = lv;
    mx = fmaxf(mx, lv);
  }
  float rmax; BLK_REDUCE_F(fmaxf, mx, rmax);
  float s = 0.f;
  for (int mi = 0; mi < 4; ++mi) {
    int m = mi * 256 + tid;
    float p = expf(lg[m] - rmax);
    lg[m] = p;
    s += p;
  }
  float rsum; BLK_REDUCE_F(addf, s, rsum);
  int d = tid & 63, pt = tid >> 6;
  float a = 0.f;
  for (int mm = 0; mm < 256; ++mm) {
    int m = pt * 256 + mm;
    a = fmaf(lg[m], v[((size_t)b * Mmm + m) * ADc + h * 64 + d], a);
  }
  part[pt][d] = a;
  __syncthreads();
  if (tid < 64)
    ctx[(size_t)bn * ADc + h * 64 + tid] =
        (part[0][tid] + part[1][tid] + part[2][tid] + part[3][tid]) / rsum;
}

// ---------------------------------------------------------------------------
// Sinkhorn row pass (fuses previous colLse subtraction).
// ---------------------------------------------------------------------------
__global__ __launch_bounds__(256) void row_lse_k(float* __restrict__ logS, const float* __restrict__ colLse)
{
  const int tid = threadIdx.x;
  const int bn = blockIdx.x;
  const int b = bn >> 10;
  float* row = logS + (size_t)bn * Mmm;
  const float* cl = colLse ? colLse + (size_t)b * Mmm : nullptr;
  __shared__ float buf[Mmm];
  __shared__ float red[256];
  float lmax = -1e30f;
  for (int j = tid; j < Mmm; j += 256) {
    float v = row[j];
    if (cl) v -= cl[j];
    buf[j] = v;
    lmax = fmaxf(lmax, v);
  }
  float rmax; BLK_REDUCE_F(fmaxf, lmax, rmax);
  float ls = 0.f;
  for (int j = tid; j < Mmm; j += 256) ls += expf(buf[j] - rmax);
  float rsum; BLK_REDUCE_F(addf, ls, rsum);
  float lse = rmax + logf(rsum);
  for (int j = tid; j < Mmm; j += 256) row[j] = buf[j] - lse;
}

// Column LSE: one thread per (b,m), two coalesced passes over rows.
__global__ __launch_bounds__(256) void ncol_lse(
    const float* __restrict__ logS, float* __restrict__ colLse)
{
  int gid = blockIdx.x * 256 + threadIdx.x;   // B*M = 4096
  int b = gid >> 10, m = gid & 1023;
  const float* base = logS + (size_t)b * Nn * Mmm + m;
  float mx = -1e30f;
  for (int n = 0; n < Nn; ++n) mx = fmaxf(mx, base[(size_t)n * Mmm]);
  float sm = 0.f;
  for (int n = 0; n < Nn; ++n) sm += expf(base[(size_t)n * Mmm] - mx);
  colLse[gid] = mx + logf(sm);
}

// ---------------------------------------------------------------------------
// Finalize: S = exp(logS - colLse); fp32 outputs.
// ---------------------------------------------------------------------------
__global__ __launch_bounds__(256) void finalize_k(
    const float* __restrict__ logS, const float* __restrict__ colLse,
    const float* __restrict__ tgt_pts, float* __restrict__ outS, float* __restrict__ outConf,
    float* __restrict__ conf, float* __restrict__ tcp)
{
  const int tid = threadIdx.x;
  const int bn = blockIdx.x;
  const int b = bn >> 10;
  const float* row = logS + (size_t)bn * Mmm;
  const float* cl = colLse + (size_t)b * Mmm;
  const float* tp = tgt_pts + (size_t)b * Mmm * 3;
  __shared__ float red[256];
  float mx = -1e30f, s0 = 0.f, s1 = 0.f, s2 = 0.f;
  for (int m = tid; m < Mmm; m += 256) {
    float sv = expf(row[m] - cl[m]);
    outS[(size_t)bn * Mmm + m] = sv;
    mx = fmaxf(mx, sv);
    s0 = fmaf(sv, tp[m * 3 + 0], s0);
    s1 = fmaf(sv, tp[m * 3 + 1], s1);
    s2 = fmaf(sv, tp[m * 3 + 2], s2);
  }
  float rmx, r0, r1, r2;
  BLK_REDUCE_F(fmaxf, mx, rmx);
  BLK_REDUCE_F(addf, s0, r0);
  BLK_REDUCE_F(addf, s1, r1);
  BLK_REDUCE_F(addf, s2, r2);
  if (tid == 0) {
    conf[bn] = rmx;
    outConf[bn] = rmx;
    tcp[(size_t)bn * 3 + 0] = r0;
    tcp[(size_t)bn * 3 + 1] = r1;
    tcp[(size_t)bn * 3 + 2] = r2;
  }
}

// ---------------------------------------------------------------------------
// Kabsch stage 1: per-batch weighted sums (double)
// ---------------------------------------------------------------------------
__global__ __launch_bounds__(256) void kabsch_red_k(
    const float* __restrict__ conf, const float* __restrict__ src_pts,
    const float* __restrict__ tcp, double* __restrict__ kab)
{
  const int b = blockIdx.x;
  const int tid = threadIdx.x;
  __shared__ double redd[256];
  __shared__ double sh[8];
  const float* cb = conf + (size_t)b * Nn;
  const float* sb = src_pts + (size_t)b * Nn * 3;
  const float* tb = tcp + (size_t)b * Nn * 3;

  double a = 0.0;
  for (int n = tid; n < Nn; n += 256) a += (double)cb[n];
  double wsum; BLK_REDUCE_D(addd, a, wsum);
  double inv = 1.0 / (wsum + 1e-8);

  double c0 = 0, c1 = 0, c2 = 0, t0 = 0, t1 = 0, t2 = 0;
  for (int n = tid; n < Nn; n += 256) {
    double wn = (double)cb[n] * inv;
    c0 += wn * (double)sb[n * 3 + 0];
    c1 += wn * (double)sb[n * 3 + 1];
    c2 += wn * (double)sb[n * 3 + 2];
    t0 += wn * (double)tb[n * 3 + 0];
    t1 += wn * (double)tb[n * 3 + 1];
    t2 += wn * (double)tb[n * 3 + 2];
  }
  double r;
  BLK_REDUCE_D(addd, c0, r); if (tid == 0) sh[0] = r; __syncthreads();
  BLK_REDUCE_D(addd, c1, r); if (tid == 0) sh[1] = r; __syncthreads();
  BLK_REDUCE_D(addd, c2, r); if (tid == 0) sh[2] = r; __syncthreads();
  BLK_REDUCE_D(addd, t0, r); if (tid == 0) sh[3] = r; __syncthreads();
  BLK_REDUCE_D(addd, t1, r); if (tid == 0) sh[4] = r; __syncthreads();
  BLK_REDUCE_D(addd, t2, r); if (tid == 0) sh[5] = r; __syncthreads();
  double cs[3] = {sh[0], sh[1], sh[2]};
  double ct[3] = {sh[3], sh[4], sh[5]};

  double hm[9] = {};
  for (int n = tid; n < Nn; n += 256) {
    double wn = (double)cb[n] * inv;
    double d0 = (double)sb[n * 3 + 0] - cs[0];
    double d1 = (double)sb[n * 3 + 1] - cs[1];
    double d2 = (double)sb[n * 3 + 2] - cs[2];
    double e0 = (double)tb[n * 3 + 0] - ct[0];
    double e1 = (double)tb[n * 3 + 1] - ct[1];
    double e2 = (double)tb[n * 3 + 2] - ct[2];
    hm[0] += wn * d0 * e0; hm[1] += wn * d0 * e1; hm[2] += wn * d0 * e2;
    hm[3] += wn * d1 * e0; hm[4] += wn * d1 * e1; hm[5] += wn * d1 * e2;
    hm[6] += wn * d2 * e0; hm[7] += wn * d2 * e1; hm[8] += wn * d2 * e2;
  }
  for (int i = 0; i < 9; ++i) {
    BLK_REDUCE_D(addd, hm[i], r);
    if (tid == 0) kab[(size_t)b * 16 + i] = r;
    __syncthreads();
  }
  if (tid == 0) {
    for (int i = 0; i < 3; ++i) {
      kab[(size_t)b * 16 + 9 + i]  = cs[i];
      kab[(size_t)b * 16 + 12 + i] = ct[i];
    }
  }
}

// ---------------------------------------------------------------------------
// Kabsch stage 2 — numpy-mirror SVD; fp32 outputs.
// ---------------------------------------------------------------------------
__device__ __forceinline__ double trip(const double a[3], const double b[3], const double c[3]) {
  return a[0] * (b[1] * c[2] - b[2] * c[1])
       - a[1] * (b[0] * c[2] - b[2] * c[0])
       + a[2] * (b[0] * c[1] - b[1] * c[0]);
}

__global__ void kabsch_svd_k(const double* __restrict__ kab, float* __restrict__ outR, float* __restrict__ outT)
{
  const int b = threadIdx.x;
  if (b >= Bn) return;
  const double* kb = kab + (size_t)b * 16;
  double A[3][3], cs[3], ct[3];
  for (int i = 0; i < 3; ++i)
    for (int j = 0; j < 3; ++j) A[i][j] = kb[i * 3 + j];
  for (int i = 0; i < 3; ++i) { cs[i] = kb[9 + i]; ct[i] = kb[12 + i]; }

  double Km[3][3];
  for (int i = 0; i < 3; ++i)
    for (int j = 0; j < 3; ++j)
      Km[i][j] = A[0][i] * A[0][j] + A[1][i] * A[1][j] + A[2][i] * A[2][j];
  double V[3][3] = {{1, 0, 0}, {0, 1, 0}, {0, 0, 1}};
  const int PP[3] = {0, 0, 1}, QQ[3] = {1, 2, 2};
  for (int sweep = 0; sweep < 30; ++sweep) {
    for (int pi = 0; pi < 3; ++pi) {
      int p = PP[pi], qd = QQ[pi];
      double apq = Km[p][qd];
      if (fabs(apq) < 1e-300) continue;
      double theta = (Km[qd][qd] - Km[p][p]) / (2.0 * apq);
      double tt = (theta >= 0 ? 1.0 : -1.0) / (fabs(theta) + sqrt(theta * theta + 1.0));
      double cc = 1.0 / sqrt(tt * tt + 1.0), ss = tt * cc;
      for (int r = 0; r < 3; ++r) {
        double kp = Km[r][p], kq = Km[r][qd];
        Km[r][p] = cc * kp - ss * kq; Km[r][qd] = ss * kp + cc * kq;
      }
      for (int c = 0; c < 3; ++c) {
        double kp = Km[p][c], kq = Km[qd][c];
        Km[p][c] = cc * kp - ss * kq; Km[qd][c] = ss * kp + cc * kq;
      }
      for (int r = 0; r < 3; ++r) {
        double vp = V[r][p], vq = V[r][qd];
        V[r][p] = cc * vp - ss * vq; V[r][qd] = ss * vp + cc * vq;
      }
    }
  }
  double lam[3] = {Km[0][0], Km[1][1], Km[2][2]};
  int i0 = 0, i1 = 1, i2 = 2, tsw;
  if (lam[i0] < lam[i1]) { tsw = i0; i0 = i1; i1 = tsw; }
  if (lam[i0] < lam[i2]) { tsw = i0; i0 = i2; i2 = tsw; }
  if (lam[i1] < lam[i2]) { tsw = i1; i1 = i2; i2 = tsw; }
  double vv[3][3];
  for (int r = 0; r < 3; ++r) { vv[0][r] = V[r][i0]; vv[1][r] = V[r][i1]; vv[2][r] = V[r][i2]; }
  double sg[3] = { sqrt(fmax(lam[i0], 0.0)), sqrt(fmax(lam[i1], 0.0)), sqrt(fmax(lam[i2], 0.0)) };

  double uu[3][3];
  double eps = 1e-12 * (sg[0] > 0 ? sg[0] : 1.0);
  if (sg[0] > eps) {
    for (int r = 0; r < 3; ++r)
      uu[0][r] = (A[r][0] * vv[0][0] + A[r][1] * vv[0][1] + A[r][2] * vv[0][2]) / sg[0];
    double n = sqrt(uu[0][0]*uu[0][0] + uu[0][1]*uu[0][1] + uu[0][2]*uu[0][2]);
    if (n > 1e-14) { uu[0][0]/=n; uu[0][1]/=n; uu[0][2]/=n; }
  } else { uu[0][0]=1; uu[0][1]=0; uu[0][2]=0; }
  if (sg[1] > eps) {
    for (int r = 0; r < 3; ++r)
      uu[1][r] = (A[r][0] * vv[1][0] + A[r][1] * vv[1][1] + A[r][2] * vv[1][2]) / sg[1];
  } else {
    int ax = (fabs(uu[0][0]) <= fabs(uu[0][1]) && fabs(uu[0][0]) <= fabs(uu[0][2])) ? 0
           : (fabs(uu[0][1]) <= fabs(uu[0][2]) ? 1 : 2);
    uu[1][0] = uu[1][1] = uu[1][2] = 0.0; uu[1][ax] = 1.0;
  }
  {
    double pr = uu[0][0]*uu[1][0] + uu[0][1]*uu[1][1] + uu[0][2]*uu[1][2];
    for (int r = 0; r < 3; ++r) uu[1][r] -= pr * uu[0][r];
    double n = sqrt(uu[1][0]*uu[1][0] + uu[1][1]*uu[1][1] + uu[1][2]*uu[1][2]);
    if (n > 1e-14) { uu[1][0]/=n; uu[1][1]/=n; uu[1][2]/=n; }
  }
  if (sg[2] > eps) {
    for (int r = 0; r < 3; ++r)
      uu[2][r] = (A[r][0] * vv[2][0] + A[r][1] * vv[2][1] + A[r][2] * vv[2][2]) / sg[2];
    double p0 = uu[0][0]*uu[2][0] + uu[0][1]*uu[2][1] + uu[0][2]*uu[2][2];
    double p1 = uu[1][0]*uu[2][0] + uu[1][1]*uu[2][1] + uu[1][2]*uu[2][2];
    for (int r = 0; r < 3; ++r) uu[2][r] -= p0 * uu[0][r] + p1 * uu[1][r];
    double n = sqrt(uu[2][0]*uu[2][0] + uu[2][1]*uu[2][1] + uu[2][2]*uu[2][2]);
    if (n > 1e-14) { uu[2][0]/=n; uu[2][1]/=n; uu[2][2]/=n; }
    else {
      uu[2][0] = uu[0][1]*uu[1][2] - uu[0][2]*uu[1][1];
      uu[2][1] = uu[0][2]*uu[1][0] - uu[0][0]*uu[1][2];
      uu[2][2] = uu[0][0]*uu[1][1] - uu[0][1]*uu[1][0];
    }
  } else {
    uu[2][0] = uu[0][1]*uu[1][2] - uu[0][2]*uu[1][1];
    uu[2][1] = uu[0][2]*uu[1][0] - uu[0][0]*uu[1][2];
    uu[2][2] = uu[0][0]*uu[1][1] - uu[0][1]*uu[1][0];
  }

  double detU = trip(uu[0], uu[1], uu[2]);
  double detV = trip(vv[0], vv[1], vv[2]);
  double d = (detU * detV < 0.0) ? -1.0 : 1.0;

  double R[3][3];
  for (int i = 0; i < 3; ++i)
    for (int j = 0; j < 3; ++j)
      R[i][j] = vv[0][i] * uu[0][j] + vv[1][i] * uu[1][j] + d * vv[2][i] * uu[2][j];
  for (int i = 0; i < 3; ++i) {
    double t = ct[i] - (R[i][0] * cs[0] + R[i][1] * cs[1] + R[i][2] * cs[2]);
    outT[(size_t)b * 3 + i] = (float)t;
    for (int j = 0; j < 3; ++j)
      outR[(size_t)b * 9 + i * 3 + j] = (float)R[i][j];
  }
}

// x.max over N
__global__ __launch_bounds__(256) void xmax_k(const float* __restrict__ x, float* __restrict__ xmax)
{
  const int b = blockIdx.x;
  const int d = threadIdx.x;
  float mx = -1e30f;
  for (int n = 0; n < Nn; ++n) mx = fmaxf(mx, x[((size_t)b * Nn + n) * ADc + d]);
  xmax[(size_t)b * ADc + d] = mx;
}

__global__ __launch_bounds__(256) void combined_k(
    const float* __restrict__ gl, const float* __restrict__ tgt_global, float* __restrict__ outC)
{
  int i = blockIdx.x * 256 + threadIdx.x;
  int b = i >> 10, j = i & 1023;
  float v = (j < GFDc) ? gl[(size_t)b * GFDc + j] : tgt_global[(size_t)b * GFDc + (j - GFDc)];
  outC[i] = v;
}

// ---------------------------------------------------------------------------
extern "C" void kernel_launch(void* const* d_in, const int* in_sizes, int n_in,
                              void* d_out, int out_size, void* d_ws, size_t ws_size,
                              hipStream_t stream) {
  (void)in_sizes; (void)n_in; (void)out_size; (void)ws_size;
  const float* src_feats = (const float*)d_in[0];
  const float* tgt_feats = (const float*)d_in[1];
  const float* src_pts   = (const float*)d_in[2];
  const float* tgt_pts   = (const float*)d_in[3];
  const float* tgt_glob  = (const float*)d_in[4];
  const float* sfp_w = (const float*)d_in[5];  const float* sfp_b = (const float*)d_in[6];
  const float* sfp_g = (const float*)d_in[7];  const float* sfp_bb = (const float*)d_in[8];
  const float* tfp_w = (const float*)d_in[9];  const float* tfp_b = (const float*)d_in[10];
  const float* tfp_g = (const float*)d_in[11]; const float* tfp_bb = (const float*)d_in[12];
  const float* rbf_w = (const float*)d_in[13];
  const float* qw = (const float*)d_in[14]; const float* qb = (const float*)d_in[15];
  const float* kw = (const float*)d_in[16]; const float* kb = (const float*)d_in[17];
  const float* vw = (const float*)d_in[18]; const float* vb = (const float*)d_in[19];
  const float* ow = (const float*)d_in[20]; const float* ob = (const float*)d_in[21];
  const float* n1_g = (const float*)d_in[22]; const float* n1_b = (const float*)d_in[23];
  const float* f1_w = (const float*)d_in[24]; const float* f1_b = (const float*)d_in[25];
  const float* f2_w = (const float*)d_in[26]; const float* f2_b = (const float*)d_in[27];
  const float* n2_g = (const float*)d_in[28]; const float* n2_b = (const float*)d_in[29];
  const float* scp_w = (const float*)d_in[30]; const float* scp_b = (const float*)d_in[31];
  const float* tcp_w = (const float*)d_in[32]; const float* tcp_b = (const float*)d_in[33];
  const float* temp  = (const float*)d_in[34];
  const float* gp_w = (const float*)d_in[35]; const float* gp_b = (const float*)d_in[36];
  const float* gp_g = (const float*)d_in[37]; const float* gp_bb = (const float*)d_in[38];

  // Outputs are fp32 (reference computes in jnp.float32).
  float* out = (float*)d_out;
  float* outR    = out;                    // (B,3,3) = 36
  float* outT    = out + 36;               // (B,3)   = 12
  float* outC    = out + 48;               // (B,1024)= 4096
  float* outConf = out + 48 + 4096;        // (B,N)   = 4096
  float* outS    = out + 48 + 4096 + 4096; // (B,N,M) = 4194304

  // overlay workspace, peak ~29.1 MB
  float* ws = (float*)d_ws;
  const size_t M1 = 1048576;
  float* A_   = ws + 0 * M1;     // raw proj / xq / h
  float* B_   = ws + 1 * M1;     // xc / ctx
  float* C_   = ws + 2 * M1;     // q / ffn chunk
  float* D_   = ws + 3 * M1;     // tproj
  float* logS = ws + 0 * M1;     // overlays A..D after they die
  float* E_   = ws + 4 * M1;     // k / src_corr
  float* F_   = ws + 5 * M1;     // v / tgt_corr
  float* G_   = ws + 6 * M1;     // src_proj -> x
  float* tail = ws + 7 * M1;
  float* colLse = tail;                         // 4096
  float* conf   = colLse + 4096;                // 4096
  float* tcp    = conf + 4096;                  // 12288
  float* xmax   = tcp + 12288;                  // 1024
  float* glraw  = xmax + 1024;                  // 2048
  float* gl     = glraw + 2048;                 // 2048
  double* kab   = (double*)(gl + 2048);         // 64 doubles

  const int BN = Bn * Nn;   // 4096

  // 1) projections + LN + ReLU
  ngemm<<<BN * ADc / 256, 256, 0, stream>>>(src_feats, sfp_w, sfp_b, nullptr, A_, BN, PFDc, ADc, 0);
  ln_k<<<BN, 256, 0, stream>>>(A_, sfp_g, sfp_bb, G_, ADc, 1);
  ngemm<<<BN * ADc / 256, 256, 0, stream>>>(tgt_feats, tfp_w, tfp_b, nullptr, A_, BN, PFDc, ADc, 0);
  ln_k<<<BN, 256, 0, stream>>>(A_, tfp_g, tfp_bb, D_, ADc, 1);

  // 2) pre-LN + q/k/v
  ln_k<<<BN, 256, 0, stream>>>(G_, n1_g, n1_b, A_, ADc, 0);
  ngemm<<<BN * ADc / 256, 256, 0, stream>>>(A_, qw, qb, nullptr, C_, BN, ADc, ADc, 0);
  ln_k<<<BN, 256, 0, stream>>>(D_, n1_g, n1_b, B_, ADc, 0);
  ngemm<<<BN * ADc / 256, 256, 0, stream>>>(B_, kw, kb, nullptr, E_, BN, ADc, ADc, 0);
  ngemm<<<BN * ADc / 256, 256, 0, stream>>>(B_, vw, vb, nullptr, F_, BN, ADc, ADc, 0);

  // 3) attention -> ctx (B_), out-proj + residual -> G_
  nattn<<<BN * Hc, 256, 0, stream>>>(C_, E_, F_, src_pts, tgt_pts, rbf_w, B_);
  ngemm<<<BN * ADc / 256, 256, 0, stream>>>(B_, ow, ob, G_, G_, BN, ADc, ADc, 0);

  // 4) FFN, hidden chunked through C_
  ln_k<<<BN, 256, 0, stream>>>(G_, n2_g, n2_b, A_, ADc, 0);
  for (int c = 0; c < 4; ++c) {
    const float* hA = A_ + (size_t)c * 1024 * ADc;
    float* xA = G_ + (size_t)c * 1024 * ADc;
    ngemm<<<1024 * 1024 / 256, 256, 0, stream>>>(hA, f1_w, f1_b, nullptr, C_, 1024, ADc, 1024, 1);
    ngemm<<<1024 * ADc / 256, 256, 0, stream>>>(C_, f2_w, f2_b, xA, xA, 1024, 1024, ADc, 0);
  }

  // 5) correspondences + Sinkhorn
  ngemm<<<BN * ADc / 256, 256, 0, stream>>>(G_, scp_w, scp_b, nullptr, E_, BN, ADc, ADc, 0);
  ngemm<<<BN * ADc / 256, 256, 0, stream>>>(D_, tcp_w, tcp_b, nullptr, F_, BN, ADc, ADc, 0);
  ngemm_nt<<<Bn * Nn * Mmm / 256, 256, 0, stream>>>(E_, F_, logS, temp);

  for (int it = 0; it < 3; ++it) {
    row_lse_k<<<BN, 256, 0, stream>>>(logS, it == 0 ? nullptr : colLse);
    ncol_lse<<<Bn * Mmm / 256, 256, 0, stream>>>(logS, colLse);
  }
  finalize_k<<<BN, 256, 0, stream>>>(logS, colLse, tgt_pts, outS, outConf, conf, tcp);

  // 6) Kabsch
  kabsch_red_k<<<Bn, 256, 0, stream>>>(conf, src_pts, tcp, kab);
  kabsch_svd_k<<<1, 64, 0, stream>>>(kab, outR, outT);

  // 7) global pooling head
  xmax_k<<<Bn, 256, 0, stream>>>(G_, xmax);
  ngemm<<<Bn * GFDc / 256, 256, 0, stream>>>(xmax, gp_w, gp_b, nullptr, glraw, Bn, ADc, GFDc, 0);
  ln_k<<<Bn, 256, 0, stream>>>(glraw, gp_g, gp_bb, gl, GFDc, 1);
  combined_k<<<(Bn * 2 * GFDc) / 256, 256, 0, stream>>>(gl, tgt_glob, outC);
}

// Round 7
// 3603.045 us; speedup vs baseline: 1.3324x; 1.3324x over previous
//
#include <hip/hip_runtime.h>
#include <hip/hip_bf16.h>
#include <math.h>

constexpr int Bn  = 4;
constexpr int Nn  = 1024;
constexpr int Mmm = 1024;
constexpr int PFDc = 1024;
constexpr int ADc  = 256;
constexpr int GFDc = 512;
constexpr int Hc   = 4;
constexpr int NRc  = 16;
constexpr float COEFFc = -28.125f;    // -0.5/(CUT/(NR-1))^2
constexpr float SCALEc = 0.125f;      // DH^-0.5
constexpr float STEPc  = 2.0f / 15.0f;

__device__ __forceinline__ float addf(float a, float b) { return a + b; }
__device__ __forceinline__ double addd(double a, double b) { return a + b; }

#define BLK_REDUCE_F(OP, VAR, RES) \
  red[tid] = (VAR); __syncthreads(); \
  for (int st_ = 128; st_ > 0; st_ >>= 1) { if (tid < st_) red[tid] = OP(red[tid], red[tid + st_]); __syncthreads(); } \
  (RES) = red[0]; __syncthreads();

#define BLK_REDUCE_D(OP, VAR, RES) \
  redd[tid] = (VAR); __syncthreads(); \
  for (int st_ = 128; st_ > 0; st_ >>= 1) { if (tid < st_) redd[tid] = OP(redd[tid], redd[tid + st_]); __syncthreads(); } \
  (RES) = redd[0]; __syncthreads();

// ---------------------------------------------------------------------------
// Tiled GEMM: C[r][c] = sum_k A[r,k]W[k,c]+bias (+addsrc) (+gelu).
// 64x64 tile, BK=16, 4x4 per thread, all fp32.
// ---------------------------------------------------------------------------
__global__ __launch_bounds__(256) void gemm_k(
    const float* __restrict__ A, const float* __restrict__ W, const float* __restrict__ bias,
    const float* __restrict__ addsrc, float* __restrict__ C,
    int R, int K, int Cc, int act)
{
  __shared__ __align__(16) float As[16][68];   // [k][row]
  __shared__ __align__(16) float Ws[16][68];   // [k][col]
  const int tid = threadIdx.x;
  const int tx = tid & 15, ty = tid >> 4;
  const int r0 = blockIdx.y * 64, c0 = blockIdx.x * 64;
  float acc[4][4] = {};
  for (int k0 = 0; k0 < K; k0 += 16) {
    #pragma unroll
    for (int j = 0; j < 4; ++j) {
      int e = tid + j * 256;
      int ar = e >> 4, ak = e & 15;
      int gr = r0 + ar;
      As[ak][ar] = (gr < R) ? A[(size_t)gr * K + k0 + ak] : 0.f;
    }
    #pragma unroll
    for (int j = 0; j < 4; ++j) {
      int e = tid + j * 256;
      int wk = e >> 6, wc = e & 63;
      int gc = c0 + wc;
      Ws[wk][wc] = (gc < Cc) ? W[(size_t)(k0 + wk) * Cc + gc] : 0.f;
    }
    __syncthreads();
    #pragma unroll
    for (int kk = 0; kk < 16; ++kk) {
      float4 av = *(const float4*)&As[kk][ty * 4];
      float4 wv = *(const float4*)&Ws[kk][tx * 4];
      float a[4] = {av.x, av.y, av.z, av.w};
      float w[4] = {wv.x, wv.y, wv.z, wv.w};
      #pragma unroll
      for (int i = 0; i < 4; ++i)
        #pragma unroll
        for (int j = 0; j < 4; ++j)
          acc[i][j] = fmaf(a[i], w[j], acc[i][j]);
    }
    __syncthreads();
  }
  #pragma unroll
  for (int i = 0; i < 4; ++i) {
    int r = r0 + ty * 4 + i;
    if (r >= R) continue;
    #pragma unroll
    for (int j = 0; j < 4; ++j) {
      int c = c0 + tx * 4 + j;
      if (c >= Cc) continue;
      float v = acc[i][j] + bias[c];
      if (addsrc) v += addsrc[(size_t)r * Cc + c];
      if (act == 1) v = 0.5f * v * (1.f + erff(v * 0.70710678118654752f));
      C[(size_t)r * Cc + c] = v;
    }
  }
}

// Batched NT GEMM: logS[b][n][m] = (1/tau) * sum_k A[b,n,k]*Bm[b,m,k]
__global__ __launch_bounds__(256) void gemm_nt_k(
    const float* __restrict__ A, const float* __restrict__ Bm, float* __restrict__ C,
    const float* __restrict__ temp)
{
  const int K = ADc;
  __shared__ __align__(16) float As[16][68];
  __shared__ __align__(16) float Bs[16][68];
  const int tid = threadIdx.x;
  const int tx = tid & 15, ty = tid >> 4;
  const int b = blockIdx.z;
  const int r0 = blockIdx.y * 64, c0 = blockIdx.x * 64;
  const float* Ab = A + (size_t)b * Nn * K;
  const float* Bb = Bm + (size_t)b * Mmm * K;
  float* Cb = C + (size_t)b * Nn * Mmm;
  float tau = fminf(fmaxf(temp[0], 0.01f), 1.0f);
  float inv_tau = 1.f / tau;
  float acc[4][4] = {};
  for (int k0 = 0; k0 < K; k0 += 16) {
    #pragma unroll
    for (int j = 0; j < 4; ++j) {
      int e = tid + j * 256;
      int ar = e >> 4, ak = e & 15;
      As[ak][ar] = Ab[(size_t)(r0 + ar) * K + k0 + ak];
      Bs[ak][ar] = Bb[(size_t)(c0 + ar) * K + k0 + ak];
    }
    __syncthreads();
    #pragma unroll
    for (int kk = 0; kk < 16; ++kk) {
      float4 av = *(const float4*)&As[kk][ty * 4];
      float4 bv = *(const float4*)&Bs[kk][tx * 4];
      float a[4] = {av.x, av.y, av.z, av.w};
      float w[4] = {bv.x, bv.y, bv.z, bv.w};
      #pragma unroll
      for (int i = 0; i < 4; ++i)
        #pragma unroll
        for (int j = 0; j < 4; ++j)
          acc[i][j] = fmaf(a[i], w[j], acc[i][j]);
    }
    __syncthreads();
  }
  #pragma unroll
  for (int i = 0; i < 4; ++i) {
    int r = r0 + ty * 4 + i;
    #pragma unroll
    for (int j = 0; j < 4; ++j) {
      int c = c0 + tx * 4 + j;
      Cb[(size_t)r * Mmm + c] = acc[i][j] * inv_tau;
    }
  }
}

// ---------------------------------------------------------------------------
// LayerNorm (+ optional ReLU): one block per row
// ---------------------------------------------------------------------------
__global__ __launch_bounds__(256) void ln_k(
    const float* __restrict__ in, const float* __restrict__ g, const float* __restrict__ bb,
    float* __restrict__ out, int Cc, int relu)
{
  const int tid = threadIdx.x;
  const int row = blockIdx.x;
  const float* x = in + (size_t)row * Cc;
  float* o = out + (size_t)row * Cc;
  __shared__ float red[256];
  float s = 0.f;
  for (int j = tid; j < Cc; j += 256) s += x[j];
  float tot; BLK_REDUCE_F(addf, s, tot);
  float mu = tot / Cc;
  float s2 = 0.f;
  for (int j = tid; j < Cc; j += 256) { float d = x[j] - mu; s2 += d * d; }
  float tot2; BLK_REDUCE_F(addf, s2, tot2);
  float inv = 1.f / sqrtf(tot2 / Cc + 1e-5f);
  for (int j = tid; j < Cc; j += 256) {
    float v = (x[j] - mu) * inv * g[j] + bb[j];
    if (relu) v = fmaxf(v, 0.f);
    o[j] = v;
  }
}

// ---------------------------------------------------------------------------
// K transpose: k[b][m][h*64+d] -> Kt[(b*4+h)][d][m]  (64x64 LDS tiles)
// grid: (B*H, M/64)
// ---------------------------------------------------------------------------
__global__ __launch_bounds__(256) void ktrans_k(
    const float* __restrict__ k, float* __restrict__ Kt)
{
  __shared__ float t[64][65];
  const int tid = threadIdx.x;
  const int bh = blockIdx.x;          // b*4+h
  const int b = bh >> 2, h = bh & 3;
  const int m0 = blockIdx.y * 64;
  const int col = tid & 63;
  const int rbase = tid >> 6;         // 0..3
  #pragma unroll
  for (int rr = 0; rr < 64; rr += 4) {
    int row = rr + rbase;             // m-local
    t[row][col] = k[((size_t)b * Mmm + m0 + row) * ADc + h * 64 + col];
  }
  __syncthreads();
  #pragma unroll
  for (int rr = 0; rr < 64; rr += 4) {
    int row = rr + rbase;             // d
    Kt[((size_t)bh * 64 + row) * Mmm + m0 + col] = t[col][row];
  }
}

// ---------------------------------------------------------------------------
// Flash cross-attention, coalesced: one block per (b,n); wave = head.
// QK dot reads Kt[d][m] (lane=m -> coalesced); PV reads v[m][h*64+d]
// (lane=d -> coalesced). tgt_pts staged in LDS. Online softmax via shuffles.
// ---------------------------------------------------------------------------
__global__ __launch_bounds__(256) void attn2_k(
    const float* __restrict__ q, const float* __restrict__ Kt, const float* __restrict__ v,
    const float* __restrict__ src_pts, const float* __restrict__ tgt_pts,
    const float* __restrict__ rbfw, float* __restrict__ ctx)
{
  const int tid = threadIdx.x;
  const int bn = blockIdx.x;
  const int b = bn >> 10;
  const int h = tid >> 6, lane = tid & 63;
  __shared__ float qs[256];
  __shared__ float rw[64];
  __shared__ float tp[Mmm * 3];       // 12 KB
  qs[tid] = q[(size_t)bn * ADc + tid];
  if (tid < 64) rw[tid] = rbfw[tid];
  for (int i = tid; i < Mmm * 3; i += 256) tp[i] = tgt_pts[(size_t)b * Mmm * 3 + i];
  __syncthreads();
  float sp0 = src_pts[(size_t)bn * 3 + 0];
  float sp1 = src_pts[(size_t)bn * 3 + 1];
  float sp2 = src_pts[(size_t)bn * 3 + 2];
  float sp_sq = sp0 * sp0 + sp1 * sp1 + sp2 * sp2;
  const float* Ktb = Kt + ((size_t)(b * Hc + h)) * 64 * Mmm;   // [d][m]
  const float* vb  = v + (size_t)b * Mmm * ADc;

  float m_run = -1e30f, l_run = 0.f, acc = 0.f;
  for (int t = 0; t < Mmm / 64; ++t) {
    int m = t * 64 + lane;
    float dot = 0.f;
    #pragma unroll
    for (int d = 0; d < 64; ++d)
      dot = fmaf(qs[h * 64 + d], Ktb[(size_t)d * Mmm + m], dot);
    float tp0 = tp[m * 3 + 0], tp1 = tp[m * 3 + 1], tp2 = tp[m * 3 + 2];
    float d2 = sp_sq + tp0 * tp0 + tp1 * tp1 + tp2 * tp2
             - 2.f * (sp0 * tp0 + sp1 * tp1 + sp2 * tp2);
    float dist = sqrtf(fmaxf(d2, 0.f));
    float bias = 0.f;
    #pragma unroll
    for (int r = 0; r < NRc; ++r) {
      float dd = dist - STEPc * r;
      bias = fmaf(expf(COEFFc * dd * dd), rw[r * Hc + h], bias);
    }
    float logit = dot * SCALEc + bias;
    float tmax = logit;
    #pragma unroll
    for (int off = 32; off > 0; off >>= 1) tmax = fmaxf(tmax, __shfl_xor(tmax, off, 64));
    float m_new = fmaxf(m_run, tmax);
    float p = expf(logit - m_new);
    float alpha = expf(m_run - m_new);
    float psum = p;
    #pragma unroll
    for (int off = 32; off > 0; off >>= 1) psum += __shfl_xor(psum, off, 64);
    l_run = l_run * alpha + psum;
    float acc_n = acc * alpha;
    const float* vrow = vb + (size_t)(t * 64) * ADc + h * 64 + lane;
    #pragma unroll
    for (int j = 0; j < 64; ++j) {
      float pj = __shfl(p, j, 64);
      acc_n = fmaf(pj, vrow[(size_t)j * ADc], acc_n);
    }
    acc = acc_n;
    m_run = m_new;
  }
  ctx[(size_t)bn * ADc + h * 64 + lane] = acc / l_run;
}

// ---------------------------------------------------------------------------
// Sinkhorn row pass (fuses previous colLse subtraction).
// ---------------------------------------------------------------------------
__global__ __launch_bounds__(256) void row_lse_k(float* __restrict__ logS, const float* __restrict__ colLse)
{
  const int tid = threadIdx.x;
  const int bn = blockIdx.x;
  const int b = bn >> 10;
  float* row = logS + (size_t)bn * Mmm;
  const float* cl = colLse ? colLse + (size_t)b * Mmm : nullptr;
  __shared__ float buf[Mmm];
  __shared__ float red[256];
  float lmax = -1e30f;
  for (int j = tid; j < Mmm; j += 256) {
    float v = row[j];
    if (cl) v -= cl[j];
    buf[j] = v;
    lmax = fmaxf(lmax, v);
  }
  float rmax; BLK_REDUCE_F(fmaxf, lmax, rmax);
  float ls = 0.f;
  for (int j = tid; j < Mmm; j += 256) ls += expf(buf[j] - rmax);
  float rsum; BLK_REDUCE_F(addf, ls, rsum);
  float lse = rmax + logf(rsum);
  for (int j = tid; j < Mmm; j += 256) row[j] = buf[j] - lse;
}

// Column LSE: one thread per (b,m), two coalesced passes over rows.
__global__ __launch_bounds__(256) void ncol_lse(
    const float* __restrict__ logS, float* __restrict__ colLse)
{
  int gid = blockIdx.x * 256 + threadIdx.x;   // B*M = 4096
  int b = gid >> 10, m = gid & 1023;
  const float* base = logS + (size_t)b * Nn * Mmm + m;
  float mx = -1e30f;
  for (int n = 0; n < Nn; ++n) mx = fmaxf(mx, base[(size_t)n * Mmm]);
  float sm = 0.f;
  for (int n = 0; n < Nn; ++n) sm += expf(base[(size_t)n * Mmm] - mx);
  colLse[gid] = mx + logf(sm);
}

// ---------------------------------------------------------------------------
// Finalize: S = exp(logS - colLse); fp32 outputs.
// ---------------------------------------------------------------------------
__global__ __launch_bounds__(256) void finalize_k(
    const float* __restrict__ logS, const float* __restrict__ colLse,
    const float* __restrict__ tgt_pts, float* __restrict__ outS, float* __restrict__ outConf,
    float* __restrict__ conf, float* __restrict__ tcp)
{
  const int tid = threadIdx.x;
  const int bn = blockIdx.x;
  const int b = bn >> 10;
  const float* row = logS + (size_t)bn * Mmm;
  const float* cl = colLse + (size_t)b * Mmm;
  const float* tp = tgt_pts + (size_t)b * Mmm * 3;
  __shared__ float red[256];
  float mx = -1e30f, s0 = 0.f, s1 = 0.f, s2 = 0.f;
  for (int m = tid; m < Mmm; m += 256) {
    float sv = expf(row[m] - cl[m]);
    outS[(size_t)bn * Mmm + m] = sv;
    mx = fmaxf(mx, sv);
    s0 = fmaf(sv, tp[m * 3 + 0], s0);
    s1 = fmaf(sv, tp[m * 3 + 1], s1);
    s2 = fmaf(sv, tp[m * 3 + 2], s2);
  }
  float rmx, r0, r1, r2;
  BLK_REDUCE_F(fmaxf, mx, rmx);
  BLK_REDUCE_F(addf, s0, r0);
  BLK_REDUCE_F(addf, s1, r1);
  BLK_REDUCE_F(addf, s2, r2);
  if (tid == 0) {
    conf[bn] = rmx;
    outConf[bn] = rmx;
    tcp[(size_t)bn * 3 + 0] = r0;
    tcp[(size_t)bn * 3 + 1] = r1;
    tcp[(size_t)bn * 3 + 2] = r2;
  }
}

// ---------------------------------------------------------------------------
// Kabsch stage 1: per-batch weighted sums (double)
// ---------------------------------------------------------------------------
__global__ __launch_bounds__(256) void kabsch_red_k(
    const float* __restrict__ conf, const float* __restrict__ src_pts,
    const float* __restrict__ tcp, double* __restrict__ kab)
{
  const int b = blockIdx.x;
  const int tid = threadIdx.x;
  __shared__ double redd[256];
  __shared__ double sh[8];
  const float* cb = conf + (size_t)b * Nn;
  const float* sb = src_pts + (size_t)b * Nn * 3;
  const float* tb = tcp + (size_t)b * Nn * 3;

  double a = 0.0;
  for (int n = tid; n < Nn; n += 256) a += (double)cb[n];
  double wsum; BLK_REDUCE_D(addd, a, wsum);
  double inv = 1.0 / (wsum + 1e-8);

  double c0 = 0, c1 = 0, c2 = 0, t0 = 0, t1 = 0, t2 = 0;
  for (int n = tid; n < Nn; n += 256) {
    double wn = (double)cb[n] * inv;
    c0 += wn * (double)sb[n * 3 + 0];
    c1 += wn * (double)sb[n * 3 + 1];
    c2 += wn * (double)sb[n * 3 + 2];
    t0 += wn * (double)tb[n * 3 + 0];
    t1 += wn * (double)tb[n * 3 + 1];
    t2 += wn * (double)tb[n * 3 + 2];
  }
  double r;
  BLK_REDUCE_D(addd, c0, r); if (tid == 0) sh[0] = r; __syncthreads();
  BLK_REDUCE_D(addd, c1, r); if (tid == 0) sh[1] = r; __syncthreads();
  BLK_REDUCE_D(addd, c2, r); if (tid == 0) sh[2] = r; __syncthreads();
  BLK_REDUCE_D(addd, t0, r); if (tid == 0) sh[3] = r; __syncthreads();
  BLK_REDUCE_D(addd, t1, r); if (tid == 0) sh[4] = r; __syncthreads();
  BLK_REDUCE_D(addd, t2, r); if (tid == 0) sh[5] = r; __syncthreads();
  double cs[3] = {sh[0], sh[1], sh[2]};
  double ct[3] = {sh[3], sh[4], sh[5]};

  double hm[9] = {};
  for (int n = tid; n < Nn; n += 256) {
    double wn = (double)cb[n] * inv;
    double d0 = (double)sb[n * 3 + 0] - cs[0];
    double d1 = (double)sb[n * 3 + 1] - cs[1];
    double d2 = (double)sb[n * 3 + 2] - cs[2];
    double e0 = (double)tb[n * 3 + 0] - ct[0];
    double e1 = (double)tb[n * 3 + 1] - ct[1];
    double e2 = (double)tb[n * 3 + 2] - ct[2];
    hm[0] += wn * d0 * e0; hm[1] += wn * d0 * e1; hm[2] += wn * d0 * e2;
    hm[3] += wn * d1 * e0; hm[4] += wn * d1 * e1; hm[5] += wn * d1 * e2;
    hm[6] += wn * d2 * e0; hm[7] += wn * d2 * e1; hm[8] += wn * d2 * e2;
  }
  for (int i = 0; i < 9; ++i) {
    BLK_REDUCE_D(addd, hm[i], r);
    if (tid == 0) kab[(size_t)b * 16 + i] = r;
    __syncthreads();
  }
  if (tid == 0) {
    for (int i = 0; i < 3; ++i) {
      kab[(size_t)b * 16 + 9 + i]  = cs[i];
      kab[(size_t)b * 16 + 12 + i] = ct[i];
    }
  }
}

// ---------------------------------------------------------------------------
// Kabsch stage 2 — numpy-mirror SVD; fp32 outputs.
// ---------------------------------------------------------------------------
__device__ __forceinline__ double trip(const double a[3], const double b[3], const double c[3]) {
  return a[0] * (b[1] * c[2] - b[2] * c[1])
       - a[1] * (b[0] * c[2] - b[2] * c[0])
       + a[2] * (b[0] * c[1] - b[1] * c[0]);
}

__global__ void kabsch_svd_k(const double* __restrict__ kab, float* __restrict__ outR, float* __restrict__ outT)
{
  const int b = threadIdx.x;
  if (b >= Bn) return;
  const double* kb = kab + (size_t)b * 16;
  double A[3][3], cs[3], ct[3];
  for (int i = 0; i < 3; ++i)
    for (int j = 0; j < 3; ++j) A[i][j] = kb[i * 3 + j];
  for (int i = 0; i < 3; ++i) { cs[i] = kb[9 + i]; ct[i] = kb[12 + i]; }

  double Km[3][3];
  for (int i = 0; i < 3; ++i)
    for (int j = 0; j < 3; ++j)
      Km[i][j] = A[0][i] * A[0][j] + A[1][i] * A[1][j] + A[2][i] * A[2][j];
  double V[3][3] = {{1, 0, 0}, {0, 1, 0}, {0, 0, 1}};
  const int PP[3] = {0, 0, 1}, QQ[3] = {1, 2, 2};
  for (int sweep = 0; sweep < 30; ++sweep) {
    for (int pi = 0; pi < 3; ++pi) {
      int p = PP[pi], qd = QQ[pi];
      double apq = Km[p][qd];
      if (fabs(apq) < 1e-300) continue;
      double theta = (Km[qd][qd] - Km[p][p]) / (2.0 * apq);
      double tt = (theta >= 0 ? 1.0 : -1.0) / (fabs(theta) + sqrt(theta * theta + 1.0));
      double cc = 1.0 / sqrt(tt * tt + 1.0), ss = tt * cc;
      for (int r = 0; r < 3; ++r) {
        double kp = Km[r][p], kq = Km[r][qd];
        Km[r][p] = cc * kp - ss * kq; Km[r][qd] = ss * kp + cc * kq;
      }
      for (int c = 0; c < 3; ++c) {
        double kp = Km[p][c], kq = Km[qd][c];
        Km[p][c] = cc * kp - ss * kq; Km[qd][c] = ss * kp + cc * kq;
      }
      for (int r = 0; r < 3; ++r) {
        double vp = V[r][p], vq = V[r][qd];
        V[r][p] = cc * vp - ss * vq; V[r][qd] = ss * vp + cc * vq;
      }
    }
  }
  double lam[3] = {Km[0][0], Km[1][1], Km[2][2]};
  int i0 = 0, i1 = 1, i2 = 2, tsw;
  if (lam[i0] < lam[i1]) { tsw = i0; i0 = i1; i1 = tsw; }
  if (lam[i0] < lam[i2]) { tsw = i0; i0 = i2; i2 = tsw; }
  if (lam[i1] < lam[i2]) { tsw = i1; i1 = i2; i2 = tsw; }
  double vv[3][3];
  for (int r = 0; r < 3; ++r) { vv[0][r] = V[r][i0]; vv[1][r] = V[r][i1]; vv[2][r] = V[r][i2]; }
  double sg[3] = { sqrt(fmax(lam[i0], 0.0)), sqrt(fmax(lam[i1], 0.0)), sqrt(fmax(lam[i2], 0.0)) };

  double uu[3][3];
  double eps = 1e-12 * (sg[0] > 0 ? sg[0] : 1.0);
  if (sg[0] > eps) {
    for (int r = 0; r < 3; ++r)
      uu[0][r] = (A[r][0] * vv[0][0] + A[r][1] * vv[0][1] + A[r][2] * vv[0][2]) / sg[0];
    double n = sqrt(uu[0][0]*uu[0][0] + uu[0][1]*uu[0][1] + uu[0][2]*uu[0][2]);
    if (n > 1e-14) { uu[0][0]/=n; uu[0][1]/=n; uu[0][2]/=n; }
  } else { uu[0][0]=1; uu[0][1]=0; uu[0][2]=0; }
  if (sg[1] > eps) {
    for (int r = 0; r < 3; ++r)
      uu[1][r] = (A[r][0] * vv[1][0] + A[r][1] * vv[1][1] + A[r][2] * vv[1][2]) / sg[1];
  } else {
    int ax = (fabs(uu[0][0]) <= fabs(uu[0][1]) && fabs(uu[0][0]) <= fabs(uu[0][2])) ? 0
           : (fabs(uu[0][1]) <= fabs(uu[0][2]) ? 1 : 2);
    uu[1][0] = uu[1][1] = uu[1][2] = 0.0; uu[1][ax] = 1.0;
  }
  {
    double pr = uu[0][0]*uu[1][0] + uu[0][1]*uu[1][1] + uu[0][2]*uu[1][2];
    for (int r = 0; r < 3; ++r) uu[1][r] -= pr * uu[0][r];
    double n = sqrt(uu[1][0]*uu[1][0] + uu[1][1]*uu[1][1] + uu[1][2]*uu[1][2]);
    if (n > 1e-14) { uu[1][0]/=n; uu[1][1]/=n; uu[1][2]/=n; }
  }
  if (sg[2] > eps) {
    for (int r = 0; r < 3; ++r)
      uu[2][r] = (A[r][0] * vv[2][0] + A[r][1] * vv[2][1] + A[r][2] * vv[2][2]) / sg[2];
    double p0 = uu[0][0]*uu[2][0] + uu[0][1]*uu[2][1] + uu[0][2]*uu[2][2];
    double p1 = uu[1][0]*uu[2][0] + uu[1][1]*uu[2][1] + uu[1][2]*uu[2][2];
    for (int r = 0; r < 3; ++r) uu[2][r] -= p0 * uu[0][r] + p1 * uu[1][r];
    double n = sqrt(uu[2][0]*uu[2][0] + uu[2][1]*uu[2][1] + uu[2][2]*uu[2][2]);
    if (n > 1e-14) { uu[2][0]/=n; uu[2][1]/=n; uu[2][2]/=n; }
    else {
      uu[2][0] = uu[0][1]*uu[1][2] - uu[0][2]*uu[1][1];
      uu[2][1] = uu[0][2]*uu[1][0] - uu[0][0]*uu[1][2];
      uu[2][2] = uu[0][0]*uu[1][1] - uu[0][1]*uu[1][0];
    }
  } else {
    uu[2][0] = uu[0][1]*uu[1][2] - uu[0][2]*uu[1][1];
    uu[2][1] = uu[0][2]*uu[1][0] - uu[0][0]*uu[1][2];
    uu[2][2] = uu[0][0]*uu[1][1] - uu[0][1]*uu[1][0];
  }

  double detU = trip(uu[0], uu[1], uu[2]);
  double detV = trip(vv[0], vv[1], vv[2]);
  double d = (detU * detV < 0.0) ? -1.0 : 1.0;

  double R[3][3];
  for (int i = 0; i < 3; ++i)
    for (int j = 0; j < 3; ++j)
      R[i][j] = vv[0][i] * uu[0][j] + vv[1][i] * uu[1][j] + d * vv[2][i] * uu[2][j];
  for (int i = 0; i < 3; ++i) {
    double t = ct[i] - (R[i][0] * cs[0] + R[i][1] * cs[1] + R[i][2] * cs[2]);
    outT[(size_t)b * 3 + i] = (float)t;
    for (int j = 0; j < 3; ++j)
      outR[(size_t)b * 9 + i * 3 + j] = (float)R[i][j];
  }
}

// x.max over N
__global__ __launch_bounds__(256) void xmax_k(const float* __restrict__ x, float* __restrict__ xmax)
{
  const int b = blockIdx.x;
  const int d = threadIdx.x;
  float mx = -1e30f;
  for (int n = 0; n < Nn; ++n) mx = fmaxf(mx, x[((size_t)b * Nn + n) * ADc + d]);
  xmax[(size_t)b * ADc + d] = mx;
}

__global__ __launch_bounds__(256) void combined_k(
    const float* __restrict__ gl, const float* __restrict__ tgt_global, float* __restrict__ outC)
{
  int i = blockIdx.x * 256 + threadIdx.x;
  int b = i >> 10, j = i & 1023;
  float v = (j < GFDc) ? gl[(size_t)b * GFDc + j] : tgt_global[(size_t)b * GFDc + (j - GFDc)];
  outC[i] = v;
}

// ---------------------------------------------------------------------------
extern "C" void kernel_launch(void* const* d_in, const int* in_sizes, int n_in,
                              void* d_out, int out_size, void* d_ws, size_t ws_size,
                              hipStream_t stream) {
  (void)in_sizes; (void)n_in; (void)out_size; (void)ws_size;
  const float* src_feats = (const float*)d_in[0];
  const float* tgt_feats = (const float*)d_in[1];
  const float* src_pts   = (const float*)d_in[2];
  const float* tgt_pts   = (const float*)d_in[3];
  const float* tgt_glob  = (const float*)d_in[4];
  const float* sfp_w = (const float*)d_in[5];  const float* sfp_b = (const float*)d_in[6];
  const float* sfp_g = (const float*)d_in[7];  const float* sfp_bb = (const float*)d_in[8];
  const float* tfp_w = (const float*)d_in[9];  const float* tfp_b = (const float*)d_in[10];
  const float* tfp_g = (const float*)d_in[11]; const float* tfp_bb = (const float*)d_in[12];
  const float* rbf_w = (const float*)d_in[13];
  const float* qw = (const float*)d_in[14]; const float* qb = (const float*)d_in[15];
  const float* kw = (const float*)d_in[16]; const float* kb = (const float*)d_in[17];
  const float* vw = (const float*)d_in[18]; const float* vb = (const float*)d_in[19];
  const float* ow = (const float*)d_in[20]; const float* ob = (const float*)d_in[21];
  const float* n1_g = (const float*)d_in[22]; const float* n1_b = (const float*)d_in[23];
  const float* f1_w = (const float*)d_in[24]; const float* f1_b = (const float*)d_in[25];
  const float* f2_w = (const float*)d_in[26]; const float* f2_b = (const float*)d_in[27];
  const float* n2_g = (const float*)d_in[28]; const float* n2_b = (const float*)d_in[29];
  const float* scp_w = (const float*)d_in[30]; const float* scp_b = (const float*)d_in[31];
  const float* tcp_w = (const float*)d_in[32]; const float* tcp_b = (const float*)d_in[33];
  const float* temp  = (const float*)d_in[34];
  const float* gp_w = (const float*)d_in[35]; const float* gp_b = (const float*)d_in[36];
  const float* gp_g = (const float*)d_in[37]; const float* gp_bb = (const float*)d_in[38];

  float* out = (float*)d_out;
  float* outR    = out;                    // (B,3,3)
  float* outT    = out + 36;               // (B,3)
  float* outC    = out + 48;               // (B,1024)
  float* outConf = out + 48 + 4096;        // (B,N)
  float* outS    = out + 48 + 4096 + 4096; // (B,N,M)

  // overlay workspace, peak ~29.1 MB (validated)
  float* ws = (float*)d_ws;
  const size_t M1 = 1048576;
  float* A_   = ws + 0 * M1;     // raw proj / xq / Kt / h
  float* B_   = ws + 1 * M1;     // xc / ctx
  float* C_   = ws + 2 * M1;     // q / ffn chunk
  float* D_   = ws + 3 * M1;     // tproj
  float* logS = ws + 0 * M1;     // overlays A..D after they die
  float* E_   = ws + 4 * M1;     // k / src_corr
  float* F_   = ws + 5 * M1;     // v / tgt_corr
  float* G_   = ws + 6 * M1;     // src_proj -> x
  float* tail = ws + 7 * M1;
  float* colLse = tail;                         // 4096
  float* conf   = colLse + 4096;                // 4096
  float* tcp    = conf + 4096;                  // 12288
  float* xmax   = tcp + 12288;                  // 1024
  float* glraw  = xmax + 1024;                  // 2048
  float* gl     = glraw + 2048;                 // 2048
  double* kab   = (double*)(gl + 2048);         // 64 doubles

  const int BN = Bn * Nn;   // 4096

  // 1) projections + LN + ReLU
  gemm_k<<<dim3(ADc / 64, BN / 64), 256, 0, stream>>>(src_feats, sfp_w, sfp_b, nullptr, A_, BN, PFDc, ADc, 0);
  ln_k<<<BN, 256, 0, stream>>>(A_, sfp_g, sfp_bb, G_, ADc, 1);
  gemm_k<<<dim3(ADc / 64, BN / 64), 256, 0, stream>>>(tgt_feats, tfp_w, tfp_b, nullptr, A_, BN, PFDc, ADc, 0);
  ln_k<<<BN, 256, 0, stream>>>(A_, tfp_g, tfp_bb, D_, ADc, 1);

  // 2) pre-LN + q/k/v
  ln_k<<<BN, 256, 0, stream>>>(G_, n1_g, n1_b, A_, ADc, 0);                   // xq -> A
  gemm_k<<<dim3(ADc / 64, BN / 64), 256, 0, stream>>>(A_, qw, qb, nullptr, C_, BN, ADc, ADc, 0);
  ln_k<<<BN, 256, 0, stream>>>(D_, n1_g, n1_b, B_, ADc, 0);                   // xc -> B
  gemm_k<<<dim3(ADc / 64, BN / 64), 256, 0, stream>>>(B_, kw, kb, nullptr, E_, BN, ADc, ADc, 0);
  gemm_k<<<dim3(ADc / 64, BN / 64), 256, 0, stream>>>(B_, vw, vb, nullptr, F_, BN, ADc, ADc, 0);

  // 3) K transpose (A_ is free: xq dead), attention, out-proj + residual
  ktrans_k<<<dim3(Bn * Hc, Mmm / 64), 256, 0, stream>>>(E_, A_);              // Kt -> A
  attn2_k<<<BN, 256, 0, stream>>>(C_, A_, F_, src_pts, tgt_pts, rbf_w, B_);   // ctx -> B
  gemm_k<<<dim3(ADc / 64, BN / 64), 256, 0, stream>>>(B_, ow, ob, G_, G_, BN, ADc, ADc, 0);

  // 4) FFN, hidden chunked through C_
  ln_k<<<BN, 256, 0, stream>>>(G_, n2_g, n2_b, A_, ADc, 0);                   // h -> A (kills Kt)
  for (int c = 0; c < 4; ++c) {
    const float* hA = A_ + (size_t)c * 1024 * ADc;
    float* xA = G_ + (size_t)c * 1024 * ADc;
    gemm_k<<<dim3(1024 / 64, 1024 / 64), 256, 0, stream>>>(hA, f1_w, f1_b, nullptr, C_, 1024, ADc, 1024, 1);
    gemm_k<<<dim3(ADc / 64, 1024 / 64), 256, 0, stream>>>(C_, f2_w, f2_b, xA, xA, 1024, 1024, ADc, 0);
  }

  // 5) correspondences + Sinkhorn
  gemm_k<<<dim3(ADc / 64, BN / 64), 256, 0, stream>>>(G_, scp_w, scp_b, nullptr, E_, BN, ADc, ADc, 0);
  gemm_k<<<dim3(ADc / 64, BN / 64), 256, 0, stream>>>(D_, tcp_w, tcp_b, nullptr, F_, BN, ADc, ADc, 0);
  gemm_nt_k<<<dim3(Mmm / 64, Nn / 64, Bn), 256, 0, stream>>>(E_, F_, logS, temp);

  for (int it = 0; it < 3; ++it) {
    row_lse_k<<<BN, 256, 0, stream>>>(logS, it == 0 ? nullptr : colLse);
    ncol_lse<<<Bn * Mmm / 256, 256, 0, stream>>>(logS, colLse);
  }
  finalize_k<<<BN, 256, 0, stream>>>(logS, colLse, tgt_pts, outS, outConf, conf, tcp);

  // 6) Kabsch
  kabsch_red_k<<<Bn, 256, 0, stream>>>(conf, src_pts, tcp, kab);
  kabsch_svd_k<<<1, 64, 0, stream>>>(kab, outR, outT);

  // 7) global pooling head
  xmax_k<<<Bn, 256, 0, stream>>>(G_, xmax);
  gemm_k<<<dim3(GFDc / 64, 1), 256, 0, stream>>>(xmax, gp_w, gp_b, nullptr, glraw, Bn, ADc, GFDc, 0);
  ln_k<<<Bn, 256, 0, stream>>>(glraw, gp_g, gp_bb, gl, GFDc, 1);
  combined_k<<<(Bn * 2 * GFDc) / 256, 256, 0, stream>>>(gl, tgt_glob, outC);
}

// Round 8
// 2350.948 us; speedup vs baseline: 2.0421x; 1.5326x over previous
//
#include <hip/hip_runtime.h>
#include <hip/hip_bf16.h>
#include <math.h>

constexpr int Bn  = 4;
constexpr int Nn  = 1024;
constexpr int Mmm = 1024;
constexpr int PFDc = 1024;
constexpr int ADc  = 256;
constexpr int GFDc = 512;
constexpr int Hc   = 4;
constexpr int NRc  = 16;
constexpr float COEFFc = -28.125f;    // -0.5/(CUT/(NR-1))^2
constexpr float SCALEc = 0.125f;      // DH^-0.5
constexpr float STEPc  = 2.0f / 15.0f;

__device__ __forceinline__ float addf(float a, float b) { return a + b; }
__device__ __forceinline__ double addd(double a, double b) { return a + b; }

#define BLK_REDUCE_F(OP, VAR, RES) \
  red[tid] = (VAR); __syncthreads(); \
  for (int st_ = 128; st_ > 0; st_ >>= 1) { if (tid < st_) red[tid] = OP(red[tid], red[tid + st_]); __syncthreads(); } \
  (RES) = red[0]; __syncthreads();

#define BLK_REDUCE_D(OP, VAR, RES) \
  redd[tid] = (VAR); __syncthreads(); \
  for (int st_ = 128; st_ > 0; st_ >>= 1) { if (tid < st_) redd[tid] = OP(redd[tid], redd[tid + st_]); __syncthreads(); } \
  (RES) = redd[0]; __syncthreads();

// ---------------------------------------------------------------------------
// Tiled GEMM: 64x64 tile, BK=16, 4x4 per thread, all fp32.
// ---------------------------------------------------------------------------
__global__ __launch_bounds__(256) void gemm_k(
    const float* __restrict__ A, const float* __restrict__ W, const float* __restrict__ bias,
    const float* __restrict__ addsrc, float* __restrict__ C,
    int R, int K, int Cc, int act)
{
  __shared__ __align__(16) float As[16][68];   // [k][row]
  __shared__ __align__(16) float Ws[16][68];   // [k][col]
  const int tid = threadIdx.x;
  const int tx = tid & 15, ty = tid >> 4;
  const int r0 = blockIdx.y * 64, c0 = blockIdx.x * 64;
  float acc[4][4] = {};
  for (int k0 = 0; k0 < K; k0 += 16) {
    #pragma unroll
    for (int j = 0; j < 4; ++j) {
      int e = tid + j * 256;
      int ar = e >> 4, ak = e & 15;
      int gr = r0 + ar;
      As[ak][ar] = (gr < R) ? A[(size_t)gr * K + k0 + ak] : 0.f;
    }
    #pragma unroll
    for (int j = 0; j < 4; ++j) {
      int e = tid + j * 256;
      int wk = e >> 6, wc = e & 63;
      int gc = c0 + wc;
      Ws[wk][wc] = (gc < Cc) ? W[(size_t)(k0 + wk) * Cc + gc] : 0.f;
    }
    __syncthreads();
    #pragma unroll
    for (int kk = 0; kk < 16; ++kk) {
      float4 av = *(const float4*)&As[kk][ty * 4];
      float4 wv = *(const float4*)&Ws[kk][tx * 4];
      float a[4] = {av.x, av.y, av.z, av.w};
      float w[4] = {wv.x, wv.y, wv.z, wv.w};
      #pragma unroll
      for (int i = 0; i < 4; ++i)
        #pragma unroll
        for (int j = 0; j < 4; ++j)
          acc[i][j] = fmaf(a[i], w[j], acc[i][j]);
    }
    __syncthreads();
  }
  #pragma unroll
  for (int i = 0; i < 4; ++i) {
    int r = r0 + ty * 4 + i;
    if (r >= R) continue;
    #pragma unroll
    for (int j = 0; j < 4; ++j) {
      int c = c0 + tx * 4 + j;
      if (c >= Cc) continue;
      float v = acc[i][j] + bias[c];
      if (addsrc) v += addsrc[(size_t)r * Cc + c];
      if (act == 1) v = 0.5f * v * (1.f + erff(v * 0.70710678118654752f));
      C[(size_t)r * Cc + c] = v;
    }
  }
}

// Batched NT GEMM: logS[b][n][m] = (1/tau) * sum_k A[b,n,k]*Bm[b,m,k]
__global__ __launch_bounds__(256) void gemm_nt_k(
    const float* __restrict__ A, const float* __restrict__ Bm, float* __restrict__ C,
    const float* __restrict__ temp)
{
  const int K = ADc;
  __shared__ __align__(16) float As[16][68];
  __shared__ __align__(16) float Bs[16][68];
  const int tid = threadIdx.x;
  const int tx = tid & 15, ty = tid >> 4;
  const int b = blockIdx.z;
  const int r0 = blockIdx.y * 64, c0 = blockIdx.x * 64;
  const float* Ab = A + (size_t)b * Nn * K;
  const float* Bb = Bm + (size_t)b * Mmm * K;
  float* Cb = C + (size_t)b * Nn * Mmm;
  float tau = fminf(fmaxf(temp[0], 0.01f), 1.0f);
  float inv_tau = 1.f / tau;
  float acc[4][4] = {};
  for (int k0 = 0; k0 < K; k0 += 16) {
    #pragma unroll
    for (int j = 0; j < 4; ++j) {
      int e = tid + j * 256;
      int ar = e >> 4, ak = e & 15;
      As[ak][ar] = Ab[(size_t)(r0 + ar) * K + k0 + ak];
      Bs[ak][ar] = Bb[(size_t)(c0 + ar) * K + k0 + ak];
    }
    __syncthreads();
    #pragma unroll
    for (int kk = 0; kk < 16; ++kk) {
      float4 av = *(const float4*)&As[kk][ty * 4];
      float4 bv = *(const float4*)&Bs[kk][tx * 4];
      float a[4] = {av.x, av.y, av.z, av.w};
      float w[4] = {bv.x, bv.y, bv.z, bv.w};
      #pragma unroll
      for (int i = 0; i < 4; ++i)
        #pragma unroll
        for (int j = 0; j < 4; ++j)
          acc[i][j] = fmaf(a[i], w[j], acc[i][j]);
    }
    __syncthreads();
  }
  #pragma unroll
  for (int i = 0; i < 4; ++i) {
    int r = r0 + ty * 4 + i;
    #pragma unroll
    for (int j = 0; j < 4; ++j) {
      int c = c0 + tx * 4 + j;
      Cb[(size_t)r * Mmm + c] = acc[i][j] * inv_tau;
    }
  }
}

// ---------------------------------------------------------------------------
// LayerNorm (+ optional ReLU): one block per row
// ---------------------------------------------------------------------------
__global__ __launch_bounds__(256) void ln_k(
    const float* __restrict__ in, const float* __restrict__ g, const float* __restrict__ bb,
    float* __restrict__ out, int Cc, int relu)
{
  const int tid = threadIdx.x;
  const int row = blockIdx.x;
  const float* x = in + (size_t)row * Cc;
  float* o = out + (size_t)row * Cc;
  __shared__ float red[256];
  float s = 0.f;
  for (int j = tid; j < Cc; j += 256) s += x[j];
  float tot; BLK_REDUCE_F(addf, s, tot);
  float mu = tot / Cc;
  float s2 = 0.f;
  for (int j = tid; j < Cc; j += 256) { float d = x[j] - mu; s2 += d * d; }
  float tot2; BLK_REDUCE_F(addf, s2, tot2);
  float inv = 1.f / sqrtf(tot2 / Cc + 1e-5f);
  for (int j = tid; j < Cc; j += 256) {
    float v = (x[j] - mu) * inv * g[j] + bb[j];
    if (relu) v = fmaxf(v, 0.f);
    o[j] = v;
  }
}

// ---------------------------------------------------------------------------
// Flash cross-attention, Q-tiled: grid (B*H, N/64), block 256.
// Per block: Q-tile (64 q) staged once; loop 16 m-tiles of 64:
//   S-tile = QK^T (64x64x64 tile GEMM, 4x4/thread) + RBF bias,
//   online softmax (row state in LDS), P->LDS, O += P*V (second tile GEMM).
// K/V traffic: 256 blocks x 512 KB = 128 MB total (vs 8 GB in round 7).
// ---------------------------------------------------------------------------
__global__ __launch_bounds__(256) void fattn(
    const float* __restrict__ q, const float* __restrict__ k, const float* __restrict__ v,
    const float* __restrict__ src_pts, const float* __restrict__ tgt_pts,
    const float* __restrict__ rbfw, float* __restrict__ ctx)
{
  const int bh = blockIdx.x;
  const int b = bh >> 2, h = bh & 3;
  const int n0 = blockIdx.y * 64;
  const int tid = threadIdx.x;
  const int tx = tid & 15, ty = tid >> 4;   // tx: m/d quad, ty: n quad

  __shared__ __align__(16) float Qs[64][68];   // [d][n]
  __shared__ __align__(16) float Ks[64][68];   // [d][m]
  __shared__ __align__(16) float Vs[64][68];   // [m][d]
  __shared__ __align__(16) float Ps[64][68];   // [n][m]
  __shared__ float spx[64], spy[64], spz[64];
  __shared__ float tpx[64], tpy[64], tpz[64];
  __shared__ float rw[16];
  __shared__ float mrun[64], lrun[64], alpha_s[64], mnew_s[64];
  __shared__ float rowred[64][17];

  // stage Q-tile [d][n], coalesced reads (consecutive tid -> consecutive d)
  #pragma unroll
  for (int c = 0; c < 16; ++c) {
    int e = c * 256 + tid;
    int n = e >> 6, d = e & 63;
    Qs[d][n] = q[((size_t)b * Nn + n0 + n) * ADc + h * 64 + d];
  }
  if (tid < 64) {
    spx[tid] = src_pts[((size_t)b * Nn + n0 + tid) * 3 + 0];
    spy[tid] = src_pts[((size_t)b * Nn + n0 + tid) * 3 + 1];
    spz[tid] = src_pts[((size_t)b * Nn + n0 + tid) * 3 + 2];
    mrun[tid] = -1e30f;
    lrun[tid] = 0.f;
  }
  if (tid < NRc) rw[tid] = rbfw[tid * Hc + h];

  float O[4][4] = {};

  for (int t = 0; t < Mmm / 64; ++t) {
    const int m0 = t * 64;
    __syncthreads();   // protect Ks/Vs/tp from previous iteration's readers
    #pragma unroll
    for (int c = 0; c < 16; ++c) {
      int e = c * 256 + tid;
      int mm = e >> 6, d = e & 63;
      float kvv = k[((size_t)b * Mmm + m0 + mm) * ADc + h * 64 + d];
      float vvv = v[((size_t)b * Mmm + m0 + mm) * ADc + h * 64 + d];
      Ks[d][mm] = kvv;
      Vs[mm][d] = vvv;
    }
    if (tid < 64) {
      tpx[tid] = tgt_pts[((size_t)b * Mmm + m0 + tid) * 3 + 0];
      tpy[tid] = tgt_pts[((size_t)b * Mmm + m0 + tid) * 3 + 1];
      tpz[tid] = tgt_pts[((size_t)b * Mmm + m0 + tid) * 3 + 2];
    }
    __syncthreads();

    // S-tile GEMM over d
    float S[4][4] = {};
    #pragma unroll
    for (int d = 0; d < 64; ++d) {
      float4 qv = *(const float4*)&Qs[d][ty * 4];
      float4 kv = *(const float4*)&Ks[d][tx * 4];
      float a[4] = {qv.x, qv.y, qv.z, qv.w};
      float w[4] = {kv.x, kv.y, kv.z, kv.w};
      #pragma unroll
      for (int i = 0; i < 4; ++i)
        #pragma unroll
        for (int j = 0; j < 4; ++j)
          S[i][j] = fmaf(a[i], w[j], S[i][j]);
    }
    // scale + RBF bias; track per-row tile max
    #pragma unroll
    for (int i = 0; i < 4; ++i) {
      int n = ty * 4 + i;
      float s0 = spx[n], s1 = spy[n], s2 = spz[n];
      float ssq = s0 * s0 + s1 * s1 + s2 * s2;
      float rmx = -1e30f;
      #pragma unroll
      for (int j = 0; j < 4; ++j) {
        int mj = tx * 4 + j;
        float t0 = tpx[mj], t1 = tpy[mj], t2 = tpz[mj];
        float d2 = ssq + t0 * t0 + t1 * t1 + t2 * t2 - 2.f * (s0 * t0 + s1 * t1 + s2 * t2);
        float dist = sqrtf(fmaxf(d2, 0.f));
        float bias = 0.f;
        #pragma unroll
        for (int r = 0; r < NRc; ++r) {
          float dd = dist - STEPc * r;
          bias = fmaf(expf(COEFFc * dd * dd), rw[r], bias);
        }
        float lv = S[i][j] * SCALEc + bias;
        S[i][j] = lv;
        rmx = fmaxf(rmx, lv);
      }
      rowred[n][tx] = rmx;
    }
    __syncthreads();
    if (tid < 64) {
      float mt = rowred[tid][0];
      #pragma unroll
      for (int s = 1; s < 16; ++s) mt = fmaxf(mt, rowred[tid][s]);
      float mn = fmaxf(mrun[tid], mt);
      mnew_s[tid] = mn;
      alpha_s[tid] = expf(mrun[tid] - mn);
      mrun[tid] = mn;
    }
    __syncthreads();
    // P = exp(S - mnew) -> Ps[n][m]; partial row sums
    #pragma unroll
    for (int i = 0; i < 4; ++i) {
      int n = ty * 4 + i;
      float mn = mnew_s[n];
      float p0 = expf(S[i][0] - mn);
      float p1 = expf(S[i][1] - mn);
      float p2 = expf(S[i][2] - mn);
      float p3 = expf(S[i][3] - mn);
      *(float4*)&Ps[n][tx * 4] = make_float4(p0, p1, p2, p3);
      rowred[n][tx] = p0 + p1 + p2 + p3;
    }
    __syncthreads();
    if (tid < 64) {
      float ls = 0.f;
      #pragma unroll
      for (int s = 0; s < 16; ++s) ls += rowred[tid][s];
      lrun[tid] = lrun[tid] * alpha_s[tid] + ls;
    }
    // rescale O and accumulate PV
    #pragma unroll
    for (int i = 0; i < 4; ++i) {
      float a = alpha_s[ty * 4 + i];
      #pragma unroll
      for (int j = 0; j < 4; ++j) O[i][j] *= a;
    }
    #pragma unroll
    for (int m = 0; m < 64; ++m) {
      float4 vv = *(const float4*)&Vs[m][tx * 4];
      float w[4] = {vv.x, vv.y, vv.z, vv.w};
      #pragma unroll
      for (int i = 0; i < 4; ++i) {
        float p = Ps[ty * 4 + i][m];
        #pragma unroll
        for (int j = 0; j < 4; ++j)
          O[i][j] = fmaf(p, w[j], O[i][j]);
      }
    }
  }
  __syncthreads();
  #pragma unroll
  for (int i = 0; i < 4; ++i) {
    int n = ty * 4 + i;
    float invl = 1.f / lrun[n];
    #pragma unroll
    for (int j = 0; j < 4; ++j)
      ctx[((size_t)b * Nn + n0 + n) * ADc + h * 64 + tx * 4 + j] = O[i][j] * invl;
  }
}

// ---------------------------------------------------------------------------
// Sinkhorn row pass (fuses previous colLse subtraction).
// ---------------------------------------------------------------------------
__global__ __launch_bounds__(256) void row_lse_k(float* __restrict__ logS, const float* __restrict__ colLse)
{
  const int tid = threadIdx.x;
  const int bn = blockIdx.x;
  const int b = bn >> 10;
  float* row = logS + (size_t)bn * Mmm;
  const float* cl = colLse ? colLse + (size_t)b * Mmm : nullptr;
  __shared__ float buf[Mmm];
  __shared__ float red[256];
  float lmax = -1e30f;
  for (int j = tid; j < Mmm; j += 256) {
    float v = row[j];
    if (cl) v -= cl[j];
    buf[j] = v;
    lmax = fmaxf(lmax, v);
  }
  float rmax; BLK_REDUCE_F(fmaxf, lmax, rmax);
  float ls = 0.f;
  for (int j = tid; j < Mmm; j += 256) ls += expf(buf[j] - rmax);
  float rsum; BLK_REDUCE_F(addf, ls, rsum);
  float lse = rmax + logf(rsum);
  for (int j = tid; j < Mmm; j += 256) row[j] = buf[j] - lse;
}

// Column LSE: one thread per (b,m), two coalesced passes over rows.
__global__ __launch_bounds__(256) void ncol_lse(
    const float* __restrict__ logS, float* __restrict__ colLse)
{
  int gid = blockIdx.x * 256 + threadIdx.x;   // B*M = 4096
  int b = gid >> 10, m = gid & 1023;
  const float* base = logS + (size_t)b * Nn * Mmm + m;
  float mx = -1e30f;
  for (int n = 0; n < Nn; ++n) mx = fmaxf(mx, base[(size_t)n * Mmm]);
  float sm = 0.f;
  for (int n = 0; n < Nn; ++n) sm += expf(base[(size_t)n * Mmm] - mx);
  colLse[gid] = mx + logf(sm);
}

// ---------------------------------------------------------------------------
// Finalize: S = exp(logS - colLse); fp32 outputs.
// ---------------------------------------------------------------------------
__global__ __launch_bounds__(256) void finalize_k(
    const float* __restrict__ logS, const float* __restrict__ colLse,
    const float* __restrict__ tgt_pts, float* __restrict__ outS, float* __restrict__ outConf,
    float* __restrict__ conf, float* __restrict__ tcp)
{
  const int tid = threadIdx.x;
  const int bn = blockIdx.x;
  const int b = bn >> 10;
  const float* row = logS + (size_t)bn * Mmm;
  const float* cl = colLse + (size_t)b * Mmm;
  const float* tp = tgt_pts + (size_t)b * Mmm * 3;
  __shared__ float red[256];
  float mx = -1e30f, s0 = 0.f, s1 = 0.f, s2 = 0.f;
  for (int m = tid; m < Mmm; m += 256) {
    float sv = expf(row[m] - cl[m]);
    outS[(size_t)bn * Mmm + m] = sv;
    mx = fmaxf(mx, sv);
    s0 = fmaf(sv, tp[m * 3 + 0], s0);
    s1 = fmaf(sv, tp[m * 3 + 1], s1);
    s2 = fmaf(sv, tp[m * 3 + 2], s2);
  }
  float rmx, r0, r1, r2;
  BLK_REDUCE_F(fmaxf, mx, rmx);
  BLK_REDUCE_F(addf, s0, r0);
  BLK_REDUCE_F(addf, s1, r1);
  BLK_REDUCE_F(addf, s2, r2);
  if (tid == 0) {
    conf[bn] = rmx;
    outConf[bn] = rmx;
    tcp[(size_t)bn * 3 + 0] = r0;
    tcp[(size_t)bn * 3 + 1] = r1;
    tcp[(size_t)bn * 3 + 2] = r2;
  }
}

// ---------------------------------------------------------------------------
// Kabsch stage 1: per-batch weighted sums (double)
// ---------------------------------------------------------------------------
__global__ __launch_bounds__(256) void kabsch_red_k(
    const float* __restrict__ conf, const float* __restrict__ src_pts,
    const float* __restrict__ tcp, double* __restrict__ kab)
{
  const int b = blockIdx.x;
  const int tid = threadIdx.x;
  __shared__ double redd[256];
  __shared__ double sh[8];
  const float* cb = conf + (size_t)b * Nn;
  const float* sb = src_pts + (size_t)b * Nn * 3;
  const float* tb = tcp + (size_t)b * Nn * 3;

  double a = 0.0;
  for (int n = tid; n < Nn; n += 256) a += (double)cb[n];
  double wsum; BLK_REDUCE_D(addd, a, wsum);
  double inv = 1.0 / (wsum + 1e-8);

  double c0 = 0, c1 = 0, c2 = 0, t0 = 0, t1 = 0, t2 = 0;
  for (int n = tid; n < Nn; n += 256) {
    double wn = (double)cb[n] * inv;
    c0 += wn * (double)sb[n * 3 + 0];
    c1 += wn * (double)sb[n * 3 + 1];
    c2 += wn * (double)sb[n * 3 + 2];
    t0 += wn * (double)tb[n * 3 + 0];
    t1 += wn * (double)tb[n * 3 + 1];
    t2 += wn * (double)tb[n * 3 + 2];
  }
  double r;
  BLK_REDUCE_D(addd, c0, r); if (tid == 0) sh[0] = r; __syncthreads();
  BLK_REDUCE_D(addd, c1, r); if (tid == 0) sh[1] = r; __syncthreads();
  BLK_REDUCE_D(addd, c2, r); if (tid == 0) sh[2] = r; __syncthreads();
  BLK_REDUCE_D(addd, t0, r); if (tid == 0) sh[3] = r; __syncthreads();
  BLK_REDUCE_D(addd, t1, r); if (tid == 0) sh[4] = r; __syncthreads();
  BLK_REDUCE_D(addd, t2, r); if (tid == 0) sh[5] = r; __syncthreads();
  double cs[3] = {sh[0], sh[1], sh[2]};
  double ct[3] = {sh[3], sh[4], sh[5]};

  double hm[9] = {};
  for (int n = tid; n < Nn; n += 256) {
    double wn = (double)cb[n] * inv;
    double d0 = (double)sb[n * 3 + 0] - cs[0];
    double d1 = (double)sb[n * 3 + 1] - cs[1];
    double d2 = (double)sb[n * 3 + 2] - cs[2];
    double e0 = (double)tb[n * 3 + 0] - ct[0];
    double e1 = (double)tb[n * 3 + 1] - ct[1];
    double e2 = (double)tb[n * 3 + 2] - ct[2];
    hm[0] += wn * d0 * e0; hm[1] += wn * d0 * e1; hm[2] += wn * d0 * e2;
    hm[3] += wn * d1 * e0; hm[4] += wn * d1 * e1; hm[5] += wn * d1 * e2;
    hm[6] += wn * d2 * e0; hm[7] += wn * d2 * e1; hm[8] += wn * d2 * e2;
  }
  for (int i = 0; i < 9; ++i) {
    BLK_REDUCE_D(addd, hm[i], r);
    if (tid == 0) kab[(size_t)b * 16 + i] = r;
    __syncthreads();
  }
  if (tid == 0) {
    for (int i = 0; i < 3; ++i) {
      kab[(size_t)b * 16 + 9 + i]  = cs[i];
      kab[(size_t)b * 16 + 12 + i] = ct[i];
    }
  }
}

// ---------------------------------------------------------------------------
// Kabsch stage 2 — numpy-mirror SVD; fp32 outputs.
// ---------------------------------------------------------------------------
__device__ __forceinline__ double trip(const double a[3], const double b[3], const double c[3]) {
  return a[0] * (b[1] * c[2] - b[2] * c[1])
       - a[1] * (b[0] * c[2] - b[2] * c[0])
       + a[2] * (b[0] * c[1] - b[1] * c[0]);
}

__global__ void kabsch_svd_k(const double* __restrict__ kab, float* __restrict__ outR, float* __restrict__ outT)
{
  const int b = threadIdx.x;
  if (b >= Bn) return;
  const double* kb = kab + (size_t)b * 16;
  double A[3][3], cs[3], ct[3];
  for (int i = 0; i < 3; ++i)
    for (int j = 0; j < 3; ++j) A[i][j] = kb[i * 3 + j];
  for (int i = 0; i < 3; ++i) { cs[i] = kb[9 + i]; ct[i] = kb[12 + i]; }

  double Km[3][3];
  for (int i = 0; i < 3; ++i)
    for (int j = 0; j < 3; ++j)
      Km[i][j] = A[0][i] * A[0][j] + A[1][i] * A[1][j] + A[2][i] * A[2][j];
  double V[3][3] = {{1, 0, 0}, {0, 1, 0}, {0, 0, 1}};
  const int PP[3] = {0, 0, 1}, QQ[3] = {1, 2, 2};
  for (int sweep = 0; sweep < 30; ++sweep) {
    for (int pi = 0; pi < 3; ++pi) {
      int p = PP[pi], qd = QQ[pi];
      double apq = Km[p][qd];
      if (fabs(apq) < 1e-300) continue;
      double theta = (Km[qd][qd] - Km[p][p]) / (2.0 * apq);
      double tt = (theta >= 0 ? 1.0 : -1.0) / (fabs(theta) + sqrt(theta * theta + 1.0));
      double cc = 1.0 / sqrt(tt * tt + 1.0), ss = tt * cc;
      for (int r = 0; r < 3; ++r) {
        double kp = Km[r][p], kq = Km[r][qd];
        Km[r][p] = cc * kp - ss * kq; Km[r][qd] = ss * kp + cc * kq;
      }
      for (int c = 0; c < 3; ++c) {
        double kp = Km[p][c], kq = Km[qd][c];
        Km[p][c] = cc * kp - ss * kq; Km[qd][c] = ss * kp + cc * kq;
      }
      for (int r = 0; r < 3; ++r) {
        double vp = V[r][p], vq = V[r][qd];
        V[r][p] = cc * vp - ss * vq; V[r][qd] = ss * vp + cc * vq;
      }
    }
  }
  double lam[3] = {Km[0][0], Km[1][1], Km[2][2]};
  int i0 = 0, i1 = 1, i2 = 2, tsw;
  if (lam[i0] < lam[i1]) { tsw = i0; i0 = i1; i1 = tsw; }
  if (lam[i0] < lam[i2]) { tsw = i0; i0 = i2; i2 = tsw; }
  if (lam[i1] < lam[i2]) { tsw = i1; i1 = i2; i2 = tsw; }
  double vv[3][3];
  for (int r = 0; r < 3; ++r) { vv[0][r] = V[r][i0]; vv[1][r] = V[r][i1]; vv[2][r] = V[r][i2]; }
  double sg[3] = { sqrt(fmax(lam[i0], 0.0)), sqrt(fmax(lam[i1], 0.0)), sqrt(fmax(lam[i2], 0.0)) };

  double uu[3][3];
  double eps = 1e-12 * (sg[0] > 0 ? sg[0] : 1.0);
  if (sg[0] > eps) {
    for (int r = 0; r < 3; ++r)
      uu[0][r] = (A[r][0] * vv[0][0] + A[r][1] * vv[0][1] + A[r][2] * vv[0][2]) / sg[0];
    double n = sqrt(uu[0][0]*uu[0][0] + uu[0][1]*uu[0][1] + uu[0][2]*uu[0][2]);
    if (n > 1e-14) { uu[0][0]/=n; uu[0][1]/=n; uu[0][2]/=n; }
  } else { uu[0][0]=1; uu[0][1]=0; uu[0][2]=0; }
  if (sg[1] > eps) {
    for (int r = 0; r < 3; ++r)
      uu[1][r] = (A[r][0] * vv[1][0] + A[r][1] * vv[1][1] + A[r][2] * vv[1][2]) / sg[1];
  } else {
    int ax = (fabs(uu[0][0]) <= fabs(uu[0][1]) && fabs(uu[0][0]) <= fabs(uu[0][2])) ? 0
           : (fabs(uu[0][1]) <= fabs(uu[0][2]) ? 1 : 2);
    uu[1][0] = uu[1][1] = uu[1][2] = 0.0; uu[1][ax] = 1.0;
  }
  {
    double pr = uu[0][0]*uu[1][0] + uu[0][1]*uu[1][1] + uu[0][2]*uu[1][2];
    for (int r = 0; r < 3; ++r) uu[1][r] -= pr * uu[0][r];
    double n = sqrt(uu[1][0]*uu[1][0] + uu[1][1]*uu[1][1] + uu[1][2]*uu[1][2]);
    if (n > 1e-14) { uu[1][0]/=n; uu[1][1]/=n; uu[1][2]/=n; }
  }
  if (sg[2] > eps) {
    for (int r = 0; r < 3; ++r)
      uu[2][r] = (A[r][0] * vv[2][0] + A[r][1] * vv[2][1] + A[r][2] * vv[2][2]) / sg[2];
    double p0 = uu[0][0]*uu[2][0] + uu[0][1]*uu[2][1] + uu[0][2]*uu[2][2];
    double p1 = uu[1][0]*uu[2][0] + uu[1][1]*uu[2][1] + uu[1][2]*uu[2][2];
    for (int r = 0; r < 3; ++r) uu[2][r] -= p0 * uu[0][r] + p1 * uu[1][r];
    double n = sqrt(uu[2][0]*uu[2][0] + uu[2][1]*uu[2][1] + uu[2][2]*uu[2][2]);
    if (n > 1e-14) { uu[2][0]/=n; uu[2][1]/=n; uu[2][2]/=n; }
    else {
      uu[2][0] = uu[0][1]*uu[1][2] - uu[0][2]*uu[1][1];
      uu[2][1] = uu[0][2]*uu[1][0] - uu[0][0]*uu[1][2];
      uu[2][2] = uu[0][0]*uu[1][1] - uu[0][1]*uu[1][0];
    }
  } else {
    uu[2][0] = uu[0][1]*uu[1][2] - uu[0][2]*uu[1][1];
    uu[2][1] = uu[0][2]*uu[1][0] - uu[0][0]*uu[1][2];
    uu[2][2] = uu[0][0]*uu[1][1] - uu[0][1]*uu[1][0];
  }

  double detU = trip(uu[0], uu[1], uu[2]);
  double detV = trip(vv[0], vv[1], vv[2]);
  double d = (detU * detV < 0.0) ? -1.0 : 1.0;

  double R[3][3];
  for (int i = 0; i < 3; ++i)
    for (int j = 0; j < 3; ++j)
      R[i][j] = vv[0][i] * uu[0][j] + vv[1][i] * uu[1][j] + d * vv[2][i] * uu[2][j];
  for (int i = 0; i < 3; ++i) {
    double t = ct[i] - (R[i][0] * cs[0] + R[i][1] * cs[1] + R[i][2] * cs[2]);
    outT[(size_t)b * 3 + i] = (float)t;
    for (int j = 0; j < 3; ++j)
      outR[(size_t)b * 9 + i * 3 + j] = (float)R[i][j];
  }
}

// x.max over N
__global__ __launch_bounds__(256) void xmax_k(const float* __restrict__ x, float* __restrict__ xmax)
{
  const int b = blockIdx.x;
  const int d = threadIdx.x;
  float mx = -1e30f;
  for (int n = 0; n < Nn; ++n) mx = fmaxf(mx, x[((size_t)b * Nn + n) * ADc + d]);
  xmax[(size_t)b * ADc + d] = mx;
}

__global__ __launch_bounds__(256) void combined_k(
    const float* __restrict__ gl, const float* __restrict__ tgt_global, float* __restrict__ outC)
{
  int i = blockIdx.x * 256 + threadIdx.x;
  int b = i >> 10, j = i & 1023;
  float v = (j < GFDc) ? gl[(size_t)b * GFDc + j] : tgt_global[(size_t)b * GFDc + (j - GFDc)];
  outC[i] = v;
}

// ---------------------------------------------------------------------------
extern "C" void kernel_launch(void* const* d_in, const int* in_sizes, int n_in,
                              void* d_out, int out_size, void* d_ws, size_t ws_size,
                              hipStream_t stream) {
  (void)in_sizes; (void)n_in; (void)out_size; (void)ws_size;
  const float* src_feats = (const float*)d_in[0];
  const float* tgt_feats = (const float*)d_in[1];
  const float* src_pts   = (const float*)d_in[2];
  const float* tgt_pts   = (const float*)d_in[3];
  const float* tgt_glob  = (const float*)d_in[4];
  const float* sfp_w = (const float*)d_in[5];  const float* sfp_b = (const float*)d_in[6];
  const float* sfp_g = (const float*)d_in[7];  const float* sfp_bb = (const float*)d_in[8];
  const float* tfp_w = (const float*)d_in[9];  const float* tfp_b = (const float*)d_in[10];
  const float* tfp_g = (const float*)d_in[11]; const float* tfp_bb = (const float*)d_in[12];
  const float* rbf_w = (const float*)d_in[13];
  const float* qw = (const float*)d_in[14]; const float* qb = (const float*)d_in[15];
  const float* kw = (const float*)d_in[16]; const float* kb = (const float*)d_in[17];
  const float* vw = (const float*)d_in[18]; const float* vb = (const float*)d_in[19];
  const float* ow = (const float*)d_in[20]; const float* ob = (const float*)d_in[21];
  const float* n1_g = (const float*)d_in[22]; const float* n1_b = (const float*)d_in[23];
  const float* f1_w = (const float*)d_in[24]; const float* f1_b = (const float*)d_in[25];
  const float* f2_w = (const float*)d_in[26]; const float* f2_b = (const float*)d_in[27];
  const float* n2_g = (const float*)d_in[28]; const float* n2_b = (const float*)d_in[29];
  const float* scp_w = (const float*)d_in[30]; const float* scp_b = (const float*)d_in[31];
  const float* tcp_w = (const float*)d_in[32]; const float* tcp_b = (const float*)d_in[33];
  const float* temp  = (const float*)d_in[34];
  const float* gp_w = (const float*)d_in[35]; const float* gp_b = (const float*)d_in[36];
  const float* gp_g = (const float*)d_in[37]; const float* gp_bb = (const float*)d_in[38];

  float* out = (float*)d_out;
  float* outR    = out;                    // (B,3,3)
  float* outT    = out + 36;               // (B,3)
  float* outC    = out + 48;               // (B,1024)
  float* outConf = out + 48 + 4096;        // (B,N)
  float* outS    = out + 48 + 4096 + 4096; // (B,N,M)

  // overlay workspace, peak ~29.1 MB (validated)
  float* ws = (float*)d_ws;
  const size_t M1 = 1048576;
  float* A_   = ws + 0 * M1;     // raw proj / xq / h
  float* B_   = ws + 1 * M1;     // xc / ctx
  float* C_   = ws + 2 * M1;     // q / ffn chunk
  float* D_   = ws + 3 * M1;     // tproj
  float* logS = ws + 0 * M1;     // overlays A..D after they die
  float* E_   = ws + 4 * M1;     // k / src_corr
  float* F_   = ws + 5 * M1;     // v / tgt_corr
  float* G_   = ws + 6 * M1;     // src_proj -> x
  float* tail = ws + 7 * M1;
  float* colLse = tail;                         // 4096
  float* conf   = colLse + 4096;                // 4096
  float* tcp    = conf + 4096;                  // 12288
  float* xmax   = tcp + 12288;                  // 1024
  float* glraw  = xmax + 1024;                  // 2048
  float* gl     = glraw + 2048;                 // 2048
  double* kab   = (double*)(gl + 2048);         // 64 doubles

  const int BN = Bn * Nn;   // 4096

  // 1) projections + LN + ReLU
  gemm_k<<<dim3(ADc / 64, BN / 64), 256, 0, stream>>>(src_feats, sfp_w, sfp_b, nullptr, A_, BN, PFDc, ADc, 0);
  ln_k<<<BN, 256, 0, stream>>>(A_, sfp_g, sfp_bb, G_, ADc, 1);
  gemm_k<<<dim3(ADc / 64, BN / 64), 256, 0, stream>>>(tgt_feats, tfp_w, tfp_b, nullptr, A_, BN, PFDc, ADc, 0);
  ln_k<<<BN, 256, 0, stream>>>(A_, tfp_g, tfp_bb, D_, ADc, 1);

  // 2) pre-LN + q/k/v
  ln_k<<<BN, 256, 0, stream>>>(G_, n1_g, n1_b, A_, ADc, 0);                   // xq -> A
  gemm_k<<<dim3(ADc / 64, BN / 64), 256, 0, stream>>>(A_, qw, qb, nullptr, C_, BN, ADc, ADc, 0);
  ln_k<<<BN, 256, 0, stream>>>(D_, n1_g, n1_b, B_, ADc, 0);                   // xc -> B
  gemm_k<<<dim3(ADc / 64, BN / 64), 256, 0, stream>>>(B_, kw, kb, nullptr, E_, BN, ADc, ADc, 0);
  gemm_k<<<dim3(ADc / 64, BN / 64), 256, 0, stream>>>(B_, vw, vb, nullptr, F_, BN, ADc, ADc, 0);

  // 3) flash attention (Q-tiled), out-proj + residual
  fattn<<<dim3(Bn * Hc, Nn / 64), 256, 0, stream>>>(C_, E_, F_, src_pts, tgt_pts, rbf_w, B_);  // ctx -> B
  gemm_k<<<dim3(ADc / 64, BN / 64), 256, 0, stream>>>(B_, ow, ob, G_, G_, BN, ADc, ADc, 0);

  // 4) FFN, hidden chunked through C_
  ln_k<<<BN, 256, 0, stream>>>(G_, n2_g, n2_b, A_, ADc, 0);                   // h -> A
  for (int c = 0; c < 4; ++c) {
    const float* hA = A_ + (size_t)c * 1024 * ADc;
    float* xA = G_ + (size_t)c * 1024 * ADc;
    gemm_k<<<dim3(1024 / 64, 1024 / 64), 256, 0, stream>>>(hA, f1_w, f1_b, nullptr, C_, 1024, ADc, 1024, 1);
    gemm_k<<<dim3(ADc / 64, 1024 / 64), 256, 0, stream>>>(C_, f2_w, f2_b, xA, xA, 1024, 1024, ADc, 0);
  }

  // 5) correspondences + Sinkhorn
  gemm_k<<<dim3(ADc / 64, BN / 64), 256, 0, stream>>>(G_, scp_w, scp_b, nullptr, E_, BN, ADc, ADc, 0);
  gemm_k<<<dim3(ADc / 64, BN / 64), 256, 0, stream>>>(D_, tcp_w, tcp_b, nullptr, F_, BN, ADc, ADc, 0);
  gemm_nt_k<<<dim3(Mmm / 64, Nn / 64, Bn), 256, 0, stream>>>(E_, F_, logS, temp);

  for (int it = 0; it < 3; ++it) {
    row_lse_k<<<BN, 256, 0, stream>>>(logS, it == 0 ? nullptr : colLse);
    ncol_lse<<<Bn * Mmm / 256, 256, 0, stream>>>(logS, colLse);
  }
  finalize_k<<<BN, 256, 0, stream>>>(logS, colLse, tgt_pts, outS, outConf, conf, tcp);

  // 6) Kabsch
  kabsch_red_k<<<Bn, 256, 0, stream>>>(conf, src_pts, tcp, kab);
  kabsch_svd_k<<<1, 64, 0, stream>>>(kab, outR, outT);

  // 7) global pooling head
  xmax_k<<<Bn, 256, 0, stream>>>(G_, xmax);
  gemm_k<<<dim3(GFDc / 64, 1), 256, 0, stream>>>(xmax, gp_w, gp_b, nullptr, glraw, Bn, ADc, GFDc, 0);
  ln_k<<<Bn, 256, 0, stream>>>(glraw, gp_g, gp_bb, gl, GFDc, 1);
  combined_k<<<(Bn * 2 * GFDc) / 256, 256, 0, stream>>>(gl, tgt_glob, outC);
}

// Round 9
// 1777.736 us; speedup vs baseline: 2.7005x; 1.3224x over previous
//
#include <hip/hip_runtime.h>
#include <hip/hip_bf16.h>
#include <math.h>

constexpr int Bn  = 4;
constexpr int Nn  = 1024;
constexpr int Mmm = 1024;
constexpr int PFDc = 1024;
constexpr int ADc  = 256;
constexpr int GFDc = 512;
constexpr int Hc   = 4;
constexpr int NRc  = 16;
constexpr int NSPLIT = 32;
constexpr float COEFFc = -28.125f;    // -0.5/(CUT/(NR-1))^2
constexpr float SCALEc = 0.125f;      // DH^-0.5
constexpr float STEPc  = 2.0f / 15.0f;

__device__ __forceinline__ float addf(float a, float b) { return a + b; }
__device__ __forceinline__ double addd(double a, double b) { return a + b; }

#define BLK_REDUCE_F(OP, VAR, RES) \
  red[tid] = (VAR); __syncthreads(); \
  for (int st_ = 128; st_ > 0; st_ >>= 1) { if (tid < st_) red[tid] = OP(red[tid], red[tid + st_]); __syncthreads(); } \
  (RES) = red[0]; __syncthreads();

#define BLK_REDUCE_D(OP, VAR, RES) \
  redd[tid] = (VAR); __syncthreads(); \
  for (int st_ = 128; st_ > 0; st_ >>= 1) { if (tid < st_) redd[tid] = OP(redd[tid], redd[tid + st_]); __syncthreads(); } \
  (RES) = redd[0]; __syncthreads();

// ---------------------------------------------------------------------------
// Tiled GEMM: 64x64 tile, BK=16, 4x4 per thread, fp32.
// ---------------------------------------------------------------------------
__global__ __launch_bounds__(256) void gemm_k(
    const float* __restrict__ A, const float* __restrict__ W, const float* __restrict__ bias,
    const float* __restrict__ addsrc, float* __restrict__ C,
    int R, int K, int Cc, int act)
{
  __shared__ __align__(16) float As[16][68];   // [k][row]
  __shared__ __align__(16) float Ws[16][68];   // [k][col]
  const int tid = threadIdx.x;
  const int tx = tid & 15, ty = tid >> 4;
  const int r0 = blockIdx.y * 64, c0 = blockIdx.x * 64;
  float acc[4][4] = {};
  for (int k0 = 0; k0 < K; k0 += 16) {
    #pragma unroll
    for (int j = 0; j < 4; ++j) {
      int e = tid + j * 256;
      int ar = e >> 4, ak = e & 15;
      int gr = r0 + ar;
      As[ak][ar] = (gr < R) ? A[(size_t)gr * K + k0 + ak] : 0.f;
    }
    #pragma unroll
    for (int j = 0; j < 4; ++j) {
      int e = tid + j * 256;
      int wk = e >> 6, wc = e & 63;
      int gc = c0 + wc;
      Ws[wk][wc] = (gc < Cc) ? W[(size_t)(k0 + wk) * Cc + gc] : 0.f;
    }
    __syncthreads();
    #pragma unroll
    for (int kk = 0; kk < 16; ++kk) {
      float4 av = *(const float4*)&As[kk][ty * 4];
      float4 wv = *(const float4*)&Ws[kk][tx * 4];
      float a[4] = {av.x, av.y, av.z, av.w};
      float w[4] = {wv.x, wv.y, wv.z, wv.w};
      #pragma unroll
      for (int i = 0; i < 4; ++i)
        #pragma unroll
        for (int j = 0; j < 4; ++j)
          acc[i][j] = fmaf(a[i], w[j], acc[i][j]);
    }
    __syncthreads();
  }
  #pragma unroll
  for (int i = 0; i < 4; ++i) {
    int r = r0 + ty * 4 + i;
    if (r >= R) continue;
    #pragma unroll
    for (int j = 0; j < 4; ++j) {
      int c = c0 + tx * 4 + j;
      if (c >= Cc) continue;
      float v = acc[i][j] + bias[c];
      if (addsrc) v += addsrc[(size_t)r * Cc + c];
      if (act == 1) v = 0.5f * v * (1.f + erff(v * 0.70710678118654752f));
      C[(size_t)r * Cc + c] = v;
    }
  }
}

// ---------------------------------------------------------------------------
// Big-tile GEMM: 128x128 tile, BK=16, 8x8 per thread, fp32.
// Requires R%128==0, Cc%128==0, K%16==0.
// ---------------------------------------------------------------------------
__global__ __launch_bounds__(256) void gemm2_k(
    const float* __restrict__ A, const float* __restrict__ W, const float* __restrict__ bias,
    const float* __restrict__ addsrc, float* __restrict__ C,
    int R, int K, int Cc, int act)
{
  __shared__ __align__(16) float As[16][132];   // [k][row]
  __shared__ __align__(16) float Ws[16][132];   // [k][col]
  const int tid = threadIdx.x;
  const int tx = tid & 15, ty = tid >> 4;
  const int r0 = blockIdx.y * 128, c0 = blockIdx.x * 128;
  float acc[8][8] = {};
  for (int k0 = 0; k0 < K; k0 += 16) {
    #pragma unroll
    for (int j = 0; j < 8; ++j) {
      int e = tid + j * 256;          // 0..2047
      int ar = e >> 4, ak = e & 15;
      As[ak][ar] = A[(size_t)(r0 + ar) * K + k0 + ak];
      int wk = e >> 7, wc = e & 127;
      Ws[wk][wc] = W[(size_t)(k0 + wk) * Cc + c0 + wc];
    }
    __syncthreads();
    #pragma unroll
    for (int kk = 0; kk < 16; ++kk) {
      float a[8], w[8];
      *(float4*)&a[0] = *(const float4*)&As[kk][ty * 8];
      *(float4*)&a[4] = *(const float4*)&As[kk][ty * 8 + 4];
      *(float4*)&w[0] = *(const float4*)&Ws[kk][tx * 8];
      *(float4*)&w[4] = *(const float4*)&Ws[kk][tx * 8 + 4];
      #pragma unroll
      for (int i = 0; i < 8; ++i)
        #pragma unroll
        for (int j = 0; j < 8; ++j)
          acc[i][j] = fmaf(a[i], w[j], acc[i][j]);
    }
    __syncthreads();
  }
  #pragma unroll
  for (int i = 0; i < 8; ++i) {
    int r = r0 + ty * 8 + i;
    #pragma unroll
    for (int j = 0; j < 8; ++j) {
      int c = c0 + tx * 8 + j;
      float v = acc[i][j] + bias[c];
      if (addsrc) v += addsrc[(size_t)r * Cc + c];
      if (act == 1) v = 0.5f * v * (1.f + erff(v * 0.70710678118654752f));
      C[(size_t)r * Cc + c] = v;
    }
  }
}

// ---------------------------------------------------------------------------
// Batched NT GEMM, 128x128 tile: logS[b][n][m] = (1/tau)*sum_k A[b,n,k]*Bm[b,m,k]
// ---------------------------------------------------------------------------
__global__ __launch_bounds__(256) void gemm_nt2_k(
    const float* __restrict__ A, const float* __restrict__ Bm, float* __restrict__ C,
    const float* __restrict__ temp)
{
  const int K = ADc;
  __shared__ __align__(16) float As[16][132];
  __shared__ __align__(16) float Bs[16][132];
  const int tid = threadIdx.x;
  const int tx = tid & 15, ty = tid >> 4;
  const int b = blockIdx.z;
  const int r0 = blockIdx.y * 128, c0 = blockIdx.x * 128;
  const float* Ab = A + (size_t)b * Nn * K;
  const float* Bb = Bm + (size_t)b * Mmm * K;
  float* Cb = C + (size_t)b * Nn * Mmm;
  float tau = fminf(fmaxf(temp[0], 0.01f), 1.0f);
  float inv_tau = 1.f / tau;
  float acc[8][8] = {};
  for (int k0 = 0; k0 < K; k0 += 16) {
    #pragma unroll
    for (int j = 0; j < 8; ++j) {
      int e = tid + j * 256;
      int ar = e >> 4, ak = e & 15;
      As[ak][ar] = Ab[(size_t)(r0 + ar) * K + k0 + ak];
      Bs[ak][ar] = Bb[(size_t)(c0 + ar) * K + k0 + ak];
    }
    __syncthreads();
    #pragma unroll
    for (int kk = 0; kk < 16; ++kk) {
      float a[8], w[8];
      *(float4*)&a[0] = *(const float4*)&As[kk][ty * 8];
      *(float4*)&a[4] = *(const float4*)&As[kk][ty * 8 + 4];
      *(float4*)&w[0] = *(const float4*)&Bs[kk][tx * 8];
      *(float4*)&w[4] = *(const float4*)&Bs[kk][tx * 8 + 4];
      #pragma unroll
      for (int i = 0; i < 8; ++i)
        #pragma unroll
        for (int j = 0; j < 8; ++j)
          acc[i][j] = fmaf(a[i], w[j], acc[i][j]);
    }
    __syncthreads();
  }
  #pragma unroll
  for (int i = 0; i < 8; ++i) {
    int r = r0 + ty * 8 + i;
    #pragma unroll
    for (int j = 0; j < 8; ++j) {
      int c = c0 + tx * 8 + j;
      Cb[(size_t)r * Mmm + c] = acc[i][j] * inv_tau;
    }
  }
}

// ---------------------------------------------------------------------------
// LayerNorm (+ optional ReLU): one block per row
// ---------------------------------------------------------------------------
__global__ __launch_bounds__(256) void ln_k(
    const float* __restrict__ in, const float* __restrict__ g, const float* __restrict__ bb,
    float* __restrict__ out, int Cc, int relu)
{
  const int tid = threadIdx.x;
  const int row = blockIdx.x;
  const float* x = in + (size_t)row * Cc;
  float* o = out + (size_t)row * Cc;
  __shared__ float red[256];
  float s = 0.f;
  for (int j = tid; j < Cc; j += 256) s += x[j];
  float tot; BLK_REDUCE_F(addf, s, tot);
  float mu = tot / Cc;
  float s2 = 0.f;
  for (int j = tid; j < Cc; j += 256) { float d = x[j] - mu; s2 += d * d; }
  float tot2; BLK_REDUCE_F(addf, s2, tot2);
  float inv = 1.f / sqrtf(tot2 / Cc + 1e-5f);
  for (int j = tid; j < Cc; j += 256) {
    float v = (x[j] - mu) * inv * g[j] + bb[j];
    if (relu) v = fmaxf(v, 0.f);
    o[j] = v;
  }
}

// ---------------------------------------------------------------------------
// Flash cross-attention, Q-tiled (validated round 8).
// ---------------------------------------------------------------------------
__global__ __launch_bounds__(256) void fattn(
    const float* __restrict__ q, const float* __restrict__ k, const float* __restrict__ v,
    const float* __restrict__ src_pts, const float* __restrict__ tgt_pts,
    const float* __restrict__ rbfw, float* __restrict__ ctx)
{
  const int bh = blockIdx.x;
  const int b = bh >> 2, h = bh & 3;
  const int n0 = blockIdx.y * 64;
  const int tid = threadIdx.x;
  const int tx = tid & 15, ty = tid >> 4;

  __shared__ __align__(16) float Qs[64][68];   // [d][n]
  __shared__ __align__(16) float Ks[64][68];   // [d][m]
  __shared__ __align__(16) float Vs[64][68];   // [m][d]
  __shared__ __align__(16) float Ps[64][68];   // [n][m]
  __shared__ float spx[64], spy[64], spz[64];
  __shared__ float tpx[64], tpy[64], tpz[64];
  __shared__ float rw[16];
  __shared__ float mrun[64], lrun[64], alpha_s[64], mnew_s[64];
  __shared__ float rowred[64][17];

  #pragma unroll
  for (int c = 0; c < 16; ++c) {
    int e = c * 256 + tid;
    int n = e >> 6, d = e & 63;
    Qs[d][n] = q[((size_t)b * Nn + n0 + n) * ADc + h * 64 + d];
  }
  if (tid < 64) {
    spx[tid] = src_pts[((size_t)b * Nn + n0 + tid) * 3 + 0];
    spy[tid] = src_pts[((size_t)b * Nn + n0 + tid) * 3 + 1];
    spz[tid] = src_pts[((size_t)b * Nn + n0 + tid) * 3 + 2];
    mrun[tid] = -1e30f;
    lrun[tid] = 0.f;
  }
  if (tid < NRc) rw[tid] = rbfw[tid * Hc + h];

  float O[4][4] = {};

  for (int t = 0; t < Mmm / 64; ++t) {
    const int m0 = t * 64;
    __syncthreads();
    #pragma unroll
    for (int c = 0; c < 16; ++c) {
      int e = c * 256 + tid;
      int mm = e >> 6, d = e & 63;
      float kvv = k[((size_t)b * Mmm + m0 + mm) * ADc + h * 64 + d];
      float vvv = v[((size_t)b * Mmm + m0 + mm) * ADc + h * 64 + d];
      Ks[d][mm] = kvv;
      Vs[mm][d] = vvv;
    }
    if (tid < 64) {
      tpx[tid] = tgt_pts[((size_t)b * Mmm + m0 + tid) * 3 + 0];
      tpy[tid] = tgt_pts[((size_t)b * Mmm + m0 + tid) * 3 + 1];
      tpz[tid] = tgt_pts[((size_t)b * Mmm + m0 + tid) * 3 + 2];
    }
    __syncthreads();

    float S[4][4] = {};
    #pragma unroll
    for (int d = 0; d < 64; ++d) {
      float4 qv = *(const float4*)&Qs[d][ty * 4];
      float4 kv = *(const float4*)&Ks[d][tx * 4];
      float a[4] = {qv.x, qv.y, qv.z, qv.w};
      float w[4] = {kv.x, kv.y, kv.z, kv.w};
      #pragma unroll
      for (int i = 0; i < 4; ++i)
        #pragma unroll
        for (int j = 0; j < 4; ++j)
          S[i][j] = fmaf(a[i], w[j], S[i][j]);
    }
    #pragma unroll
    for (int i = 0; i < 4; ++i) {
      int n = ty * 4 + i;
      float s0 = spx[n], s1 = spy[n], s2 = spz[n];
      float ssq = s0 * s0 + s1 * s1 + s2 * s2;
      float rmx = -1e30f;
      #pragma unroll
      for (int j = 0; j < 4; ++j) {
        int mj = tx * 4 + j;
        float t0 = tpx[mj], t1 = tpy[mj], t2 = tpz[mj];
        float d2 = ssq + t0 * t0 + t1 * t1 + t2 * t2 - 2.f * (s0 * t0 + s1 * t1 + s2 * t2);
        float dist = sqrtf(fmaxf(d2, 0.f));
        float bias = 0.f;
        #pragma unroll
        for (int r = 0; r < NRc; ++r) {
          float dd = dist - STEPc * r;
          bias = fmaf(expf(COEFFc * dd * dd), rw[r], bias);
        }
        float lv = S[i][j] * SCALEc + bias;
        S[i][j] = lv;
        rmx = fmaxf(rmx, lv);
      }
      rowred[n][tx] = rmx;
    }
    __syncthreads();
    if (tid < 64) {
      float mt = rowred[tid][0];
      #pragma unroll
      for (int s = 1; s < 16; ++s) mt = fmaxf(mt, rowred[tid][s]);
      float mn = fmaxf(mrun[tid], mt);
      mnew_s[tid] = mn;
      alpha_s[tid] = expf(mrun[tid] - mn);
      mrun[tid] = mn;
    }
    __syncthreads();
    #pragma unroll
    for (int i = 0; i < 4; ++i) {
      int n = ty * 4 + i;
      float mn = mnew_s[n];
      float p0 = expf(S[i][0] - mn);
      float p1 = expf(S[i][1] - mn);
      float p2 = expf(S[i][2] - mn);
      float p3 = expf(S[i][3] - mn);
      *(float4*)&Ps[n][tx * 4] = make_float4(p0, p1, p2, p3);
      rowred[n][tx] = p0 + p1 + p2 + p3;
    }
    __syncthreads();
    if (tid < 64) {
      float ls = 0.f;
      #pragma unroll
      for (int s = 0; s < 16; ++s) ls += rowred[tid][s];
      lrun[tid] = lrun[tid] * alpha_s[tid] + ls;
    }
    #pragma unroll
    for (int i = 0; i < 4; ++i) {
      float a = alpha_s[ty * 4 + i];
      #pragma unroll
      for (int j = 0; j < 4; ++j) O[i][j] *= a;
    }
    #pragma unroll
    for (int m = 0; m < 64; ++m) {
      float4 vv = *(const float4*)&Vs[m][tx * 4];
      float w[4] = {vv.x, vv.y, vv.z, vv.w};
      #pragma unroll
      for (int i = 0; i < 4; ++i) {
        float p = Ps[ty * 4 + i][m];
        #pragma unroll
        for (int j = 0; j < 4; ++j)
          O[i][j] = fmaf(p, w[j], O[i][j]);
      }
    }
  }
  __syncthreads();
  #pragma unroll
  for (int i = 0; i < 4; ++i) {
    int n = ty * 4 + i;
    float invl = 1.f / lrun[n];
    #pragma unroll
    for (int j = 0; j < 4; ++j)
      ctx[((size_t)b * Nn + n0 + n) * ADc + h * 64 + tx * 4 + j] = O[i][j] * invl;
  }
}

// ---------------------------------------------------------------------------
// Sinkhorn row pass (fuses previous colLse subtraction).
// ---------------------------------------------------------------------------
__global__ __launch_bounds__(256) void row_lse_k(float* __restrict__ logS, const float* __restrict__ colLse)
{
  const int tid = threadIdx.x;
  const int bn = blockIdx.x;
  const int b = bn >> 10;
  float* row = logS + (size_t)bn * Mmm;
  const float* cl = colLse ? colLse + (size_t)b * Mmm : nullptr;
  __shared__ float buf[Mmm];
  __shared__ float red[256];
  float lmax = -1e30f;
  for (int j = tid; j < Mmm; j += 256) {
    float v = row[j];
    if (cl) v -= cl[j];
    buf[j] = v;
    lmax = fmaxf(lmax, v);
  }
  float rmax; BLK_REDUCE_F(fmaxf, lmax, rmax);
  float ls = 0.f;
  for (int j = tid; j < Mmm; j += 256) ls += expf(buf[j] - rmax);
  float rsum; BLK_REDUCE_F(addf, ls, rsum);
  float lse = rmax + logf(rsum);
  for (int j = tid; j < Mmm; j += 256) row[j] = buf[j] - lse;
}

// Column-LSE partials: grid (M/256, NSPLIT, B); online max/sum over N/NSPLIT rows
__global__ __launch_bounds__(256) void col_part_k(
    const float* __restrict__ logS, float* __restrict__ pmax, float* __restrict__ psum)
{
  const int b = blockIdx.z, sp = blockIdx.y;
  const int m = blockIdx.x * 256 + threadIdx.x;
  const int RPS = Nn / NSPLIT;
  const float* base = logS + ((size_t)b * Nn + sp * RPS) * Mmm + m;
  float mx = -1e30f, sm = 0.f;
  for (int i = 0; i < RPS; ++i) {
    float v = base[(size_t)i * Mmm];
    if (v > mx) { sm = sm * expf(mx - v) + 1.f; mx = v; }
    else sm += expf(v - mx);
  }
  size_t o = ((size_t)b * NSPLIT + sp) * Mmm + m;
  pmax[o] = mx; psum[o] = sm;
}

__global__ __launch_bounds__(256) void col_comb_k(
    const float* __restrict__ pmax, const float* __restrict__ psum, float* __restrict__ colLse)
{
  const int b = blockIdx.y;
  const int m = blockIdx.x * 256 + threadIdx.x;
  float mx = -1e30f;
  for (int s = 0; s < NSPLIT; ++s) mx = fmaxf(mx, pmax[((size_t)b * NSPLIT + s) * Mmm + m]);
  float sm = 0.f;
  for (int s = 0; s < NSPLIT; ++s) {
    size_t o = ((size_t)b * NSPLIT + s) * Mmm + m;
    sm += psum[o] * expf(pmax[o] - mx);
  }
  colLse[(size_t)b * Mmm + m] = mx + logf(sm);
}

// ---------------------------------------------------------------------------
// Finalize: S = exp(logS - colLse); fp32 outputs.
// ---------------------------------------------------------------------------
__global__ __launch_bounds__(256) void finalize_k(
    const float* __restrict__ logS, const float* __restrict__ colLse,
    const float* __restrict__ tgt_pts, float* __restrict__ outS, float* __restrict__ outConf,
    float* __restrict__ conf, float* __restrict__ tcp)
{
  const int tid = threadIdx.x;
  const int bn = blockIdx.x;
  const int b = bn >> 10;
  const float* row = logS + (size_t)bn * Mmm;
  const float* cl = colLse + (size_t)b * Mmm;
  const float* tp = tgt_pts + (size_t)b * Mmm * 3;
  __shared__ float red[256];
  float mx = -1e30f, s0 = 0.f, s1 = 0.f, s2 = 0.f;
  for (int m = tid; m < Mmm; m += 256) {
    float sv = expf(row[m] - cl[m]);
    outS[(size_t)bn * Mmm + m] = sv;
    mx = fmaxf(mx, sv);
    s0 = fmaf(sv, tp[m * 3 + 0], s0);
    s1 = fmaf(sv, tp[m * 3 + 1], s1);
    s2 = fmaf(sv, tp[m * 3 + 2], s2);
  }
  float rmx, r0, r1, r2;
  BLK_REDUCE_F(fmaxf, mx, rmx);
  BLK_REDUCE_F(addf, s0, r0);
  BLK_REDUCE_F(addf, s1, r1);
  BLK_REDUCE_F(addf, s2, r2);
  if (tid == 0) {
    conf[bn] = rmx;
    outConf[bn] = rmx;
    tcp[(size_t)bn * 3 + 0] = r0;
    tcp[(size_t)bn * 3 + 1] = r1;
    tcp[(size_t)bn * 3 + 2] = r2;
  }
}

// ---------------------------------------------------------------------------
// Kabsch stage 1: per-batch weighted sums (double)
// ---------------------------------------------------------------------------
__global__ __launch_bounds__(256) void kabsch_red_k(
    const float* __restrict__ conf, const float* __restrict__ src_pts,
    const float* __restrict__ tcp, double* __restrict__ kab)
{
  const int b = blockIdx.x;
  const int tid = threadIdx.x;
  __shared__ double redd[256];
  __shared__ double sh[8];
  const float* cb = conf + (size_t)b * Nn;
  const float* sb = src_pts + (size_t)b * Nn * 3;
  const float* tb = tcp + (size_t)b * Nn * 3;

  double a = 0.0;
  for (int n = tid; n < Nn; n += 256) a += (double)cb[n];
  double wsum; BLK_REDUCE_D(addd, a, wsum);
  double inv = 1.0 / (wsum + 1e-8);

  double c0 = 0, c1 = 0, c2 = 0, t0 = 0, t1 = 0, t2 = 0;
  for (int n = tid; n < Nn; n += 256) {
    double wn = (double)cb[n] * inv;
    c0 += wn * (double)sb[n * 3 + 0];
    c1 += wn * (double)sb[n * 3 + 1];
    c2 += wn * (double)sb[n * 3 + 2];
    t0 += wn * (double)tb[n * 3 + 0];
    t1 += wn * (double)tb[n * 3 + 1];
    t2 += wn * (double)tb[n * 3 + 2];
  }
  double r;
  BLK_REDUCE_D(addd, c0, r); if (tid == 0) sh[0] = r; __syncthreads();
  BLK_REDUCE_D(addd, c1, r); if (tid == 0) sh[1] = r; __syncthreads();
  BLK_REDUCE_D(addd, c2, r); if (tid == 0) sh[2] = r; __syncthreads();
  BLK_REDUCE_D(addd, t0, r); if (tid == 0) sh[3] = r; __syncthreads();
  BLK_REDUCE_D(addd, t1, r); if (tid == 0) sh[4] = r; __syncthreads();
  BLK_REDUCE_D(addd, t2, r); if (tid == 0) sh[5] = r; __syncthreads();
  double cs[3] = {sh[0], sh[1], sh[2]};
  double ct[3] = {sh[3], sh[4], sh[5]};

  double hm[9] = {};
  for (int n = tid; n < Nn; n += 256) {
    double wn = (double)cb[n] * inv;
    double d0 = (double)sb[n * 3 + 0] - cs[0];
    double d1 = (double)sb[n * 3 + 1] - cs[1];
    double d2 = (double)sb[n * 3 + 2] - cs[2];
    double e0 = (double)tb[n * 3 + 0] - ct[0];
    double e1 = (double)tb[n * 3 + 1] - ct[1];
    double e2 = (double)tb[n * 3 + 2] - ct[2];
    hm[0] += wn * d0 * e0; hm[1] += wn * d0 * e1; hm[2] += wn * d0 * e2;
    hm[3] += wn * d1 * e0; hm[4] += wn * d1 * e1; hm[5] += wn * d1 * e2;
    hm[6] += wn * d2 * e0; hm[7] += wn * d2 * e1; hm[8] += wn * d2 * e2;
  }
  for (int i = 0; i < 9; ++i) {
    BLK_REDUCE_D(addd, hm[i], r);
    if (tid == 0) kab[(size_t)b * 16 + i] = r;
    __syncthreads();
  }
  if (tid == 0) {
    for (int i = 0; i < 3; ++i) {
      kab[(size_t)b * 16 + 9 + i]  = cs[i];
      kab[(size_t)b * 16 + 12 + i] = ct[i];
    }
  }
}

// ---------------------------------------------------------------------------
// Kabsch stage 2 — numpy-mirror SVD; fp32 outputs.
// ---------------------------------------------------------------------------
__device__ __forceinline__ double trip(const double a[3], const double b[3], const double c[3]) {
  return a[0] * (b[1] * c[2] - b[2] * c[1])
       - a[1] * (b[0] * c[2] - b[2] * c[0])
       + a[2] * (b[0] * c[1] - b[1] * c[0]);
}

__global__ void kabsch_svd_k(const double* __restrict__ kab, float* __restrict__ outR, float* __restrict__ outT)
{
  const int b = threadIdx.x;
  if (b >= Bn) return;
  const double* kb = kab + (size_t)b * 16;
  double A[3][3], cs[3], ct[3];
  for (int i = 0; i < 3; ++i)
    for (int j = 0; j < 3; ++j) A[i][j] = kb[i * 3 + j];
  for (int i = 0; i < 3; ++i) { cs[i] = kb[9 + i]; ct[i] = kb[12 + i]; }

  double Km[3][3];
  for (int i = 0; i < 3; ++i)
    for (int j = 0; j < 3; ++j)
      Km[i][j] = A[0][i] * A[0][j] + A[1][i] * A[1][j] + A[2][i] * A[2][j];
  double V[3][3] = {{1, 0, 0}, {0, 1, 0}, {0, 0, 1}};
  const int PP[3] = {0, 0, 1}, QQ[3] = {1, 2, 2};
  for (int sweep = 0; sweep < 30; ++sweep) {
    for (int pi = 0; pi < 3; ++pi) {
      int p = PP[pi], qd = QQ[pi];
      double apq = Km[p][qd];
      if (fabs(apq) < 1e-300) continue;
      double theta = (Km[qd][qd] - Km[p][p]) / (2.0 * apq);
      double tt = (theta >= 0 ? 1.0 : -1.0) / (fabs(theta) + sqrt(theta * theta + 1.0));
      double cc = 1.0 / sqrt(tt * tt + 1.0), ss = tt * cc;
      for (int r = 0; r < 3; ++r) {
        double kp = Km[r][p], kq = Km[r][qd];
        Km[r][p] = cc * kp - ss * kq; Km[r][qd] = ss * kp + cc * kq;
      }
      for (int c = 0; c < 3; ++c) {
        double kp = Km[p][c], kq = Km[qd][c];
        Km[p][c] = cc * kp - ss * kq; Km[qd][c] = ss * kp + cc * kq;
      }
      for (int r = 0; r < 3; ++r) {
        double vp = V[r][p], vq = V[r][qd];
        V[r][p] = cc * vp - ss * vq; V[r][qd] = ss * vp + cc * vq;
      }
    }
  }
  double lam[3] = {Km[0][0], Km[1][1], Km[2][2]};
  int i0 = 0, i1 = 1, i2 = 2, tsw;
  if (lam[i0] < lam[i1]) { tsw = i0; i0 = i1; i1 = tsw; }
  if (lam[i0] < lam[i2]) { tsw = i0; i0 = i2; i2 = tsw; }
  if (lam[i1] < lam[i2]) { tsw = i1; i1 = i2; i2 = tsw; }
  double vv[3][3];
  for (int r = 0; r < 3; ++r) { vv[0][r] = V[r][i0]; vv[1][r] = V[r][i1]; vv[2][r] = V[r][i2]; }
  double sg[3] = { sqrt(fmax(lam[i0], 0.0)), sqrt(fmax(lam[i1], 0.0)), sqrt(fmax(lam[i2], 0.0)) };

  double uu[3][3];
  double eps = 1e-12 * (sg[0] > 0 ? sg[0] : 1.0);
  if (sg[0] > eps) {
    for (int r = 0; r < 3; ++r)
      uu[0][r] = (A[r][0] * vv[0][0] + A[r][1] * vv[0][1] + A[r][2] * vv[0][2]) / sg[0];
    double n = sqrt(uu[0][0]*uu[0][0] + uu[0][1]*uu[0][1] + uu[0][2]*uu[0][2]);
    if (n > 1e-14) { uu[0][0]/=n; uu[0][1]/=n; uu[0][2]/=n; }
  } else { uu[0][0]=1; uu[0][1]=0; uu[0][2]=0; }
  if (sg[1] > eps) {
    for (int r = 0; r < 3; ++r)
      uu[1][r] = (A[r][0] * vv[1][0] + A[r][1] * vv[1][1] + A[r][2] * vv[1][2]) / sg[1];
  } else {
    int ax = (fabs(uu[0][0]) <= fabs(uu[0][1]) && fabs(uu[0][0]) <= fabs(uu[0][2])) ? 0
           : (fabs(uu[0][1]) <= fabs(uu[0][2]) ? 1 : 2);
    uu[1][0] = uu[1][1] = uu[1][2] = 0.0; uu[1][ax] = 1.0;
  }
  {
    double pr = uu[0][0]*uu[1][0] + uu[0][1]*uu[1][1] + uu[0][2]*uu[1][2];
    for (int r = 0; r < 3; ++r) uu[1][r] -= pr * uu[0][r];
    double n = sqrt(uu[1][0]*uu[1][0] + uu[1][1]*uu[1][1] + uu[1][2]*uu[1][2]);
    if (n > 1e-14) { uu[1][0]/=n; uu[1][1]/=n; uu[1][2]/=n; }
  }
  if (sg[2] > eps) {
    for (int r = 0; r < 3; ++r)
      uu[2][r] = (A[r][0] * vv[2][0] + A[r][1] * vv[2][1] + A[r][2] * vv[2][2]) / sg[2];
    double p0 = uu[0][0]*uu[2][0] + uu[0][1]*uu[2][1] + uu[0][2]*uu[2][2];
    double p1 = uu[1][0]*uu[2][0] + uu[1][1]*uu[2][1] + uu[1][2]*uu[2][2];
    for (int r = 0; r < 3; ++r) uu[2][r] -= p0 * uu[0][r] + p1 * uu[1][r];
    double n = sqrt(uu[2][0]*uu[2][0] + uu[2][1]*uu[2][1] + uu[2][2]*uu[2][2]);
    if (n > 1e-14) { uu[2][0]/=n; uu[2][1]/=n; uu[2][2]/=n; }
    else {
      uu[2][0] = uu[0][1]*uu[1][2] - uu[0][2]*uu[1][1];
      uu[2][1] = uu[0][2]*uu[1][0] - uu[0][0]*uu[1][2];
      uu[2][2] = uu[0][0]*uu[1][1] - uu[0][1]*uu[1][0];
    }
  } else {
    uu[2][0] = uu[0][1]*uu[1][2] - uu[0][2]*uu[1][1];
    uu[2][1] = uu[0][2]*uu[1][0] - uu[0][0]*uu[1][2];
    uu[2][2] = uu[0][0]*uu[1][1] - uu[0][1]*uu[1][0];
  }

  double detU = trip(uu[0], uu[1], uu[2]);
  double detV = trip(vv[0], vv[1], vv[2]);
  double d = (detU * detV < 0.0) ? -1.0 : 1.0;

  double R[3][3];
  for (int i = 0; i < 3; ++i)
    for (int j = 0; j < 3; ++j)
      R[i][j] = vv[0][i] * uu[0][j] + vv[1][i] * uu[1][j] + d * vv[2][i] * uu[2][j];
  for (int i = 0; i < 3; ++i) {
    double t = ct[i] - (R[i][0] * cs[0] + R[i][1] * cs[1] + R[i][2] * cs[2]);
    outT[(size_t)b * 3 + i] = (float)t;
    for (int j = 0; j < 3; ++j)
      outR[(size_t)b * 9 + i * 3 + j] = (float)R[i][j];
  }
}

// x.max over N
__global__ __launch_bounds__(256) void xmax_k(const float* __restrict__ x, float* __restrict__ xmax)
{
  const int b = blockIdx.x;
  const int d = threadIdx.x;
  float mx = -1e30f;
  for (int n = 0; n < Nn; ++n) mx = fmaxf(mx, x[((size_t)b * Nn + n) * ADc + d]);
  xmax[(size_t)b * ADc + d] = mx;
}

__global__ __launch_bounds__(256) void combined_k(
    const float* __restrict__ gl, const float* __restrict__ tgt_global, float* __restrict__ outC)
{
  int i = blockIdx.x * 256 + threadIdx.x;
  int b = i >> 10, j = i & 1023;
  float v = (j < GFDc) ? gl[(size_t)b * GFDc + j] : tgt_global[(size_t)b * GFDc + (j - GFDc)];
  outC[i] = v;
}

// ---------------------------------------------------------------------------
extern "C" void kernel_launch(void* const* d_in, const int* in_sizes, int n_in,
                              void* d_out, int out_size, void* d_ws, size_t ws_size,
                              hipStream_t stream) {
  (void)in_sizes; (void)n_in; (void)out_size; (void)ws_size;
  const float* src_feats = (const float*)d_in[0];
  const float* tgt_feats = (const float*)d_in[1];
  const float* src_pts   = (const float*)d_in[2];
  const float* tgt_pts   = (const float*)d_in[3];
  const float* tgt_glob  = (const float*)d_in[4];
  const float* sfp_w = (const float*)d_in[5];  const float* sfp_b = (const float*)d_in[6];
  const float* sfp_g = (const float*)d_in[7];  const float* sfp_bb = (const float*)d_in[8];
  const float* tfp_w = (const float*)d_in[9];  const float* tfp_b = (const float*)d_in[10];
  const float* tfp_g = (const float*)d_in[11]; const float* tfp_bb = (const float*)d_in[12];
  const float* rbf_w = (const float*)d_in[13];
  const float* qw = (const float*)d_in[14]; const float* qb = (const float*)d_in[15];
  const float* kw = (const float*)d_in[16]; const float* kb = (const float*)d_in[17];
  const float* vw = (const float*)d_in[18]; const float* vb = (const float*)d_in[19];
  const float* ow = (const float*)d_in[20]; const float* ob = (const float*)d_in[21];
  const float* n1_g = (const float*)d_in[22]; const float* n1_b = (const float*)d_in[23];
  const float* f1_w = (const float*)d_in[24]; const float* f1_b = (const float*)d_in[25];
  const float* f2_w = (const float*)d_in[26]; const float* f2_b = (const float*)d_in[27];
  const float* n2_g = (const float*)d_in[28]; const float* n2_b = (const float*)d_in[29];
  const float* scp_w = (const float*)d_in[30]; const float* scp_b = (const float*)d_in[31];
  const float* tcp_w = (const float*)d_in[32]; const float* tcp_b = (const float*)d_in[33];
  const float* temp  = (const float*)d_in[34];
  const float* gp_w = (const float*)d_in[35]; const float* gp_b = (const float*)d_in[36];
  const float* gp_g = (const float*)d_in[37]; const float* gp_bb = (const float*)d_in[38];

  float* out = (float*)d_out;
  float* outR    = out;                    // (B,3,3)
  float* outT    = out + 36;               // (B,3)
  float* outC    = out + 48;               // (B,1024)
  float* outConf = out + 48 + 4096;        // (B,N)
  float* outS    = out + 48 + 4096 + 4096; // (B,N,M)

  // overlay workspace, peak ~29.3 MB
  float* ws = (float*)d_ws;
  const size_t M1 = 1048576;
  float* A_   = ws + 0 * M1;     // raw proj / xq / h
  float* B_   = ws + 1 * M1;     // xc / ctx / ffn-hidden(lo)
  float* C_   = ws + 2 * M1;     // q / ffn-hidden(hi)
  float* D_   = ws + 3 * M1;     // tproj
  float* logS = ws + 0 * M1;     // overlays A..D after they die
  float* H2   = ws + 1 * M1;     // 2M-float FFN hidden chunk (B_+C_)
  float* E_   = ws + 4 * M1;     // k / src_corr
  float* F_   = ws + 5 * M1;     // v / tgt_corr
  float* G_   = ws + 6 * M1;     // src_proj -> x
  float* tail = ws + 7 * M1;
  float* colLse = tail;                         // 4096
  float* pmax   = colLse + 4096;                // 131072
  float* psum   = pmax + 131072;                // 131072
  float* conf   = psum + 131072;                // 4096
  float* tcp    = conf + 4096;                  // 12288
  float* xmax   = tcp + 12288;                  // 1024
  float* glraw  = xmax + 1024;                  // 2048
  float* gl     = glraw + 2048;                 // 2048
  double* kab   = (double*)(gl + 2048);         // 64 doubles

  const int BN = Bn * Nn;   // 4096

  // 1) projections + LN + ReLU
  gemm_k<<<dim3(ADc / 64, BN / 64), 256, 0, stream>>>(src_feats, sfp_w, sfp_b, nullptr, A_, BN, PFDc, ADc, 0);
  ln_k<<<BN, 256, 0, stream>>>(A_, sfp_g, sfp_bb, G_, ADc, 1);
  gemm_k<<<dim3(ADc / 64, BN / 64), 256, 0, stream>>>(tgt_feats, tfp_w, tfp_b, nullptr, A_, BN, PFDc, ADc, 0);
  ln_k<<<BN, 256, 0, stream>>>(A_, tfp_g, tfp_bb, D_, ADc, 1);

  // 2) pre-LN + q/k/v
  ln_k<<<BN, 256, 0, stream>>>(G_, n1_g, n1_b, A_, ADc, 0);                   // xq -> A
  gemm_k<<<dim3(ADc / 64, BN / 64), 256, 0, stream>>>(A_, qw, qb, nullptr, C_, BN, ADc, ADc, 0);
  ln_k<<<BN, 256, 0, stream>>>(D_, n1_g, n1_b, B_, ADc, 0);                   // xc -> B
  gemm_k<<<dim3(ADc / 64, BN / 64), 256, 0, stream>>>(B_, kw, kb, nullptr, E_, BN, ADc, ADc, 0);
  gemm_k<<<dim3(ADc / 64, BN / 64), 256, 0, stream>>>(B_, vw, vb, nullptr, F_, BN, ADc, ADc, 0);

  // 3) flash attention (Q-tiled), out-proj + residual
  fattn<<<dim3(Bn * Hc, Nn / 64), 256, 0, stream>>>(C_, E_, F_, src_pts, tgt_pts, rbf_w, B_);  // ctx -> B
  gemm_k<<<dim3(ADc / 64, BN / 64), 256, 0, stream>>>(B_, ow, ob, G_, G_, BN, ADc, ADc, 0);

  // 4) FFN: h -> A_ (full), hidden chunk (2048 rows) through H2 (B_+C_)
  ln_k<<<BN, 256, 0, stream>>>(G_, n2_g, n2_b, A_, ADc, 0);                   // h -> A
  for (int c = 0; c < 2; ++c) {
    const float* hA = A_ + (size_t)c * 2048 * ADc;
    float* xA = G_ + (size_t)c * 2048 * ADc;
    gemm2_k<<<dim3(1024 / 128, 2048 / 128), 256, 0, stream>>>(hA, f1_w, f1_b, nullptr, H2, 2048, ADc, 1024, 1);
    gemm_k<<<dim3(ADc / 64, 2048 / 64), 256, 0, stream>>>(H2, f2_w, f2_b, xA, xA, 2048, 1024, ADc, 0);
  }

  // 5) correspondences + Sinkhorn (logS overlays A..D — h and tproj die here)
  gemm_k<<<dim3(ADc / 64, BN / 64), 256, 0, stream>>>(G_, scp_w, scp_b, nullptr, E_, BN, ADc, ADc, 0);
  gemm_k<<<dim3(ADc / 64, BN / 64), 256, 0, stream>>>(D_, tcp_w, tcp_b, nullptr, F_, BN, ADc, ADc, 0);
  gemm_nt2_k<<<dim3(Mmm / 128, Nn / 128, Bn), 256, 0, stream>>>(E_, F_, logS, temp);

  for (int it = 0; it < 3; ++it) {
    row_lse_k<<<BN, 256, 0, stream>>>(logS, it == 0 ? nullptr : colLse);
    col_part_k<<<dim3(Mmm / 256, NSPLIT, Bn), 256, 0, stream>>>(logS, pmax, psum);
    col_comb_k<<<dim3(Mmm / 256, Bn), 256, 0, stream>>>(pmax, psum, colLse);
  }
  finalize_k<<<BN, 256, 0, stream>>>(logS, colLse, tgt_pts, outS, outConf, conf, tcp);

  // 6) Kabsch
  kabsch_red_k<<<Bn, 256, 0, stream>>>(conf, src_pts, tcp, kab);
  kabsch_svd_k<<<1, 64, 0, stream>>>(kab, outR, outT);

  // 7) global pooling head
  xmax_k<<<Bn, 256, 0, stream>>>(G_, xmax);
  gemm_k<<<dim3(GFDc / 64, 1), 256, 0, stream>>>(xmax, gp_w, gp_b, nullptr, glraw, Bn, ADc, GFDc, 0);
  ln_k<<<Bn, 256, 0, stream>>>(glraw, gp_g, gp_bb, gl, GFDc, 1);
  combined_k<<<(Bn * 2 * GFDc) / 256, 256, 0, stream>>>(gl, tgt_glob, outC);
}

// Round 10
// 1640.118 us; speedup vs baseline: 2.9271x; 1.0839x over previous
//
#include <hip/hip_runtime.h>
#include <hip/hip_bf16.h>
#include <math.h>

constexpr int Bn  = 4;
constexpr int Nn  = 1024;
constexpr int Mmm = 1024;
constexpr int PFDc = 1024;
constexpr int ADc  = 256;
constexpr int GFDc = 512;
constexpr int Hc   = 4;
constexpr int NRc  = 16;
constexpr int NSPLIT = 32;
constexpr float COEFFc = -28.125f;    // -0.5/(CUT/(NR-1))^2
constexpr float SCALEc = 0.125f;      // DH^-0.5
constexpr float STEPc  = 2.0f / 15.0f;

__device__ __forceinline__ float addf(float a, float b) { return a + b; }
__device__ __forceinline__ double addd(double a, double b) { return a + b; }

#define BLK_REDUCE_F(OP, VAR, RES) \
  red[tid] = (VAR); __syncthreads(); \
  for (int st_ = 128; st_ > 0; st_ >>= 1) { if (tid < st_) red[tid] = OP(red[tid], red[tid + st_]); __syncthreads(); } \
  (RES) = red[0]; __syncthreads();

#define BLK_REDUCE_D(OP, VAR, RES) \
  redd[tid] = (VAR); __syncthreads(); \
  for (int st_ = 128; st_ > 0; st_ >>= 1) { if (tid < st_) redd[tid] = OP(redd[tid], redd[tid + st_]); __syncthreads(); } \
  (RES) = redd[0]; __syncthreads();

// ---------------------------------------------------------------------------
// Tiled GEMM: 64x64 tile, BK=16, 4x4 per thread, fp32. (kept for tiny shapes)
// ---------------------------------------------------------------------------
__global__ __launch_bounds__(256) void gemm_k(
    const float* __restrict__ A, const float* __restrict__ W, const float* __restrict__ bias,
    const float* __restrict__ addsrc, float* __restrict__ C,
    int R, int K, int Cc, int act)
{
  __shared__ __align__(16) float As[16][68];   // [k][row]
  __shared__ __align__(16) float Ws[16][68];   // [k][col]
  const int tid = threadIdx.x;
  const int tx = tid & 15, ty = tid >> 4;
  const int r0 = blockIdx.y * 64, c0 = blockIdx.x * 64;
  float acc[4][4] = {};
  for (int k0 = 0; k0 < K; k0 += 16) {
    #pragma unroll
    for (int j = 0; j < 4; ++j) {
      int e = tid + j * 256;
      int ar = e >> 4, ak = e & 15;
      int gr = r0 + ar;
      As[ak][ar] = (gr < R) ? A[(size_t)gr * K + k0 + ak] : 0.f;
    }
    #pragma unroll
    for (int j = 0; j < 4; ++j) {
      int e = tid + j * 256;
      int wk = e >> 6, wc = e & 63;
      int gc = c0 + wc;
      Ws[wk][wc] = (gc < Cc) ? W[(size_t)(k0 + wk) * Cc + gc] : 0.f;
    }
    __syncthreads();
    #pragma unroll
    for (int kk = 0; kk < 16; ++kk) {
      float4 av = *(const float4*)&As[kk][ty * 4];
      float4 wv = *(const float4*)&Ws[kk][tx * 4];
      float a[4] = {av.x, av.y, av.z, av.w};
      float w[4] = {wv.x, wv.y, wv.z, wv.w};
      #pragma unroll
      for (int i = 0; i < 4; ++i)
        #pragma unroll
        for (int j = 0; j < 4; ++j)
          acc[i][j] = fmaf(a[i], w[j], acc[i][j]);
    }
    __syncthreads();
  }
  #pragma unroll
  for (int i = 0; i < 4; ++i) {
    int r = r0 + ty * 4 + i;
    if (r >= R) continue;
    #pragma unroll
    for (int j = 0; j < 4; ++j) {
      int c = c0 + tx * 4 + j;
      if (c >= Cc) continue;
      float v = acc[i][j] + bias[c];
      if (addsrc) v += addsrc[(size_t)r * Cc + c];
      if (act == 1) v = 0.5f * v * (1.f + erff(v * 0.70710678118654752f));
      C[(size_t)r * Cc + c] = v;
    }
  }
}

// ---------------------------------------------------------------------------
// 1-wave GEMM: 64 threads, 64x64 tile, BK=16, 8x8 per thread, fp32.
// 1 B of LDS per FMA (vs 2 for 4x4) -> VALU-bound. Requires R%64==0, Cc%64==0.
// ---------------------------------------------------------------------------
__global__ __launch_bounds__(64) void gemm3_k(
    const float* __restrict__ A, const float* __restrict__ W, const float* __restrict__ bias,
    const float* __restrict__ addsrc, float* __restrict__ C,
    int R, int K, int Cc, int act)
{
  __shared__ __align__(16) float As[16][68];   // [k][row]
  __shared__ __align__(16) float Ws[16][68];   // [k][col]
  const int tid = threadIdx.x;
  const int tx = tid & 7, ty = tid >> 3;
  const int r0 = blockIdx.y * 64, c0 = blockIdx.x * 64;
  float acc[8][8] = {};
  for (int k0 = 0; k0 < K; k0 += 16) {
    #pragma unroll
    for (int j = 0; j < 16; ++j) {
      int e = j * 64 + tid;
      int ar = e >> 4, ak = e & 15;
      As[ak][ar] = A[(size_t)(r0 + ar) * K + k0 + ak];
      Ws[j][tid] = W[(size_t)(k0 + j) * Cc + c0 + tid];
    }
    __syncthreads();
    #pragma unroll
    for (int kk = 0; kk < 16; ++kk) {
      float a[8], w[8];
      *(float4*)&a[0] = *(const float4*)&As[kk][ty * 8];
      *(float4*)&a[4] = *(const float4*)&As[kk][ty * 8 + 4];
      *(float4*)&w[0] = *(const float4*)&Ws[kk][tx * 8];
      *(float4*)&w[4] = *(const float4*)&Ws[kk][tx * 8 + 4];
      #pragma unroll
      for (int i = 0; i < 8; ++i)
        #pragma unroll
        for (int j = 0; j < 8; ++j)
          acc[i][j] = fmaf(a[i], w[j], acc[i][j]);
    }
    __syncthreads();
  }
  #pragma unroll
  for (int i = 0; i < 8; ++i) {
    int r = r0 + ty * 8 + i;
    #pragma unroll
    for (int j = 0; j < 8; ++j) {
      int c = c0 + tx * 8 + j;
      float v = acc[i][j] + bias[c];
      if (addsrc) v += addsrc[(size_t)r * Cc + c];
      if (act == 1) v = 0.5f * v * (1.f + erff(v * 0.70710678118654752f));
      C[(size_t)r * Cc + c] = v;
    }
  }
}

// ---------------------------------------------------------------------------
// 1-wave batched NT GEMM: logS[b][n][m] = (1/tau)*sum_k A[b,n,k]*Bm[b,m,k]
// 64 threads, 64x64 tile, 8x8 per thread. Grid (M/64, N/64, B) = 1024 blocks.
// ---------------------------------------------------------------------------
__global__ __launch_bounds__(64) void gemm_nt3_k(
    const float* __restrict__ A, const float* __restrict__ Bm, float* __restrict__ C,
    const float* __restrict__ temp)
{
  const int K = ADc;
  __shared__ __align__(16) float As[16][68];
  __shared__ __align__(16) float Bs[16][68];
  const int tid = threadIdx.x;
  const int tx = tid & 7, ty = tid >> 3;
  const int b = blockIdx.z;
  const int r0 = blockIdx.y * 64, c0 = blockIdx.x * 64;
  const float* Ab = A + (size_t)b * Nn * K;
  const float* Bb = Bm + (size_t)b * Mmm * K;
  float* Cb = C + (size_t)b * Nn * Mmm;
  float tau = fminf(fmaxf(temp[0], 0.01f), 1.0f);
  float inv_tau = 1.f / tau;
  float acc[8][8] = {};
  for (int k0 = 0; k0 < K; k0 += 16) {
    #pragma unroll
    for (int j = 0; j < 16; ++j) {
      int e = j * 64 + tid;
      int ar = e >> 4, ak = e & 15;
      As[ak][ar] = Ab[(size_t)(r0 + ar) * K + k0 + ak];
      Bs[ak][ar] = Bb[(size_t)(c0 + ar) * K + k0 + ak];
    }
    __syncthreads();
    #pragma unroll
    for (int kk = 0; kk < 16; ++kk) {
      float a[8], w[8];
      *(float4*)&a[0] = *(const float4*)&As[kk][ty * 8];
      *(float4*)&a[4] = *(const float4*)&As[kk][ty * 8 + 4];
      *(float4*)&w[0] = *(const float4*)&Bs[kk][tx * 8];
      *(float4*)&w[4] = *(const float4*)&Bs[kk][tx * 8 + 4];
      #pragma unroll
      for (int i = 0; i < 8; ++i)
        #pragma unroll
        for (int j = 0; j < 8; ++j)
          acc[i][j] = fmaf(a[i], w[j], acc[i][j]);
    }
    __syncthreads();
  }
  #pragma unroll
  for (int i = 0; i < 8; ++i) {
    int r = r0 + ty * 8 + i;
    #pragma unroll
    for (int j = 0; j < 8; ++j) {
      int c = c0 + tx * 8 + j;
      Cb[(size_t)r * Mmm + c] = acc[i][j] * inv_tau;
    }
  }
}

// ---------------------------------------------------------------------------
// LayerNorm (+ optional ReLU): one block per row
// ---------------------------------------------------------------------------
__global__ __launch_bounds__(256) void ln_k(
    const float* __restrict__ in, const float* __restrict__ g, const float* __restrict__ bb,
    float* __restrict__ out, int Cc, int relu)
{
  const int tid = threadIdx.x;
  const int row = blockIdx.x;
  const float* x = in + (size_t)row * Cc;
  float* o = out + (size_t)row * Cc;
  __shared__ float red[256];
  float s = 0.f;
  for (int j = tid; j < Cc; j += 256) s += x[j];
  float tot; BLK_REDUCE_F(addf, s, tot);
  float mu = tot / Cc;
  float s2 = 0.f;
  for (int j = tid; j < Cc; j += 256) { float d = x[j] - mu; s2 += d * d; }
  float tot2; BLK_REDUCE_F(addf, s2, tot2);
  float inv = 1.f / sqrtf(tot2 / Cc + 1e-5f);
  for (int j = tid; j < Cc; j += 256) {
    float v = (x[j] - mu) * inv * g[j] + bb[j];
    if (relu) v = fmaxf(v, 0.f);
    o[j] = v;
  }
}

// ---------------------------------------------------------------------------
// Flash cross-attention, Q-tiled (validated round 8).
// ---------------------------------------------------------------------------
__global__ __launch_bounds__(256) void fattn(
    const float* __restrict__ q, const float* __restrict__ k, const float* __restrict__ v,
    const float* __restrict__ src_pts, const float* __restrict__ tgt_pts,
    const float* __restrict__ rbfw, float* __restrict__ ctx)
{
  const int bh = blockIdx.x;
  const int b = bh >> 2, h = bh & 3;
  const int n0 = blockIdx.y * 64;
  const int tid = threadIdx.x;
  const int tx = tid & 15, ty = tid >> 4;

  __shared__ __align__(16) float Qs[64][68];   // [d][n]
  __shared__ __align__(16) float Ks[64][68];   // [d][m]
  __shared__ __align__(16) float Vs[64][68];   // [m][d]
  __shared__ __align__(16) float Ps[64][68];   // [n][m]
  __shared__ float spx[64], spy[64], spz[64];
  __shared__ float tpx[64], tpy[64], tpz[64];
  __shared__ float rw[16];
  __shared__ float mrun[64], lrun[64], alpha_s[64], mnew_s[64];
  __shared__ float rowred[64][17];

  #pragma unroll
  for (int c = 0; c < 16; ++c) {
    int e = c * 256 + tid;
    int n = e >> 6, d = e & 63;
    Qs[d][n] = q[((size_t)b * Nn + n0 + n) * ADc + h * 64 + d];
  }
  if (tid < 64) {
    spx[tid] = src_pts[((size_t)b * Nn + n0 + tid) * 3 + 0];
    spy[tid] = src_pts[((size_t)b * Nn + n0 + tid) * 3 + 1];
    spz[tid] = src_pts[((size_t)b * Nn + n0 + tid) * 3 + 2];
    mrun[tid] = -1e30f;
    lrun[tid] = 0.f;
  }
  if (tid < NRc) rw[tid] = rbfw[tid * Hc + h];

  float O[4][4] = {};

  for (int t = 0; t < Mmm / 64; ++t) {
    const int m0 = t * 64;
    __syncthreads();
    #pragma unroll
    for (int c = 0; c < 16; ++c) {
      int e = c * 256 + tid;
      int mm = e >> 6, d = e & 63;
      float kvv = k[((size_t)b * Mmm + m0 + mm) * ADc + h * 64 + d];
      float vvv = v[((size_t)b * Mmm + m0 + mm) * ADc + h * 64 + d];
      Ks[d][mm] = kvv;
      Vs[mm][d] = vvv;
    }
    if (tid < 64) {
      tpx[tid] = tgt_pts[((size_t)b * Mmm + m0 + tid) * 3 + 0];
      tpy[tid] = tgt_pts[((size_t)b * Mmm + m0 + tid) * 3 + 1];
      tpz[tid] = tgt_pts[((size_t)b * Mmm + m0 + tid) * 3 + 2];
    }
    __syncthreads();

    float S[4][4] = {};
    #pragma unroll
    for (int d = 0; d < 64; ++d) {
      float4 qv = *(const float4*)&Qs[d][ty * 4];
      float4 kv = *(const float4*)&Ks[d][tx * 4];
      float a[4] = {qv.x, qv.y, qv.z, qv.w};
      float w[4] = {kv.x, kv.y, kv.z, kv.w};
      #pragma unroll
      for (int i = 0; i < 4; ++i)
        #pragma unroll
        for (int j = 0; j < 4; ++j)
          S[i][j] = fmaf(a[i], w[j], S[i][j]);
    }
    #pragma unroll
    for (int i = 0; i < 4; ++i) {
      int n = ty * 4 + i;
      float s0 = spx[n], s1 = spy[n], s2 = spz[n];
      float ssq = s0 * s0 + s1 * s1 + s2 * s2;
      float rmx = -1e30f;
      #pragma unroll
      for (int j = 0; j < 4; ++j) {
        int mj = tx * 4 + j;
        float t0 = tpx[mj], t1 = tpy[mj], t2 = tpz[mj];
        float d2 = ssq + t0 * t0 + t1 * t1 + t2 * t2 - 2.f * (s0 * t0 + s1 * t1 + s2 * t2);
        float dist = sqrtf(fmaxf(d2, 0.f));
        float bias = 0.f;
        #pragma unroll
        for (int r = 0; r < NRc; ++r) {
          float dd = dist - STEPc * r;
          bias = fmaf(expf(COEFFc * dd * dd), rw[r], bias);
        }
        float lv = S[i][j] * SCALEc + bias;
        S[i][j] = lv;
        rmx = fmaxf(rmx, lv);
      }
      rowred[n][tx] = rmx;
    }
    __syncthreads();
    if (tid < 64) {
      float mt = rowred[tid][0];
      #pragma unroll
      for (int s = 1; s < 16; ++s) mt = fmaxf(mt, rowred[tid][s]);
      float mn = fmaxf(mrun[tid], mt);
      mnew_s[tid] = mn;
      alpha_s[tid] = expf(mrun[tid] - mn);
      mrun[tid] = mn;
    }
    __syncthreads();
    #pragma unroll
    for (int i = 0; i < 4; ++i) {
      int n = ty * 4 + i;
      float mn = mnew_s[n];
      float p0 = expf(S[i][0] - mn);
      float p1 = expf(S[i][1] - mn);
      float p2 = expf(S[i][2] - mn);
      float p3 = expf(S[i][3] - mn);
      *(float4*)&Ps[n][tx * 4] = make_float4(p0, p1, p2, p3);
      rowred[n][tx] = p0 + p1 + p2 + p3;
    }
    __syncthreads();
    if (tid < 64) {
      float ls = 0.f;
      #pragma unroll
      for (int s = 0; s < 16; ++s) ls += rowred[tid][s];
      lrun[tid] = lrun[tid] * alpha_s[tid] + ls;
    }
    #pragma unroll
    for (int i = 0; i < 4; ++i) {
      float a = alpha_s[ty * 4 + i];
      #pragma unroll
      for (int j = 0; j < 4; ++j) O[i][j] *= a;
    }
    #pragma unroll
    for (int m = 0; m < 64; ++m) {
      float4 vv = *(const float4*)&Vs[m][tx * 4];
      float w[4] = {vv.x, vv.y, vv.z, vv.w};
      #pragma unroll
      for (int i = 0; i < 4; ++i) {
        float p = Ps[ty * 4 + i][m];
        #pragma unroll
        for (int j = 0; j < 4; ++j)
          O[i][j] = fmaf(p, w[j], O[i][j]);
      }
    }
  }
  __syncthreads();
  #pragma unroll
  for (int i = 0; i < 4; ++i) {
    int n = ty * 4 + i;
    float invl = 1.f / lrun[n];
    #pragma unroll
    for (int j = 0; j < 4; ++j)
      ctx[((size_t)b * Nn + n0 + n) * ADc + h * 64 + tx * 4 + j] = O[i][j] * invl;
  }
}

// ---------------------------------------------------------------------------
// Sinkhorn row pass (fuses previous colLse subtraction).
// ---------------------------------------------------------------------------
__global__ __launch_bounds__(256) void row_lse_k(float* __restrict__ logS, const float* __restrict__ colLse)
{
  const int tid = threadIdx.x;
  const int bn = blockIdx.x;
  const int b = bn >> 10;
  float* row = logS + (size_t)bn * Mmm;
  const float* cl = colLse ? colLse + (size_t)b * Mmm : nullptr;
  __shared__ float buf[Mmm];
  __shared__ float red[256];
  float lmax = -1e30f;
  for (int j = tid; j < Mmm; j += 256) {
    float v = row[j];
    if (cl) v -= cl[j];
    buf[j] = v;
    lmax = fmaxf(lmax, v);
  }
  float rmax; BLK_REDUCE_F(fmaxf, lmax, rmax);
  float ls = 0.f;
  for (int j = tid; j < Mmm; j += 256) ls += expf(buf[j] - rmax);
  float rsum; BLK_REDUCE_F(addf, ls, rsum);
  float lse = rmax + logf(rsum);
  for (int j = tid; j < Mmm; j += 256) row[j] = buf[j] - lse;
}

// Column-LSE partials: grid (M/256, NSPLIT, B); online max/sum over N/NSPLIT rows
__global__ __launch_bounds__(256) void col_part_k(
    const float* __restrict__ logS, float* __restrict__ pmax, float* __restrict__ psum)
{
  const int b = blockIdx.z, sp = blockIdx.y;
  const int m = blockIdx.x * 256 + threadIdx.x;
  const int RPS = Nn / NSPLIT;
  const float* base = logS + ((size_t)b * Nn + sp * RPS) * Mmm + m;
  float mx = -1e30f, sm = 0.f;
  for (int i = 0; i < RPS; ++i) {
    float v = base[(size_t)i * Mmm];
    if (v > mx) { sm = sm * expf(mx - v) + 1.f; mx = v; }
    else sm += expf(v - mx);
  }
  size_t o = ((size_t)b * NSPLIT + sp) * Mmm + m;
  pmax[o] = mx; psum[o] = sm;
}

__global__ __launch_bounds__(256) void col_comb_k(
    const float* __restrict__ pmax, const float* __restrict__ psum, float* __restrict__ colLse)
{
  const int b = blockIdx.y;
  const int m = blockIdx.x * 256 + threadIdx.x;
  float mx = -1e30f;
  for (int s = 0; s < NSPLIT; ++s) mx = fmaxf(mx, pmax[((size_t)b * NSPLIT + s) * Mmm + m]);
  float sm = 0.f;
  for (int s = 0; s < NSPLIT; ++s) {
    size_t o = ((size_t)b * NSPLIT + s) * Mmm + m;
    sm += psum[o] * expf(pmax[o] - mx);
  }
  colLse[(size_t)b * Mmm + m] = mx + logf(sm);
}

// ---------------------------------------------------------------------------
// Finalize: S = exp(logS - colLse); fp32 outputs.
// ---------------------------------------------------------------------------
__global__ __launch_bounds__(256) void finalize_k(
    const float* __restrict__ logS, const float* __restrict__ colLse,
    const float* __restrict__ tgt_pts, float* __restrict__ outS, float* __restrict__ outConf,
    float* __restrict__ conf, float* __restrict__ tcp)
{
  const int tid = threadIdx.x;
  const int bn = blockIdx.x;
  const int b = bn >> 10;
  const float* row = logS + (size_t)bn * Mmm;
  const float* cl = colLse + (size_t)b * Mmm;
  const float* tp = tgt_pts + (size_t)b * Mmm * 3;
  __shared__ float red[256];
  float mx = -1e30f, s0 = 0.f, s1 = 0.f, s2 = 0.f;
  for (int m = tid; m < Mmm; m += 256) {
    float sv = expf(row[m] - cl[m]);
    outS[(size_t)bn * Mmm + m] = sv;
    mx = fmaxf(mx, sv);
    s0 = fmaf(sv, tp[m * 3 + 0], s0);
    s1 = fmaf(sv, tp[m * 3 + 1], s1);
    s2 = fmaf(sv, tp[m * 3 + 2], s2);
  }
  float rmx, r0, r1, r2;
  BLK_REDUCE_F(fmaxf, mx, rmx);
  BLK_REDUCE_F(addf, s0, r0);
  BLK_REDUCE_F(addf, s1, r1);
  BLK_REDUCE_F(addf, s2, r2);
  if (tid == 0) {
    conf[bn] = rmx;
    outConf[bn] = rmx;
    tcp[(size_t)bn * 3 + 0] = r0;
    tcp[(size_t)bn * 3 + 1] = r1;
    tcp[(size_t)bn * 3 + 2] = r2;
  }
}

// ---------------------------------------------------------------------------
// Kabsch stage 1: per-batch weighted sums (double)
// ---------------------------------------------------------------------------
__global__ __launch_bounds__(256) void kabsch_red_k(
    const float* __restrict__ conf, const float* __restrict__ src_pts,
    const float* __restrict__ tcp, double* __restrict__ kab)
{
  const int b = blockIdx.x;
  const int tid = threadIdx.x;
  __shared__ double redd[256];
  __shared__ double sh[8];
  const float* cb = conf + (size_t)b * Nn;
  const float* sb = src_pts + (size_t)b * Nn * 3;
  const float* tb = tcp + (size_t)b * Nn * 3;

  double a = 0.0;
  for (int n = tid; n < Nn; n += 256) a += (double)cb[n];
  double wsum; BLK_REDUCE_D(addd, a, wsum);
  double inv = 1.0 / (wsum + 1e-8);

  double c0 = 0, c1 = 0, c2 = 0, t0 = 0, t1 = 0, t2 = 0;
  for (int n = tid; n < Nn; n += 256) {
    double wn = (double)cb[n] * inv;
    c0 += wn * (double)sb[n * 3 + 0];
    c1 += wn * (double)sb[n * 3 + 1];
    c2 += wn * (double)sb[n * 3 + 2];
    t0 += wn * (double)tb[n * 3 + 0];
    t1 += wn * (double)tb[n * 3 + 1];
    t2 += wn * (double)tb[n * 3 + 2];
  }
  double r;
  BLK_REDUCE_D(addd, c0, r); if (tid == 0) sh[0] = r; __syncthreads();
  BLK_REDUCE_D(addd, c1, r); if (tid == 0) sh[1] = r; __syncthreads();
  BLK_REDUCE_D(addd, c2, r); if (tid == 0) sh[2] = r; __syncthreads();
  BLK_REDUCE_D(addd, t0, r); if (tid == 0) sh[3] = r; __syncthreads();
  BLK_REDUCE_D(addd, t1, r); if (tid == 0) sh[4] = r; __syncthreads();
  BLK_REDUCE_D(addd, t2, r); if (tid == 0) sh[5] = r; __syncthreads();
  double cs[3] = {sh[0], sh[1], sh[2]};
  double ct[3] = {sh[3], sh[4], sh[5]};

  double hm[9] = {};
  for (int n = tid; n < Nn; n += 256) {
    double wn = (double)cb[n] * inv;
    double d0 = (double)sb[n * 3 + 0] - cs[0];
    double d1 = (double)sb[n * 3 + 1] - cs[1];
    double d2 = (double)sb[n * 3 + 2] - cs[2];
    double e0 = (double)tb[n * 3 + 0] - ct[0];
    double e1 = (double)tb[n * 3 + 1] - ct[1];
    double e2 = (double)tb[n * 3 + 2] - ct[2];
    hm[0] += wn * d0 * e0; hm[1] += wn * d0 * e1; hm[2] += wn * d0 * e2;
    hm[3] += wn * d1 * e0; hm[4] += wn * d1 * e1; hm[5] += wn * d1 * e2;
    hm[6] += wn * d2 * e0; hm[7] += wn * d2 * e1; hm[8] += wn * d2 * e2;
  }
  for (int i = 0; i < 9; ++i) {
    BLK_REDUCE_D(addd, hm[i], r);
    if (tid == 0) kab[(size_t)b * 16 + i] = r;
    __syncthreads();
  }
  if (tid == 0) {
    for (int i = 0; i < 3; ++i) {
      kab[(size_t)b * 16 + 9 + i]  = cs[i];
      kab[(size_t)b * 16 + 12 + i] = ct[i];
    }
  }
}

// ---------------------------------------------------------------------------
// Kabsch stage 2 — numpy-mirror SVD; fp32 outputs.
// ---------------------------------------------------------------------------
__device__ __forceinline__ double trip(const double a[3], const double b[3], const double c[3]) {
  return a[0] * (b[1] * c[2] - b[2] * c[1])
       - a[1] * (b[0] * c[2] - b[2] * c[0])
       + a[2] * (b[0] * c[1] - b[1] * c[0]);
}

__global__ void kabsch_svd_k(const double* __restrict__ kab, float* __restrict__ outR, float* __restrict__ outT)
{
  const int b = threadIdx.x;
  if (b >= Bn) return;
  const double* kb = kab + (size_t)b * 16;
  double A[3][3], cs[3], ct[3];
  for (int i = 0; i < 3; ++i)
    for (int j = 0; j < 3; ++j) A[i][j] = kb[i * 3 + j];
  for (int i = 0; i < 3; ++i) { cs[i] = kb[9 + i]; ct[i] = kb[12 + i]; }

  double Km[3][3];
  for (int i = 0; i < 3; ++i)
    for (int j = 0; j < 3; ++j)
      Km[i][j] = A[0][i] * A[0][j] + A[1][i] * A[1][j] + A[2][i] * A[2][j];
  double V[3][3] = {{1, 0, 0}, {0, 1, 0}, {0, 0, 1}};
  const int PP[3] = {0, 0, 1}, QQ[3] = {1, 2, 2};
  for (int sweep = 0; sweep < 30; ++sweep) {
    for (int pi = 0; pi < 3; ++pi) {
      int p = PP[pi], qd = QQ[pi];
      double apq = Km[p][qd];
      if (fabs(apq) < 1e-300) continue;
      double theta = (Km[qd][qd] - Km[p][p]) / (2.0 * apq);
      double tt = (theta >= 0 ? 1.0 : -1.0) / (fabs(theta) + sqrt(theta * theta + 1.0));
      double cc = 1.0 / sqrt(tt * tt + 1.0), ss = tt * cc;
      for (int r = 0; r < 3; ++r) {
        double kp = Km[r][p], kq = Km[r][qd];
        Km[r][p] = cc * kp - ss * kq; Km[r][qd] = ss * kp + cc * kq;
      }
      for (int c = 0; c < 3; ++c) {
        double kp = Km[p][c], kq = Km[qd][c];
        Km[p][c] = cc * kp - ss * kq; Km[qd][c] = ss * kp + cc * kq;
      }
      for (int r = 0; r < 3; ++r) {
        double vp = V[r][p], vq = V[r][qd];
        V[r][p] = cc * vp - ss * vq; V[r][qd] = ss * vp + cc * vq;
      }
    }
  }
  double lam[3] = {Km[0][0], Km[1][1], Km[2][2]};
  int i0 = 0, i1 = 1, i2 = 2, tsw;
  if (lam[i0] < lam[i1]) { tsw = i0; i0 = i1; i1 = tsw; }
  if (lam[i0] < lam[i2]) { tsw = i0; i0 = i2; i2 = tsw; }
  if (lam[i1] < lam[i2]) { tsw = i1; i1 = i2; i2 = tsw; }
  double vv[3][3];
  for (int r = 0; r < 3; ++r) { vv[0][r] = V[r][i0]; vv[1][r] = V[r][i1]; vv[2][r] = V[r][i2]; }
  double sg[3] = { sqrt(fmax(lam[i0], 0.0)), sqrt(fmax(lam[i1], 0.0)), sqrt(fmax(lam[i2], 0.0)) };

  double uu[3][3];
  double eps = 1e-12 * (sg[0] > 0 ? sg[0] : 1.0);
  if (sg[0] > eps) {
    for (int r = 0; r < 3; ++r)
      uu[0][r] = (A[r][0] * vv[0][0] + A[r][1] * vv[0][1] + A[r][2] * vv[0][2]) / sg[0];
    double n = sqrt(uu[0][0]*uu[0][0] + uu[0][1]*uu[0][1] + uu[0][2]*uu[0][2]);
    if (n > 1e-14) { uu[0][0]/=n; uu[0][1]/=n; uu[0][2]/=n; }
  } else { uu[0][0]=1; uu[0][1]=0; uu[0][2]=0; }
  if (sg[1] > eps) {
    for (int r = 0; r < 3; ++r)
      uu[1][r] = (A[r][0] * vv[1][0] + A[r][1] * vv[1][1] + A[r][2] * vv[1][2]) / sg[1];
  } else {
    int ax = (fabs(uu[0][0]) <= fabs(uu[0][1]) && fabs(uu[0][0]) <= fabs(uu[0][2])) ? 0
           : (fabs(uu[0][1]) <= fabs(uu[0][2]) ? 1 : 2);
    uu[1][0] = uu[1][1] = uu[1][2] = 0.0; uu[1][ax] = 1.0;
  }
  {
    double pr = uu[0][0]*uu[1][0] + uu[0][1]*uu[1][1] + uu[0][2]*uu[1][2];
    for (int r = 0; r < 3; ++r) uu[1][r] -= pr * uu[0][r];
    double n = sqrt(uu[1][0]*uu[1][0] + uu[1][1]*uu[1][1] + uu[1][2]*uu[1][2]);
    if (n > 1e-14) { uu[1][0]/=n; uu[1][1]/=n; uu[1][2]/=n; }
  }
  if (sg[2] > eps) {
    for (int r = 0; r < 3; ++r)
      uu[2][r] = (A[r][0] * vv[2][0] + A[r][1] * vv[2][1] + A[r][2] * vv[2][2]) / sg[2];
    double p0 = uu[0][0]*uu[2][0] + uu[0][1]*uu[2][1] + uu[0][2]*uu[2][2];
    double p1 = uu[1][0]*uu[2][0] + uu[1][1]*uu[2][1] + uu[1][2]*uu[2][2];
    for (int r = 0; r < 3; ++r) uu[2][r] -= p0 * uu[0][r] + p1 * uu[1][r];
    double n = sqrt(uu[2][0]*uu[2][0] + uu[2][1]*uu[2][1] + uu[2][2]*uu[2][2]);
    if (n > 1e-14) { uu[2][0]/=n; uu[2][1]/=n; uu[2][2]/=n; }
    else {
      uu[2][0] = uu[0][1]*uu[1][2] - uu[0][2]*uu[1][1];
      uu[2][1] = uu[0][2]*uu[1][0] - uu[0][0]*uu[1][2];
      uu[2][2] = uu[0][0]*uu[1][1] - uu[0][1]*uu[1][0];
    }
  } else {
    uu[2][0] = uu[0][1]*uu[1][2] - uu[0][2]*uu[1][1];
    uu[2][1] = uu[0][2]*uu[1][0] - uu[0][0]*uu[1][2];
    uu[2][2] = uu[0][0]*uu[1][1] - uu[0][1]*uu[1][0];
  }

  double detU = trip(uu[0], uu[1], uu[2]);
  double detV = trip(vv[0], vv[1], vv[2]);
  double d = (detU * detV < 0.0) ? -1.0 : 1.0;

  double R[3][3];
  for (int i = 0; i < 3; ++i)
    for (int j = 0; j < 3; ++j)
      R[i][j] = vv[0][i] * uu[0][j] + vv[1][i] * uu[1][j] + d * vv[2][i] * uu[2][j];
  for (int i = 0; i < 3; ++i) {
    double t = ct[i] - (R[i][0] * cs[0] + R[i][1] * cs[1] + R[i][2] * cs[2]);
    outT[(size_t)b * 3 + i] = (float)t;
    for (int j = 0; j < 3; ++j)
      outR[(size_t)b * 9 + i * 3 + j] = (float)R[i][j];
  }
}

// x.max over N
__global__ __launch_bounds__(256) void xmax_k(const float* __restrict__ x, float* __restrict__ xmax)
{
  const int b = blockIdx.x;
  const int d = threadIdx.x;
  float mx = -1e30f;
  for (int n = 0; n < Nn; ++n) mx = fmaxf(mx, x[((size_t)b * Nn + n) * ADc + d]);
  xmax[(size_t)b * ADc + d] = mx;
}

__global__ __launch_bounds__(256) void combined_k(
    const float* __restrict__ gl, const float* __restrict__ tgt_global, float* __restrict__ outC)
{
  int i = blockIdx.x * 256 + threadIdx.x;
  int b = i >> 10, j = i & 1023;
  float v = (j < GFDc) ? gl[(size_t)b * GFDc + j] : tgt_global[(size_t)b * GFDc + (j - GFDc)];
  outC[i] = v;
}

// ---------------------------------------------------------------------------
extern "C" void kernel_launch(void* const* d_in, const int* in_sizes, int n_in,
                              void* d_out, int out_size, void* d_ws, size_t ws_size,
                              hipStream_t stream) {
  (void)in_sizes; (void)n_in; (void)out_size; (void)ws_size;
  const float* src_feats = (const float*)d_in[0];
  const float* tgt_feats = (const float*)d_in[1];
  const float* src_pts   = (const float*)d_in[2];
  const float* tgt_pts   = (const float*)d_in[3];
  const float* tgt_glob  = (const float*)d_in[4];
  const float* sfp_w = (const float*)d_in[5];  const float* sfp_b = (const float*)d_in[6];
  const float* sfp_g = (const float*)d_in[7];  const float* sfp_bb = (const float*)d_in[8];
  const float* tfp_w = (const float*)d_in[9];  const float* tfp_b = (const float*)d_in[10];
  const float* tfp_g = (const float*)d_in[11]; const float* tfp_bb = (const float*)d_in[12];
  const float* rbf_w = (const float*)d_in[13];
  const float* qw = (const float*)d_in[14]; const float* qb = (const float*)d_in[15];
  const float* kw = (const float*)d_in[16]; const float* kb = (const float*)d_in[17];
  const float* vw = (const float*)d_in[18]; const float* vb = (const float*)d_in[19];
  const float* ow = (const float*)d_in[20]; const float* ob = (const float*)d_in[21];
  const float* n1_g = (const float*)d_in[22]; const float* n1_b = (const float*)d_in[23];
  const float* f1_w = (const float*)d_in[24]; const float* f1_b = (const float*)d_in[25];
  const float* f2_w = (const float*)d_in[26]; const float* f2_b = (const float*)d_in[27];
  const float* n2_g = (const float*)d_in[28]; const float* n2_b = (const float*)d_in[29];
  const float* scp_w = (const float*)d_in[30]; const float* scp_b = (const float*)d_in[31];
  const float* tcp_w = (const float*)d_in[32]; const float* tcp_b = (const float*)d_in[33];
  const float* temp  = (const float*)d_in[34];
  const float* gp_w = (const float*)d_in[35]; const float* gp_b = (const float*)d_in[36];
  const float* gp_g = (const float*)d_in[37]; const float* gp_bb = (const float*)d_in[38];

  float* out = (float*)d_out;
  float* outR    = out;                    // (B,3,3)
  float* outT    = out + 36;               // (B,3)
  float* outC    = out + 48;               // (B,1024)
  float* outConf = out + 48 + 4096;        // (B,N)
  float* outS    = out + 48 + 4096 + 4096; // (B,N,M)

  // overlay workspace, peak ~29.3 MB
  float* ws = (float*)d_ws;
  const size_t M1 = 1048576;
  float* A_   = ws + 0 * M1;     // raw proj / xq / h
  float* B_   = ws + 1 * M1;     // xc / ctx / ffn-hidden(lo)
  float* C_   = ws + 2 * M1;     // q / ffn-hidden(hi)
  float* D_   = ws + 3 * M1;     // tproj
  float* logS = ws + 0 * M1;     // overlays A..D after they die
  float* H2   = ws + 1 * M1;     // 2M-float FFN hidden chunk (B_+C_)
  float* E_   = ws + 4 * M1;     // k / src_corr
  float* F_   = ws + 5 * M1;     // v / tgt_corr
  float* G_   = ws + 6 * M1;     // src_proj -> x
  float* tail = ws + 7 * M1;
  float* colLse = tail;                         // 4096
  float* pmax   = colLse + 4096;                // 131072
  float* psum   = pmax + 131072;                // 131072
  float* conf   = psum + 131072;                // 4096
  float* tcp    = conf + 4096;                  // 12288
  float* xmax   = tcp + 12288;                  // 1024
  float* glraw  = xmax + 1024;                  // 2048
  float* gl     = glraw + 2048;                 // 2048
  double* kab   = (double*)(gl + 2048);         // 64 doubles

  const int BN = Bn * Nn;   // 4096

  // 1) projections + LN + ReLU
  gemm3_k<<<dim3(ADc / 64, BN / 64), 64, 0, stream>>>(src_feats, sfp_w, sfp_b, nullptr, A_, BN, PFDc, ADc, 0);
  ln_k<<<BN, 256, 0, stream>>>(A_, sfp_g, sfp_bb, G_, ADc, 1);
  gemm3_k<<<dim3(ADc / 64, BN / 64), 64, 0, stream>>>(tgt_feats, tfp_w, tfp_b, nullptr, A_, BN, PFDc, ADc, 0);
  ln_k<<<BN, 256, 0, stream>>>(A_, tfp_g, tfp_bb, D_, ADc, 1);

  // 2) pre-LN + q/k/v
  ln_k<<<BN, 256, 0, stream>>>(G_, n1_g, n1_b, A_, ADc, 0);                   // xq -> A
  gemm3_k<<<dim3(ADc / 64, BN / 64), 64, 0, stream>>>(A_, qw, qb, nullptr, C_, BN, ADc, ADc, 0);
  ln_k<<<BN, 256, 0, stream>>>(D_, n1_g, n1_b, B_, ADc, 0);                   // xc -> B
  gemm3_k<<<dim3(ADc / 64, BN / 64), 64, 0, stream>>>(B_, kw, kb, nullptr, E_, BN, ADc, ADc, 0);
  gemm3_k<<<dim3(ADc / 64, BN / 64), 64, 0, stream>>>(B_, vw, vb, nullptr, F_, BN, ADc, ADc, 0);

  // 3) flash attention (Q-tiled), out-proj + residual
  fattn<<<dim3(Bn * Hc, Nn / 64), 256, 0, stream>>>(C_, E_, F_, src_pts, tgt_pts, rbf_w, B_);  // ctx -> B
  gemm3_k<<<dim3(ADc / 64, BN / 64), 64, 0, stream>>>(B_, ow, ob, G_, G_, BN, ADc, ADc, 0);

  // 4) FFN: h -> A_ (full), hidden chunk (2048 rows) through H2 (B_+C_)
  ln_k<<<BN, 256, 0, stream>>>(G_, n2_g, n2_b, A_, ADc, 0);                   // h -> A
  for (int c = 0; c < 2; ++c) {
    const float* hA = A_ + (size_t)c * 2048 * ADc;
    float* xA = G_ + (size_t)c * 2048 * ADc;
    gemm3_k<<<dim3(1024 / 64, 2048 / 64), 64, 0, stream>>>(hA, f1_w, f1_b, nullptr, H2, 2048, ADc, 1024, 1);
    gemm3_k<<<dim3(ADc / 64, 2048 / 64), 64, 0, stream>>>(H2, f2_w, f2_b, xA, xA, 2048, 1024, ADc, 0);
  }

  // 5) correspondences + Sinkhorn (logS overlays A..D)
  gemm3_k<<<dim3(ADc / 64, BN / 64), 64, 0, stream>>>(G_, scp_w, scp_b, nullptr, E_, BN, ADc, ADc, 0);
  gemm3_k<<<dim3(ADc / 64, BN / 64), 64, 0, stream>>>(D_, tcp_w, tcp_b, nullptr, F_, BN, ADc, ADc, 0);
  gemm_nt3_k<<<dim3(Mmm / 64, Nn / 64, Bn), 64, 0, stream>>>(E_, F_, logS, temp);

  for (int it = 0; it < 3; ++it) {
    row_lse_k<<<BN, 256, 0, stream>>>(logS, it == 0 ? nullptr : colLse);
    col_part_k<<<dim3(Mmm / 256, NSPLIT, Bn), 256, 0, stream>>>(logS, pmax, psum);
    col_comb_k<<<dim3(Mmm / 256, Bn), 256, 0, stream>>>(pmax, psum, colLse);
  }
  finalize_k<<<BN, 256, 0, stream>>>(logS, colLse, tgt_pts, outS, outConf, conf, tcp);

  // 6) Kabsch
  kabsch_red_k<<<Bn, 256, 0, stream>>>(conf, src_pts, tcp, kab);
  kabsch_svd_k<<<1, 64, 0, stream>>>(kab, outR, outT);

  // 7) global pooling head
  xmax_k<<<Bn, 256, 0, stream>>>(G_, xmax);
  gemm_k<<<dim3(GFDc / 64, 1), 256, 0, stream>>>(xmax, gp_w, gp_b, nullptr, glraw, Bn, ADc, GFDc, 0);
  ln_k<<<Bn, 256, 0, stream>>>(glraw, gp_g, gp_bb, gl, GFDc, 1);
  combined_k<<<(Bn * 2 * GFDc) / 256, 256, 0, stream>>>(gl, tgt_glob, outC);
}

// Round 11
// 1488.101 us; speedup vs baseline: 3.2262x; 1.1022x over previous
//
#include <hip/hip_runtime.h>
#include <hip/hip_bf16.h>
#include <math.h>

constexpr int Bn  = 4;
constexpr int Nn  = 1024;
constexpr int Mmm = 1024;
constexpr int PFDc = 1024;
constexpr int ADc  = 256;
constexpr int GFDc = 512;
constexpr int Hc   = 4;
constexpr int NRc  = 16;
constexpr int NSPLIT = 32;
constexpr float COEFFc = -28.125f;    // -0.5/(CUT/(NR-1))^2
constexpr float SCALEc = 0.125f;      // DH^-0.5
constexpr float STEPc  = 2.0f / 15.0f;

__device__ __forceinline__ float addf(float a, float b) { return a + b; }
__device__ __forceinline__ double addd(double a, double b) { return a + b; }

#define BLK_REDUCE_F(OP, VAR, RES) \
  red[tid] = (VAR); __syncthreads(); \
  for (int st_ = 128; st_ > 0; st_ >>= 1) { if (tid < st_) red[tid] = OP(red[tid], red[tid + st_]); __syncthreads(); } \
  (RES) = red[0]; __syncthreads();

#define BLK_REDUCE_D(OP, VAR, RES) \
  redd[tid] = (VAR); __syncthreads(); \
  for (int st_ = 128; st_ > 0; st_ >>= 1) { if (tid < st_) redd[tid] = OP(redd[tid], redd[tid + st_]); __syncthreads(); } \
  (RES) = redd[0]; __syncthreads();

// ---------------------------------------------------------------------------
// Tiled GEMM: 64x64 tile, BK=16, 4x4 per thread, fp32. (kept for tiny shapes)
// ---------------------------------------------------------------------------
__global__ __launch_bounds__(256) void gemm_k(
    const float* __restrict__ A, const float* __restrict__ W, const float* __restrict__ bias,
    const float* __restrict__ addsrc, float* __restrict__ C,
    int R, int K, int Cc, int act)
{
  __shared__ __align__(16) float As[16][68];   // [k][row]
  __shared__ __align__(16) float Ws[16][68];   // [k][col]
  const int tid = threadIdx.x;
  const int tx = tid & 15, ty = tid >> 4;
  const int r0 = blockIdx.y * 64, c0 = blockIdx.x * 64;
  float acc[4][4] = {};
  for (int k0 = 0; k0 < K; k0 += 16) {
    #pragma unroll
    for (int j = 0; j < 4; ++j) {
      int e = tid + j * 256;
      int ar = e >> 4, ak = e & 15;
      int gr = r0 + ar;
      As[ak][ar] = (gr < R) ? A[(size_t)gr * K + k0 + ak] : 0.f;
    }
    #pragma unroll
    for (int j = 0; j < 4; ++j) {
      int e = tid + j * 256;
      int wk = e >> 6, wc = e & 63;
      int gc = c0 + wc;
      Ws[wk][wc] = (gc < Cc) ? W[(size_t)(k0 + wk) * Cc + gc] : 0.f;
    }
    __syncthreads();
    #pragma unroll
    for (int kk = 0; kk < 16; ++kk) {
      float4 av = *(const float4*)&As[kk][ty * 4];
      float4 wv = *(const float4*)&Ws[kk][tx * 4];
      float a[4] = {av.x, av.y, av.z, av.w};
      float w[4] = {wv.x, wv.y, wv.z, wv.w};
      #pragma unroll
      for (int i = 0; i < 4; ++i)
        #pragma unroll
        for (int j = 0; j < 4; ++j)
          acc[i][j] = fmaf(a[i], w[j], acc[i][j]);
    }
    __syncthreads();
  }
  #pragma unroll
  for (int i = 0; i < 4; ++i) {
    int r = r0 + ty * 4 + i;
    if (r >= R) continue;
    #pragma unroll
    for (int j = 0; j < 4; ++j) {
      int c = c0 + tx * 4 + j;
      if (c >= Cc) continue;
      float v = acc[i][j] + bias[c];
      if (addsrc) v += addsrc[(size_t)r * Cc + c];
      if (act == 1) v = 0.5f * v * (1.f + erff(v * 0.70710678118654752f));
      C[(size_t)r * Cc + c] = v;
    }
  }
}

// ---------------------------------------------------------------------------
// 1-wave GEMM: 64 threads, 64x64 tile, BK=16, 8x8 per thread, fp32.
// ---------------------------------------------------------------------------
__global__ __launch_bounds__(64) void gemm3_k(
    const float* __restrict__ A, const float* __restrict__ W, const float* __restrict__ bias,
    const float* __restrict__ addsrc, float* __restrict__ C,
    int R, int K, int Cc, int act)
{
  __shared__ __align__(16) float As[16][68];   // [k][row]
  __shared__ __align__(16) float Ws[16][68];   // [k][col]
  const int tid = threadIdx.x;
  const int tx = tid & 7, ty = tid >> 3;
  const int r0 = blockIdx.y * 64, c0 = blockIdx.x * 64;
  float acc[8][8] = {};
  for (int k0 = 0; k0 < K; k0 += 16) {
    #pragma unroll
    for (int j = 0; j < 16; ++j) {
      int e = j * 64 + tid;
      int ar = e >> 4, ak = e & 15;
      As[ak][ar] = A[(size_t)(r0 + ar) * K + k0 + ak];
      Ws[j][tid] = W[(size_t)(k0 + j) * Cc + c0 + tid];
    }
    __syncthreads();
    #pragma unroll
    for (int kk = 0; kk < 16; ++kk) {
      float a[8], w[8];
      *(float4*)&a[0] = *(const float4*)&As[kk][ty * 8];
      *(float4*)&a[4] = *(const float4*)&As[kk][ty * 8 + 4];
      *(float4*)&w[0] = *(const float4*)&Ws[kk][tx * 8];
      *(float4*)&w[4] = *(const float4*)&Ws[kk][tx * 8 + 4];
      #pragma unroll
      for (int i = 0; i < 8; ++i)
        #pragma unroll
        for (int j = 0; j < 8; ++j)
          acc[i][j] = fmaf(a[i], w[j], acc[i][j]);
    }
    __syncthreads();
  }
  #pragma unroll
  for (int i = 0; i < 8; ++i) {
    int r = r0 + ty * 8 + i;
    #pragma unroll
    for (int j = 0; j < 8; ++j) {
      int c = c0 + tx * 8 + j;
      float v = acc[i][j] + bias[c];
      if (addsrc) v += addsrc[(size_t)r * Cc + c];
      if (act == 1) v = 0.5f * v * (1.f + erff(v * 0.70710678118654752f));
      C[(size_t)r * Cc + c] = v;
    }
  }
}

// ---------------------------------------------------------------------------
// 1-wave batched NT GEMM: logS[b][n][m] = (1/tau)*sum_k A[b,n,k]*Bm[b,m,k]
// ---------------------------------------------------------------------------
__global__ __launch_bounds__(64) void gemm_nt3_k(
    const float* __restrict__ A, const float* __restrict__ Bm, float* __restrict__ C,
    const float* __restrict__ temp)
{
  const int K = ADc;
  __shared__ __align__(16) float As[16][68];
  __shared__ __align__(16) float Bs[16][68];
  const int tid = threadIdx.x;
  const int tx = tid & 7, ty = tid >> 3;
  const int b = blockIdx.z;
  const int r0 = blockIdx.y * 64, c0 = blockIdx.x * 64;
  const float* Ab = A + (size_t)b * Nn * K;
  const float* Bb = Bm + (size_t)b * Mmm * K;
  float* Cb = C + (size_t)b * Nn * Mmm;
  float tau = fminf(fmaxf(temp[0], 0.01f), 1.0f);
  float inv_tau = 1.f / tau;
  float acc[8][8] = {};
  for (int k0 = 0; k0 < K; k0 += 16) {
    #pragma unroll
    for (int j = 0; j < 16; ++j) {
      int e = j * 64 + tid;
      int ar = e >> 4, ak = e & 15;
      As[ak][ar] = Ab[(size_t)(r0 + ar) * K + k0 + ak];
      Bs[ak][ar] = Bb[(size_t)(c0 + ar) * K + k0 + ak];
    }
    __syncthreads();
    #pragma unroll
    for (int kk = 0; kk < 16; ++kk) {
      float a[8], w[8];
      *(float4*)&a[0] = *(const float4*)&As[kk][ty * 8];
      *(float4*)&a[4] = *(const float4*)&As[kk][ty * 8 + 4];
      *(float4*)&w[0] = *(const float4*)&Bs[kk][tx * 8];
      *(float4*)&w[4] = *(const float4*)&Bs[kk][tx * 8 + 4];
      #pragma unroll
      for (int i = 0; i < 8; ++i)
        #pragma unroll
        for (int j = 0; j < 8; ++j)
          acc[i][j] = fmaf(a[i], w[j], acc[i][j]);
    }
    __syncthreads();
  }
  #pragma unroll
  for (int i = 0; i < 8; ++i) {
    int r = r0 + ty * 8 + i;
    #pragma unroll
    for (int j = 0; j < 8; ++j) {
      int c = c0 + tx * 8 + j;
      Cb[(size_t)r * Mmm + c] = acc[i][j] * inv_tau;
    }
  }
}

// ---------------------------------------------------------------------------
// LayerNorm generic (kept for GFD=512 path)
// ---------------------------------------------------------------------------
__global__ __launch_bounds__(256) void ln_k(
    const float* __restrict__ in, const float* __restrict__ g, const float* __restrict__ bb,
    float* __restrict__ out, int Cc, int relu)
{
  const int tid = threadIdx.x;
  const int row = blockIdx.x;
  const float* x = in + (size_t)row * Cc;
  float* o = out + (size_t)row * Cc;
  __shared__ float red[256];
  float s = 0.f;
  for (int j = tid; j < Cc; j += 256) s += x[j];
  float tot; BLK_REDUCE_F(addf, s, tot);
  float mu = tot / Cc;
  float s2 = 0.f;
  for (int j = tid; j < Cc; j += 256) { float d = x[j] - mu; s2 += d * d; }
  float tot2; BLK_REDUCE_F(addf, s2, tot2);
  float inv = 1.f / sqrtf(tot2 / Cc + 1e-5f);
  for (int j = tid; j < Cc; j += 256) {
    float v = (x[j] - mu) * inv * g[j] + bb[j];
    if (relu) v = fmaxf(v, 0.f);
    o[j] = v;
  }
}

// ---------------------------------------------------------------------------
// Fast LayerNorm for Cc=256: 1 elem/thread, shuffle reductions, single pass.
// var = E[x^2] - mu^2 (guarded); values are O(1) activations -> safe.
// ---------------------------------------------------------------------------
__global__ __launch_bounds__(256) void ln2_k(
    const float* __restrict__ in, const float* __restrict__ g, const float* __restrict__ bb,
    float* __restrict__ out, int relu)
{
  const int row = blockIdx.x;
  const int tid = threadIdx.x;
  float x = in[(size_t)row * 256 + tid];
  float s = x, s2 = x * x;
  #pragma unroll
  for (int off = 32; off > 0; off >>= 1) {
    s  += __shfl_xor(s, off, 64);
    s2 += __shfl_xor(s2, off, 64);
  }
  __shared__ float as_[4], as2_[4];
  const int wv = tid >> 6, ln = tid & 63;
  if (ln == 0) { as_[wv] = s; as2_[wv] = s2; }
  __syncthreads();
  s  = as_[0] + as_[1] + as_[2] + as_[3];
  s2 = as2_[0] + as2_[1] + as2_[2] + as2_[3];
  float mu = s * (1.f / 256.f);
  float var = fmaxf(s2 * (1.f / 256.f) - mu * mu, 0.f);
  float inv = 1.f / sqrtf(var + 1e-5f);
  float v = (x - mu) * inv * g[tid] + bb[tid];
  if (relu) v = fmaxf(v, 0.f);
  out[(size_t)row * 256 + tid] = v;
}

// ---------------------------------------------------------------------------
// Flash cross-attention, Q-tiled (validated round 8).
// ---------------------------------------------------------------------------
__global__ __launch_bounds__(256) void fattn(
    const float* __restrict__ q, const float* __restrict__ k, const float* __restrict__ v,
    const float* __restrict__ src_pts, const float* __restrict__ tgt_pts,
    const float* __restrict__ rbfw, float* __restrict__ ctx)
{
  const int bh = blockIdx.x;
  const int b = bh >> 2, h = bh & 3;
  const int n0 = blockIdx.y * 64;
  const int tid = threadIdx.x;
  const int tx = tid & 15, ty = tid >> 4;

  __shared__ __align__(16) float Qs[64][68];   // [d][n]
  __shared__ __align__(16) float Ks[64][68];   // [d][m]
  __shared__ __align__(16) float Vs[64][68];   // [m][d]
  __shared__ __align__(16) float Ps[64][68];   // [n][m]
  __shared__ float spx[64], spy[64], spz[64];
  __shared__ float tpx[64], tpy[64], tpz[64];
  __shared__ float rw[16];
  __shared__ float mrun[64], lrun[64], alpha_s[64], mnew_s[64];
  __shared__ float rowred[64][17];

  #pragma unroll
  for (int c = 0; c < 16; ++c) {
    int e = c * 256 + tid;
    int n = e >> 6, d = e & 63;
    Qs[d][n] = q[((size_t)b * Nn + n0 + n) * ADc + h * 64 + d];
  }
  if (tid < 64) {
    spx[tid] = src_pts[((size_t)b * Nn + n0 + tid) * 3 + 0];
    spy[tid] = src_pts[((size_t)b * Nn + n0 + tid) * 3 + 1];
    spz[tid] = src_pts[((size_t)b * Nn + n0 + tid) * 3 + 2];
    mrun[tid] = -1e30f;
    lrun[tid] = 0.f;
  }
  if (tid < NRc) rw[tid] = rbfw[tid * Hc + h];

  float O[4][4] = {};

  for (int t = 0; t < Mmm / 64; ++t) {
    const int m0 = t * 64;
    __syncthreads();
    #pragma unroll
    for (int c = 0; c < 16; ++c) {
      int e = c * 256 + tid;
      int mm = e >> 6, d = e & 63;
      float kvv = k[((size_t)b * Mmm + m0 + mm) * ADc + h * 64 + d];
      float vvv = v[((size_t)b * Mmm + m0 + mm) * ADc + h * 64 + d];
      Ks[d][mm] = kvv;
      Vs[mm][d] = vvv;
    }
    if (tid < 64) {
      tpx[tid] = tgt_pts[((size_t)b * Mmm + m0 + tid) * 3 + 0];
      tpy[tid] = tgt_pts[((size_t)b * Mmm + m0 + tid) * 3 + 1];
      tpz[tid] = tgt_pts[((size_t)b * Mmm + m0 + tid) * 3 + 2];
    }
    __syncthreads();

    float S[4][4] = {};
    #pragma unroll
    for (int d = 0; d < 64; ++d) {
      float4 qv = *(const float4*)&Qs[d][ty * 4];
      float4 kv = *(const float4*)&Ks[d][tx * 4];
      float a[4] = {qv.x, qv.y, qv.z, qv.w};
      float w[4] = {kv.x, kv.y, kv.z, kv.w};
      #pragma unroll
      for (int i = 0; i < 4; ++i)
        #pragma unroll
        for (int j = 0; j < 4; ++j)
          S[i][j] = fmaf(a[i], w[j], S[i][j]);
    }
    #pragma unroll
    for (int i = 0; i < 4; ++i) {
      int n = ty * 4 + i;
      float s0 = spx[n], s1 = spy[n], s2 = spz[n];
      float ssq = s0 * s0 + s1 * s1 + s2 * s2;
      float rmx = -1e30f;
      #pragma unroll
      for (int j = 0; j < 4; ++j) {
        int mj = tx * 4 + j;
        float t0 = tpx[mj], t1 = tpy[mj], t2 = tpz[mj];
        float d2 = ssq + t0 * t0 + t1 * t1 + t2 * t2 - 2.f * (s0 * t0 + s1 * t1 + s2 * t2);
        float dist = sqrtf(fmaxf(d2, 0.f));
        float bias = 0.f;
        #pragma unroll
        for (int r = 0; r < NRc; ++r) {
          float dd = dist - STEPc * r;
          bias = fmaf(expf(COEFFc * dd * dd), rw[r], bias);
        }
        float lv = S[i][j] * SCALEc + bias;
        S[i][j] = lv;
        rmx = fmaxf(rmx, lv);
      }
      rowred[n][tx] = rmx;
    }
    __syncthreads();
    if (tid < 64) {
      float mt = rowred[tid][0];
      #pragma unroll
      for (int s = 1; s < 16; ++s) mt = fmaxf(mt, rowred[tid][s]);
      float mn = fmaxf(mrun[tid], mt);
      mnew_s[tid] = mn;
      alpha_s[tid] = expf(mrun[tid] - mn);
      mrun[tid] = mn;
    }
    __syncthreads();
    #pragma unroll
    for (int i = 0; i < 4; ++i) {
      int n = ty * 4 + i;
      float mn = mnew_s[n];
      float p0 = expf(S[i][0] - mn);
      float p1 = expf(S[i][1] - mn);
      float p2 = expf(S[i][2] - mn);
      float p3 = expf(S[i][3] - mn);
      *(float4*)&Ps[n][tx * 4] = make_float4(p0, p1, p2, p3);
      rowred[n][tx] = p0 + p1 + p2 + p3;
    }
    __syncthreads();
    if (tid < 64) {
      float ls = 0.f;
      #pragma unroll
      for (int s = 0; s < 16; ++s) ls += rowred[tid][s];
      lrun[tid] = lrun[tid] * alpha_s[tid] + ls;
    }
    #pragma unroll
    for (int i = 0; i < 4; ++i) {
      float a = alpha_s[ty * 4 + i];
      #pragma unroll
      for (int j = 0; j < 4; ++j) O[i][j] *= a;
    }
    #pragma unroll
    for (int m = 0; m < 64; ++m) {
      float4 vv = *(const float4*)&Vs[m][tx * 4];
      float w[4] = {vv.x, vv.y, vv.z, vv.w};
      #pragma unroll
      for (int i = 0; i < 4; ++i) {
        float p = Ps[ty * 4 + i][m];
        #pragma unroll
        for (int j = 0; j < 4; ++j)
          O[i][j] = fmaf(p, w[j], O[i][j]);
      }
    }
  }
  __syncthreads();
  #pragma unroll
  for (int i = 0; i < 4; ++i) {
    int n = ty * 4 + i;
    float invl = 1.f / lrun[n];
    #pragma unroll
    for (int j = 0; j < 4; ++j)
      ctx[((size_t)b * Nn + n0 + n) * ADc + h * 64 + tx * 4 + j] = O[i][j] * invl;
  }
}

// ---------------------------------------------------------------------------
// Sinkhorn row pass, register-resident: float4 read, online shuffle reduce,
// float4 writeback. Fuses previous colLse subtraction.
// ---------------------------------------------------------------------------
__global__ __launch_bounds__(256) void row_lse2_k(float* __restrict__ logS, const float* __restrict__ colLse)
{
  const int tid = threadIdx.x;
  const int bn = blockIdx.x;
  const int b = bn >> 10;
  float* row = logS + (size_t)bn * Mmm;
  float4 v4 = *(float4*)&row[tid * 4];
  if (colLse) {
    const float4 c4 = *(const float4*)&colLse[(size_t)b * Mmm + tid * 4];
    v4.x -= c4.x; v4.y -= c4.y; v4.z -= c4.z; v4.w -= c4.w;
  }
  float mx = fmaxf(fmaxf(v4.x, v4.y), fmaxf(v4.z, v4.w));
  float sm = expf(v4.x - mx) + expf(v4.y - mx) + expf(v4.z - mx) + expf(v4.w - mx);
  #pragma unroll
  for (int off = 32; off > 0; off >>= 1) {
    float mo = __shfl_xor(mx, off, 64);
    float so = __shfl_xor(sm, off, 64);
    float mn = fmaxf(mx, mo);
    sm = sm * expf(mx - mn) + so * expf(mo - mn);
    mx = mn;
  }
  __shared__ float wm[4], wsum[4];
  const int wv = tid >> 6, ln = tid & 63;
  if (ln == 0) { wm[wv] = mx; wsum[wv] = sm; }
  __syncthreads();
  float m0 = fmaxf(fmaxf(wm[0], wm[1]), fmaxf(wm[2], wm[3]));
  float stot = wsum[0] * expf(wm[0] - m0) + wsum[1] * expf(wm[1] - m0)
             + wsum[2] * expf(wm[2] - m0) + wsum[3] * expf(wm[3] - m0);
  float lse = m0 + logf(stot);
  v4.x -= lse; v4.y -= lse; v4.z -= lse; v4.w -= lse;
  *(float4*)&row[tid * 4] = v4;
}

// Column-LSE partials: grid (M/256, NSPLIT, B)
__global__ __launch_bounds__(256) void col_part_k(
    const float* __restrict__ logS, float* __restrict__ pmax, float* __restrict__ psum)
{
  const int b = blockIdx.z, sp = blockIdx.y;
  const int m = blockIdx.x * 256 + threadIdx.x;
  const int RPS = Nn / NSPLIT;
  const float* base = logS + ((size_t)b * Nn + sp * RPS) * Mmm + m;
  float mx = -1e30f, sm = 0.f;
  for (int i = 0; i < RPS; ++i) {
    float v = base[(size_t)i * Mmm];
    if (v > mx) { sm = sm * expf(mx - v) + 1.f; mx = v; }
    else sm += expf(v - mx);
  }
  size_t o = ((size_t)b * NSPLIT + sp) * Mmm + m;
  pmax[o] = mx; psum[o] = sm;
}

__global__ __launch_bounds__(256) void col_comb_k(
    const float* __restrict__ pmax, const float* __restrict__ psum, float* __restrict__ colLse)
{
  const int b = blockIdx.y;
  const int m = blockIdx.x * 256 + threadIdx.x;
  float mx = -1e30f;
  for (int s = 0; s < NSPLIT; ++s) mx = fmaxf(mx, pmax[((size_t)b * NSPLIT + s) * Mmm + m]);
  float sm = 0.f;
  for (int s = 0; s < NSPLIT; ++s) {
    size_t o = ((size_t)b * NSPLIT + s) * Mmm + m;
    sm += psum[o] * expf(pmax[o] - mx);
  }
  colLse[(size_t)b * Mmm + m] = mx + logf(sm);
}

// ---------------------------------------------------------------------------
// Finalize: S = exp(logS - colLse); fp32 outputs.
// ---------------------------------------------------------------------------
__global__ __launch_bounds__(256) void finalize_k(
    const float* __restrict__ logS, const float* __restrict__ colLse,
    const float* __restrict__ tgt_pts, float* __restrict__ outS, float* __restrict__ outConf,
    float* __restrict__ conf, float* __restrict__ tcp)
{
  const int tid = threadIdx.x;
  const int bn = blockIdx.x;
  const int b = bn >> 10;
  const float* row = logS + (size_t)bn * Mmm;
  const float* cl = colLse + (size_t)b * Mmm;
  const float* tp = tgt_pts + (size_t)b * Mmm * 3;
  __shared__ float red[256];
  float mx = -1e30f, s0 = 0.f, s1 = 0.f, s2 = 0.f;
  for (int m = tid; m < Mmm; m += 256) {
    float sv = expf(row[m] - cl[m]);
    outS[(size_t)bn * Mmm + m] = sv;
    mx = fmaxf(mx, sv);
    s0 = fmaf(sv, tp[m * 3 + 0], s0);
    s1 = fmaf(sv, tp[m * 3 + 1], s1);
    s2 = fmaf(sv, tp[m * 3 + 2], s2);
  }
  float rmx, r0, r1, r2;
  BLK_REDUCE_F(fmaxf, mx, rmx);
  BLK_REDUCE_F(addf, s0, r0);
  BLK_REDUCE_F(addf, s1, r1);
  BLK_REDUCE_F(addf, s2, r2);
  if (tid == 0) {
    conf[bn] = rmx;
    outConf[bn] = rmx;
    tcp[(size_t)bn * 3 + 0] = r0;
    tcp[(size_t)bn * 3 + 1] = r1;
    tcp[(size_t)bn * 3 + 2] = r2;
  }
}

// ---------------------------------------------------------------------------
// Kabsch stage 1: per-batch weighted sums (double)
// ---------------------------------------------------------------------------
__global__ __launch_bounds__(256) void kabsch_red_k(
    const float* __restrict__ conf, const float* __restrict__ src_pts,
    const float* __restrict__ tcp, double* __restrict__ kab)
{
  const int b = blockIdx.x;
  const int tid = threadIdx.x;
  __shared__ double redd[256];
  __shared__ double sh[8];
  const float* cb = conf + (size_t)b * Nn;
  const float* sb = src_pts + (size_t)b * Nn * 3;
  const float* tb = tcp + (size_t)b * Nn * 3;

  double a = 0.0;
  for (int n = tid; n < Nn; n += 256) a += (double)cb[n];
  double wsum; BLK_REDUCE_D(addd, a, wsum);
  double inv = 1.0 / (wsum + 1e-8);

  double c0 = 0, c1 = 0, c2 = 0, t0 = 0, t1 = 0, t2 = 0;
  for (int n = tid; n < Nn; n += 256) {
    double wn = (double)cb[n] * inv;
    c0 += wn * (double)sb[n * 3 + 0];
    c1 += wn * (double)sb[n * 3 + 1];
    c2 += wn * (double)sb[n * 3 + 2];
    t0 += wn * (double)tb[n * 3 + 0];
    t1 += wn * (double)tb[n * 3 + 1];
    t2 += wn * (double)tb[n * 3 + 2];
  }
  double r;
  BLK_REDUCE_D(addd, c0, r); if (tid == 0) sh[0] = r; __syncthreads();
  BLK_REDUCE_D(addd, c1, r); if (tid == 0) sh[1] = r; __syncthreads();
  BLK_REDUCE_D(addd, c2, r); if (tid == 0) sh[2] = r; __syncthreads();
  BLK_REDUCE_D(addd, t0, r); if (tid == 0) sh[3] = r; __syncthreads();
  BLK_REDUCE_D(addd, t1, r); if (tid == 0) sh[4] = r; __syncthreads();
  BLK_REDUCE_D(addd, t2, r); if (tid == 0) sh[5] = r; __syncthreads();
  double cs[3] = {sh[0], sh[1], sh[2]};
  double ct[3] = {sh[3], sh[4], sh[5]};

  double hm[9] = {};
  for (int n = tid; n < Nn; n += 256) {
    double wn = (double)cb[n] * inv;
    double d0 = (double)sb[n * 3 + 0] - cs[0];
    double d1 = (double)sb[n * 3 + 1] - cs[1];
    double d2 = (double)sb[n * 3 + 2] - cs[2];
    double e0 = (double)tb[n * 3 + 0] - ct[0];
    double e1 = (double)tb[n * 3 + 1] - ct[1];
    double e2 = (double)tb[n * 3 + 2] - ct[2];
    hm[0] += wn * d0 * e0; hm[1] += wn * d0 * e1; hm[2] += wn * d0 * e2;
    hm[3] += wn * d1 * e0; hm[4] += wn * d1 * e1; hm[5] += wn * d1 * e2;
    hm[6] += wn * d2 * e0; hm[7] += wn * d2 * e1; hm[8] += wn * d2 * e2;
  }
  for (int i = 0; i < 9; ++i) {
    BLK_REDUCE_D(addd, hm[i], r);
    if (tid == 0) kab[(size_t)b * 16 + i] = r;
    __syncthreads();
  }
  if (tid == 0) {
    for (int i = 0; i < 3; ++i) {
      kab[(size_t)b * 16 + 9 + i]  = cs[i];
      kab[(size_t)b * 16 + 12 + i] = ct[i];
    }
  }
}

// ---------------------------------------------------------------------------
// Kabsch stage 2 — numpy-mirror SVD; fp32 outputs.
// ---------------------------------------------------------------------------
__device__ __forceinline__ double trip(const double a[3], const double b[3], const double c[3]) {
  return a[0] * (b[1] * c[2] - b[2] * c[1])
       - a[1] * (b[0] * c[2] - b[2] * c[0])
       + a[2] * (b[0] * c[1] - b[1] * c[0]);
}

__global__ void kabsch_svd_k(const double* __restrict__ kab, float* __restrict__ outR, float* __restrict__ outT)
{
  const int b = threadIdx.x;
  if (b >= Bn) return;
  const double* kb = kab + (size_t)b * 16;
  double A[3][3], cs[3], ct[3];
  for (int i = 0; i < 3; ++i)
    for (int j = 0; j < 3; ++j) A[i][j] = kb[i * 3 + j];
  for (int i = 0; i < 3; ++i) { cs[i] = kb[9 + i]; ct[i] = kb[12 + i]; }

  double Km[3][3];
  for (int i = 0; i < 3; ++i)
    for (int j = 0; j < 3; ++j)
      Km[i][j] = A[0][i] * A[0][j] + A[1][i] * A[1][j] + A[2][i] * A[2][j];
  double V[3][3] = {{1, 0, 0}, {0, 1, 0}, {0, 0, 1}};
  const int PP[3] = {0, 0, 1}, QQ[3] = {1, 2, 2};
  for (int sweep = 0; sweep < 30; ++sweep) {
    for (int pi = 0; pi < 3; ++pi) {
      int p = PP[pi], qd = QQ[pi];
      double apq = Km[p][qd];
      if (fabs(apq) < 1e-300) continue;
      double theta = (Km[qd][qd] - Km[p][p]) / (2.0 * apq);
      double tt = (theta >= 0 ? 1.0 : -1.0) / (fabs(theta) + sqrt(theta * theta + 1.0));
      double cc = 1.0 / sqrt(tt * tt + 1.0), ss = tt * cc;
      for (int r = 0; r < 3; ++r) {
        double kp = Km[r][p], kq = Km[r][qd];
        Km[r][p] = cc * kp - ss * kq; Km[r][qd] = ss * kp + cc * kq;
      }
      for (int c = 0; c < 3; ++c) {
        double kp = Km[p][c], kq = Km[qd][c];
        Km[p][c] = cc * kp - ss * kq; Km[qd][c] = ss * kp + cc * kq;
      }
      for (int r = 0; r < 3; ++r) {
        double vp = V[r][p], vq = V[r][qd];
        V[r][p] = cc * vp - ss * vq; V[r][qd] = ss * vp + cc * vq;
      }
    }
  }
  double lam[3] = {Km[0][0], Km[1][1], Km[2][2]};
  int i0 = 0, i1 = 1, i2 = 2, tsw;
  if (lam[i0] < lam[i1]) { tsw = i0; i0 = i1; i1 = tsw; }
  if (lam[i0] < lam[i2]) { tsw = i0; i0 = i2; i2 = tsw; }
  if (lam[i1] < lam[i2]) { tsw = i1; i1 = i2; i2 = tsw; }
  double vv[3][3];
  for (int r = 0; r < 3; ++r) { vv[0][r] = V[r][i0]; vv[1][r] = V[r][i1]; vv[2][r] = V[r][i2]; }
  double sg[3] = { sqrt(fmax(lam[i0], 0.0)), sqrt(fmax(lam[i1], 0.0)), sqrt(fmax(lam[i2], 0.0)) };

  double uu[3][3];
  double eps = 1e-12 * (sg[0] > 0 ? sg[0] : 1.0);
  if (sg[0] > eps) {
    for (int r = 0; r < 3; ++r)
      uu[0][r] = (A[r][0] * vv[0][0] + A[r][1] * vv[0][1] + A[r][2] * vv[0][2]) / sg[0];
    double n = sqrt(uu[0][0]*uu[0][0] + uu[0][1]*uu[0][1] + uu[0][2]*uu[0][2]);
    if (n > 1e-14) { uu[0][0]/=n; uu[0][1]/=n; uu[0][2]/=n; }
  } else { uu[0][0]=1; uu[0][1]=0; uu[0][2]=0; }
  if (sg[1] > eps) {
    for (int r = 0; r < 3; ++r)
      uu[1][r] = (A[r][0] * vv[1][0] + A[r][1] * vv[1][1] + A[r][2] * vv[1][2]) / sg[1];
  } else {
    int ax = (fabs(uu[0][0]) <= fabs(uu[0][1]) && fabs(uu[0][0]) <= fabs(uu[0][2])) ? 0
           : (fabs(uu[0][1]) <= fabs(uu[0][2]) ? 1 : 2);
    uu[1][0] = uu[1][1] = uu[1][2] = 0.0; uu[1][ax] = 1.0;
  }
  {
    double pr = uu[0][0]*uu[1][0] + uu[0][1]*uu[1][1] + uu[0][2]*uu[1][2];
    for (int r = 0; r < 3; ++r) uu[1][r] -= pr * uu[0][r];
    double n = sqrt(uu[1][0]*uu[1][0] + uu[1][1]*uu[1][1] + uu[1][2]*uu[1][2]);
    if (n > 1e-14) { uu[1][0]/=n; uu[1][1]/=n; uu[1][2]/=n; }
  }
  if (sg[2] > eps) {
    for (int r = 0; r < 3; ++r)
      uu[2][r] = (A[r][0] * vv[2][0] + A[r][1] * vv[2][1] + A[r][2] * vv[2][2]) / sg[2];
    double p0 = uu[0][0]*uu[2][0] + uu[0][1]*uu[2][1] + uu[0][2]*uu[2][2];
    double p1 = uu[1][0]*uu[2][0] + uu[1][1]*uu[2][1] + uu[1][2]*uu[2][2];
    for (int r = 0; r < 3; ++r) uu[2][r] -= p0 * uu[0][r] + p1 * uu[1][r];
    double n = sqrt(uu[2][0]*uu[2][0] + uu[2][1]*uu[2][1] + uu[2][2]*uu[2][2]);
    if (n > 1e-14) { uu[2][0]/=n; uu[2][1]/=n; uu[2][2]/=n; }
    else {
      uu[2][0] = uu[0][1]*uu[1][2] - uu[0][2]*uu[1][1];
      uu[2][1] = uu[0][2]*uu[1][0] - uu[0][0]*uu[1][2];
      uu[2][2] = uu[0][0]*uu[1][1] - uu[0][1]*uu[1][0];
    }
  } else {
    uu[2][0] = uu[0][1]*uu[1][2] - uu[0][2]*uu[1][1];
    uu[2][1] = uu[0][2]*uu[1][0] - uu[0][0]*uu[1][2];
    uu[2][2] = uu[0][0]*uu[1][1] - uu[0][1]*uu[1][0];
  }

  double detU = trip(uu[0], uu[1], uu[2]);
  double detV = trip(vv[0], vv[1], vv[2]);
  double d = (detU * detV < 0.0) ? -1.0 : 1.0;

  double R[3][3];
  for (int i = 0; i < 3; ++i)
    for (int j = 0; j < 3; ++j)
      R[i][j] = vv[0][i] * uu[0][j] + vv[1][i] * uu[1][j] + d * vv[2][i] * uu[2][j];
  for (int i = 0; i < 3; ++i) {
    double t = ct[i] - (R[i][0] * cs[0] + R[i][1] * cs[1] + R[i][2] * cs[2]);
    outT[(size_t)b * 3 + i] = (float)t;
    for (int j = 0; j < 3; ++j)
      outR[(size_t)b * 9 + i * 3 + j] = (float)R[i][j];
  }
}

// x.max over N: two-stage (partials over 64-row chunks, then combine)
__global__ __launch_bounds__(256) void xmax_part_k(const float* __restrict__ x, float* __restrict__ part)
{
  const int b = blockIdx.x, ch = blockIdx.y;
  const int d = threadIdx.x;
  float mx = -1e30f;
  const int n0 = ch * 64;
  for (int n = n0; n < n0 + 64; ++n)
    mx = fmaxf(mx, x[((size_t)b * Nn + n) * ADc + d]);
  part[((size_t)b * 16 + ch) * ADc + d] = mx;
}

__global__ __launch_bounds__(256) void xmax_comb_k(const float* __restrict__ part, float* __restrict__ xmax)
{
  const int b = blockIdx.x, d = threadIdx.x;
  float mx = -1e30f;
  for (int c = 0; c < 16; ++c) mx = fmaxf(mx, part[((size_t)b * 16 + c) * ADc + d]);
  xmax[(size_t)b * ADc + d] = mx;
}

__global__ __launch_bounds__(256) void combined_k(
    const float* __restrict__ gl, const float* __restrict__ tgt_global, float* __restrict__ outC)
{
  int i = blockIdx.x * 256 + threadIdx.x;
  int b = i >> 10, j = i & 1023;
  float v = (j < GFDc) ? gl[(size_t)b * GFDc + j] : tgt_global[(size_t)b * GFDc + (j - GFDc)];
  outC[i] = v;
}

// ---------------------------------------------------------------------------
extern "C" void kernel_launch(void* const* d_in, const int* in_sizes, int n_in,
                              void* d_out, int out_size, void* d_ws, size_t ws_size,
                              hipStream_t stream) {
  (void)in_sizes; (void)n_in; (void)out_size; (void)ws_size;
  const float* src_feats = (const float*)d_in[0];
  const float* tgt_feats = (const float*)d_in[1];
  const float* src_pts   = (const float*)d_in[2];
  const float* tgt_pts   = (const float*)d_in[3];
  const float* tgt_glob  = (const float*)d_in[4];
  const float* sfp_w = (const float*)d_in[5];  const float* sfp_b = (const float*)d_in[6];
  const float* sfp_g = (const float*)d_in[7];  const float* sfp_bb = (const float*)d_in[8];
  const float* tfp_w = (const float*)d_in[9];  const float* tfp_b = (const float*)d_in[10];
  const float* tfp_g = (const float*)d_in[11]; const float* tfp_bb = (const float*)d_in[12];
  const float* rbf_w = (const float*)d_in[13];
  const float* qw = (const float*)d_in[14]; const float* qb = (const float*)d_in[15];
  const float* kw = (const float*)d_in[16]; const float* kb = (const float*)d_in[17];
  const float* vw = (const float*)d_in[18]; const float* vb = (const float*)d_in[19];
  const float* ow = (const float*)d_in[20]; const float* ob = (const float*)d_in[21];
  const float* n1_g = (const float*)d_in[22]; const float* n1_b = (const float*)d_in[23];
  const float* f1_w = (const float*)d_in[24]; const float* f1_b = (const float*)d_in[25];
  const float* f2_w = (const float*)d_in[26]; const float* f2_b = (const float*)d_in[27];
  const float* n2_g = (const float*)d_in[28]; const float* n2_b = (const float*)d_in[29];
  const float* scp_w = (const float*)d_in[30]; const float* scp_b = (const float*)d_in[31];
  const float* tcp_w = (const float*)d_in[32]; const float* tcp_b = (const float*)d_in[33];
  const float* temp  = (const float*)d_in[34];
  const float* gp_w = (const float*)d_in[35]; const float* gp_b = (const float*)d_in[36];
  const float* gp_g = (const float*)d_in[37]; const float* gp_bb = (const float*)d_in[38];

  float* out = (float*)d_out;
  float* outR    = out;                    // (B,3,3)
  float* outT    = out + 36;               // (B,3)
  float* outC    = out + 48;               // (B,1024)
  float* outConf = out + 48 + 4096;        // (B,N)
  float* outS    = out + 48 + 4096 + 4096; // (B,N,M)

  // overlay workspace, peak ~29.4 MB
  float* ws = (float*)d_ws;
  const size_t M1 = 1048576;
  float* A_   = ws + 0 * M1;     // raw proj / xq / h
  float* B_   = ws + 1 * M1;     // xc / ctx / ffn-hidden(lo)
  float* C_   = ws + 2 * M1;     // q / ffn-hidden(hi)
  float* D_   = ws + 3 * M1;     // tproj
  float* logS = ws + 0 * M1;     // overlays A..D after they die
  float* H2   = ws + 1 * M1;     // 2M-float FFN hidden chunk (B_+C_)
  float* E_   = ws + 4 * M1;     // k / src_corr
  float* F_   = ws + 5 * M1;     // v / tgt_corr
  float* G_   = ws + 6 * M1;     // src_proj -> x
  float* tail = ws + 7 * M1;
  float* colLse = tail;                         // 4096
  float* pmax   = colLse + 4096;                // 131072
  float* psum   = pmax + 131072;                // 131072
  float* conf   = psum + 131072;                // 4096
  float* tcp    = conf + 4096;                  // 12288
  float* xmax   = tcp + 12288;                  // 1024
  float* glraw  = xmax + 1024;                  // 2048
  float* gl     = glraw + 2048;                 // 2048
  double* kab   = (double*)(gl + 2048);         // 64 doubles (128 floats)
  float* xpart  = (float*)(kab + 64);           // 16384 floats

  const int BN = Bn * Nn;   // 4096

  // 1) projections + LN + ReLU
  gemm3_k<<<dim3(ADc / 64, BN / 64), 64, 0, stream>>>(src_feats, sfp_w, sfp_b, nullptr, A_, BN, PFDc, ADc, 0);
  ln2_k<<<BN, 256, 0, stream>>>(A_, sfp_g, sfp_bb, G_, 1);
  gemm3_k<<<dim3(ADc / 64, BN / 64), 64, 0, stream>>>(tgt_feats, tfp_w, tfp_b, nullptr, A_, BN, PFDc, ADc, 0);
  ln2_k<<<BN, 256, 0, stream>>>(A_, tfp_g, tfp_bb, D_, 1);

  // 2) pre-LN + q/k/v
  ln2_k<<<BN, 256, 0, stream>>>(G_, n1_g, n1_b, A_, 0);                       // xq -> A
  gemm3_k<<<dim3(ADc / 64, BN / 64), 64, 0, stream>>>(A_, qw, qb, nullptr, C_, BN, ADc, ADc, 0);
  ln2_k<<<BN, 256, 0, stream>>>(D_, n1_g, n1_b, B_, 0);                       // xc -> B
  gemm3_k<<<dim3(ADc / 64, BN / 64), 64, 0, stream>>>(B_, kw, kb, nullptr, E_, BN, ADc, ADc, 0);
  gemm3_k<<<dim3(ADc / 64, BN / 64), 64, 0, stream>>>(B_, vw, vb, nullptr, F_, BN, ADc, ADc, 0);

  // 3) flash attention (Q-tiled), out-proj + residual
  fattn<<<dim3(Bn * Hc, Nn / 64), 256, 0, stream>>>(C_, E_, F_, src_pts, tgt_pts, rbf_w, B_);  // ctx -> B
  gemm3_k<<<dim3(ADc / 64, BN / 64), 64, 0, stream>>>(B_, ow, ob, G_, G_, BN, ADc, ADc, 0);

  // 4) FFN: h -> A_ (full), hidden chunk (2048 rows) through H2 (B_+C_)
  ln2_k<<<BN, 256, 0, stream>>>(G_, n2_g, n2_b, A_, 0);                       // h -> A
  for (int c = 0; c < 2; ++c) {
    const float* hA = A_ + (size_t)c * 2048 * ADc;
    float* xA = G_ + (size_t)c * 2048 * ADc;
    gemm3_k<<<dim3(1024 / 64, 2048 / 64), 64, 0, stream>>>(hA, f1_w, f1_b, nullptr, H2, 2048, ADc, 1024, 1);
    gemm3_k<<<dim3(ADc / 64, 2048 / 64), 64, 0, stream>>>(H2, f2_w, f2_b, xA, xA, 2048, 1024, ADc, 0);
  }

  // 5) correspondences + Sinkhorn (logS overlays A..D)
  gemm3_k<<<dim3(ADc / 64, BN / 64), 64, 0, stream>>>(G_, scp_w, scp_b, nullptr, E_, BN, ADc, ADc, 0);
  gemm3_k<<<dim3(ADc / 64, BN / 64), 64, 0, stream>>>(D_, tcp_w, tcp_b, nullptr, F_, BN, ADc, ADc, 0);
  gemm_nt3_k<<<dim3(Mmm / 64, Nn / 64, Bn), 64, 0, stream>>>(E_, F_, logS, temp);

  for (int it = 0; it < 3; ++it) {
    row_lse2_k<<<BN, 256, 0, stream>>>(logS, it == 0 ? nullptr : colLse);
    col_part_k<<<dim3(Mmm / 256, NSPLIT, Bn), 256, 0, stream>>>(logS, pmax, psum);
    col_comb_k<<<dim3(Mmm / 256, Bn), 256, 0, stream>>>(pmax, psum, colLse);
  }
  finalize_k<<<BN, 256, 0, stream>>>(logS, colLse, tgt_pts, outS, outConf, conf, tcp);

  // 6) Kabsch
  kabsch_red_k<<<Bn, 256, 0, stream>>>(conf, src_pts, tcp, kab);
  kabsch_svd_k<<<1, 64, 0, stream>>>(kab, outR, outT);

  // 7) global pooling head
  xmax_part_k<<<dim3(Bn, 16), 256, 0, stream>>>(G_, xpart);
  xmax_comb_k<<<Bn, 256, 0, stream>>>(xpart, xmax);
  gemm_k<<<dim3(GFDc / 64, 1), 256, 0, stream>>>(xmax, gp_w, gp_b, nullptr, glraw, Bn, ADc, GFDc, 0);
  ln_k<<<Bn, 256, 0, stream>>>(glraw, gp_g, gp_bb, gl, GFDc, 1);
  combined_k<<<(Bn * 2 * GFDc) / 256, 256, 0, stream>>>(gl, tgt_glob, outC);
}